// Round 16
// baseline (4637.518 us; speedup 1.0000x reference)
//
#include <hip/hip_runtime.h>
#include <cstdint>
#include <cstddef>

#define Bdim 256
#define Ndim 96
#define Edim 1024
#define HDdim 300
#define Ldim 2
#define LHdim 600
#define NCdim 7
#define GDdim 900              // HD*(L+1)
#define ROWS (Bdim*Ndim)       // 24576
#define HSLICE 155648          // 256*608 elements per Hlstm time-slice

typedef unsigned short u16;
typedef float f32x4 __attribute__((ext_vector_type(4)));
typedef short bf16x8 __attribute__((ext_vector_type(8)));

// Identity row-perm constants
#define IDP 0x7FFFFFFF, 1, 30, 0, 0

__device__ inline u16 f2bf(float x) {
    unsigned int u = __builtin_bit_cast(unsigned int, x);
    unsigned int r = (u + 0x7fffu + ((u >> 16) & 1u)) >> 16;   // RNE
    return (u16)r;
}
__device__ inline float bf2f(u16 h) {
    unsigned int u = ((unsigned int)h) << 16;
    return __builtin_bit_cast(float, u);
}

// ---------------------------------------------------------------------------
// bf16 split MFMA GEMM, bx-major bijective XCD swizzle. reg->LDS staging.
// WPASS=3: C = (Ah+Al)(Wh+Wl) (bf16x3, full precision).
// WPASS=2: C = (Ah+Al)Wh (W at single bf16 — skips WtL staging + 1 MFMA pass).
// K mult of 32; lda/ldw mult 8. W must have gridDim.y*128 rows alloc (pads 0).
// OUT: 0 -> fp32 C; 1 -> split bf16 (Ch,Cl). ACT: 1 -> prelu(aptr).
// ---------------------------------------------------------------------------
template<int OUT, int ACT, int WPASS>
__global__ __launch_bounds__(256) void gemm_mfma3(
    const u16* __restrict__ Ah, const u16* __restrict__ Al, int lda,
    const u16* __restrict__ Wh, const u16* __restrict__ Wl, int ldw,
    float* __restrict__ C, u16* __restrict__ Ch, u16* __restrict__ Cl, int ldc,
    int M, int Nd, int K,
    const float* __restrict__ bias, const float* __restrict__ aptr)
{
    __shared__ u16 AtH[4][1024];
    __shared__ u16 AtL[4][1024];
    __shared__ u16 WtH[4][1024];
    __shared__ u16 WtL[4][1024];
    const int tid  = threadIdx.x;
    const int ny  = gridDim.y;
    const int nwg = gridDim.x * ny;
    const int lin = blockIdx.y * gridDim.x + blockIdx.x;
    const int q = nwg >> 3, r8 = nwg & 7;
    const int xcd = lin & 7, off = lin >> 3;
    const int swz = (xcd < r8) ? xcd * (q + 1) + off
                               : r8 * (q + 1) + (xcd - r8) * q + off;
    const int bm   = (swz / ny) * 128;
    const int bn   = (swz % ny) * 128;
    const int wv   = tid >> 6;
    const int lane = tid & 63;
    const int wr   = (wv >> 1) * 64;
    const int wc   = (wv & 1) * 64;
    const int l15  = lane & 15;
    const int kseg = lane >> 4;

    f32x4 acc[4][4];
    #pragma unroll
    for (int i = 0; i < 4; ++i)
        #pragma unroll
        for (int j = 0; j < 4; ++j) acc[i][j] = (f32x4){0.f,0.f,0.f,0.f};

    const int srow = tid & 127;
    const bool isA = (tid < 128);
    const int gr   = isA ? (bm + srow) : (bn + srow);
    const int glim = isA ? M : 0x7FFFFFFF;
    const u16* pHbase = (isA ? Ah : Wh) + (size_t)gr * (isA ? lda : ldw);
    const u16* pLbase = (isA ? Al : Wl) + (size_t)gr * (isA ? lda : ldw);
    u16* dH = isA ? &AtH[0][0] : &WtH[0][0];
    u16* dL = isA ? &AtL[0][0] : &WtL[0][0];

    for (int k0 = 0; k0 < K; k0 += 32) {
        __syncthreads();
        {
            const bool ok = (gr < glim);
            const bool doL = (WPASS == 3) || isA;   // skip WtL staging for WPASS=2
            #pragma unroll
            for (int s = 0; s < 4; ++s) {
                bf16x8 vH = {0,0,0,0,0,0,0,0};
                if (ok) vH = *(const bf16x8*)(pHbase + k0 + s * 8);
                *(bf16x8*)(dH + s * 1024 + srow * 8) = vH;
                if (doL) {
                    bf16x8 vL = {0,0,0,0,0,0,0,0};
                    if (ok) vL = *(const bf16x8*)(pLbase + k0 + s * 8);
                    *(bf16x8*)(dL + s * 1024 + srow * 8) = vL;
                }
            }
        }
        __syncthreads();
        bf16x8 aH[4], aL[4], bH[4];
        #pragma unroll
        for (int f = 0; f < 4; ++f) {
            int ar = wr + f * 16 + l15;
            int br = wc + f * 16 + l15;
            aH[f] = *(const bf16x8*)&AtH[kseg][ar * 8];
            aL[f] = *(const bf16x8*)&AtL[kseg][ar * 8];
            bH[f] = *(const bf16x8*)&WtH[kseg][br * 8];
        }
        #pragma unroll
        for (int i = 0; i < 4; ++i)
            #pragma unroll
            for (int j = 0; j < 4; ++j)
                acc[i][j] = __builtin_amdgcn_mfma_f32_16x16x32_bf16(aH[i], bH[j], acc[i][j], 0, 0, 0);
        if (WPASS == 3) {
            bf16x8 bL[4];
            #pragma unroll
            for (int f = 0; f < 4; ++f) {
                int br = wc + f * 16 + l15;
                bL[f] = *(const bf16x8*)&WtL[kseg][br * 8];
            }
            #pragma unroll
            for (int i = 0; i < 4; ++i)
                #pragma unroll
                for (int j = 0; j < 4; ++j)
                    acc[i][j] = __builtin_amdgcn_mfma_f32_16x16x32_bf16(aH[i], bL[j], acc[i][j], 0, 0, 0);
        }
        #pragma unroll
        for (int i = 0; i < 4; ++i)
            #pragma unroll
            for (int j = 0; j < 4; ++j)
                acc[i][j] = __builtin_amdgcn_mfma_f32_16x16x32_bf16(aL[i], bH[j], acc[i][j], 0, 0, 0);
    }

    const float av = (ACT == 1) ? *aptr : 0.f;
    const int r4 = (lane >> 4) * 4;
    #pragma unroll
    for (int j = 0; j < 4; ++j) {
        int col = bn + wc + j * 16 + l15;
        if (col >= Nd) continue;
        float bv = bias ? bias[col] : 0.f;
        #pragma unroll
        for (int i = 0; i < 4; ++i) {
            #pragma unroll
            for (int rr = 0; rr < 4; ++rr) {
                int row = bm + wr + i * 16 + r4 + rr;
                if (row >= M) continue;
                float v = acc[i][j][rr] + bv;
                if (ACT == 1) v = (v >= 0.f) ? v : av * v;
                if (OUT == 0) {
                    C[(size_t)row * ldc + col] = v;
                } else {
                    u16 h = f2bf(v);
                    Ch[(size_t)row * ldc + col] = h;
                    Cl[(size_t)row * ldc + col] = f2bf(v - bf2f(h));
                }
            }
        }
    }
}

// ---------------------------------------------------------------------------
// split fp32 -> bf16 hi/lo, vectorized: 4 rows/block, 8 cols/thread.
// ---------------------------------------------------------------------------
__global__ __launch_bounds__(256) void split_rows8(
    const float* __restrict__ src, int srcld,
    int pmask, int pmul1, int pshift, int pmul2, int padd,
    u16* __restrict__ dstH, u16* __restrict__ dstL, int dstld,
    int wcols, int validK, int validRows)
{
    const int r = blockIdx.y * 4 + (threadIdx.x >> 6);
    const int c = (blockIdx.x * 64 + (threadIdx.x & 63)) * 8;
    if (c >= wcols) return;
    const int sr = (r & pmask) * pmul1 + (r >> pshift) * pmul2 + padd;
    const float* s = src + (size_t)sr * srcld;
    const bool rok = (r < validRows);
    float v[8];
    if (rok && c + 8 <= validK) {
        *(float4*)&v[0] = *(const float4*)(s + c);
        *(float4*)&v[4] = *(const float4*)(s + c + 4);
    } else {
        #pragma unroll
        for (int u = 0; u < 8; ++u) v[u] = (rok && c + u < validK) ? s[c + u] : 0.f;
    }
    bf16x8 H8, L8;
    #pragma unroll
    for (int u = 0; u < 8; ++u) {
        u16 h = f2bf(v[u]);
        H8[u] = (short)h;
        L8[u] = (short)f2bf(v[u] - bf2f(h));
    }
    *(bf16x8*)(dstH + (size_t)r * dstld + c) = H8;
    *(bf16x8*)(dstL + (size_t)r * dstld + c) = L8;
}

// biasP[n'] = b_ih[orig]+b_hh[orig], orig = (n'&3)*600+(n'>>2)
__global__ __launch_bounds__(256) void bias_perm(
    const float* __restrict__ bih, const float* __restrict__ bhh, float* __restrict__ dst)
{
    int n = blockIdx.x * 256 + threadIdx.x;
    if (n >= 4 * LHdim) return;
    int o = (n & 3) * LHdim + (n >> 2);
    dst[n] = bih[o] + bhh[o];
}

// Wr2f[l][r][c]: r<300 -> wr0[l][r][c], else wr1[l][r-300][c]
__global__ __launch_bounds__(256) void wr_cat(
    const float* __restrict__ wr0, const float* __restrict__ wr1, float* __restrict__ dst)
{
    int c = blockIdx.x * 256 + threadIdx.x;
    if (c >= HDdim) return;
    int lr = blockIdx.y;
    int l = lr / (2 * HDdim), r = lr % (2 * HDdim);
    const float* src = (r < HDdim)
        ? wr0 + ((size_t)l * HDdim + r) * HDdim
        : wr1 + ((size_t)l * HDdim + (r - HDdim)) * HDdim;
    dst[(size_t)lr * HDdim + c] = src[c];
}

__global__ __launch_bounds__(256) void zero_range(float* __restrict__ p, int n)
{
    int i = blockIdx.x * 256 + threadIdx.x;
    if (i < n) p[i] = 0.f;
}

// ---------------------------------------------------------------------------
__global__ __launch_bounds__(256) void norm_kernel(const float* __restrict__ f, float* __restrict__ invn)
{
    int row  = blockIdx.x * 4 + (threadIdx.x >> 6);
    int lane = threadIdx.x & 63;
    const float* fr = f + (size_t)row * Edim;
    float ss = 0.f;
    for (int t = lane; t < Edim; t += 64) { float v = fr[t]; ss = fmaf(v, v, ss); }
    #pragma unroll
    for (int o = 32; o > 0; o >>= 1) ss += __shfl_down(ss, o);
    if (lane == 0) invn[row] = 1.f / (sqrtf(ss) + 1e-8f);
}

__global__ __launch_bounds__(256) void simadj_kernel(
    const float* __restrict__ f, const float* __restrict__ invn,
    const float* __restrict__ entro, const float* __restrict__ alphap,
    const float* __restrict__ thrp, uint8_t* __restrict__ adj)
{
    int b = blockIdx.x;
    __shared__ float S[16][100];
    int tid = threadIdx.x;
    int i0 = (tid >> 4) * 6, j0 = (tid & 15) * 6;
    float acc[6][6];
    #pragma unroll
    for (int i = 0; i < 6; ++i)
        #pragma unroll
        for (int j = 0; j < 6; ++j) acc[i][j] = 0.f;
    const float* fb = f + (size_t)b * Ndim * Edim;

    for (int k0 = 0; k0 < Edim; k0 += 16) {
        __syncthreads();
        #pragma unroll
        for (int r = 0; r < 6; ++r) {
            int n = (tid >> 4) + r * 16;
            S[tid & 15][n] = fb[(size_t)n * Edim + k0 + (tid & 15)];
        }
        __syncthreads();
        #pragma unroll
        for (int kk = 0; kk < 16; ++kk) {
            float a[6], bb[6];
            #pragma unroll
            for (int u = 0; u < 6; ++u) a[u] = S[kk][i0 + u];
            #pragma unroll
            for (int u = 0; u < 6; ++u) bb[u] = S[kk][j0 + u];
            #pragma unroll
            for (int i = 0; i < 6; ++i)
                #pragma unroll
                for (int j = 0; j < 6; ++j)
                    acc[i][j] = fmaf(a[i], bb[j], acc[i][j]);
        }
    }

    float alpha = *alphap, thr = *thrp;
    float onem = 1.f - alpha;
    #pragma unroll
    for (int i = 0; i < 6; ++i) {
        int ii = i0 + i;
        float inv_i = invn[b * Ndim + ii];
        #pragma unroll
        for (int j = 0; j < 6; ++j) {
            int jj = j0 + j;
            float simv = acc[i][j] * inv_i * invn[b * Ndim + jj];
            float comb = alpha * entro[b * Ndim + jj] + onem * simv;
            adj[((size_t)b * Ndim + ii) * Ndim + jj] = (comb > thr) ? 1 : 0;
        }
    }
}

// k[r] = H[r,:300] . wk   (q cancels in the adjacency softmax; not computed)
__global__ __launch_bounds__(256) void k_kernel(
    const float* __restrict__ Hsrc, const float* __restrict__ wk,
    float* __restrict__ k)
{
    int row  = blockIdx.x * 4 + (threadIdx.x >> 6);
    int lane = threadIdx.x & 63;
    const float* h = Hsrc + (size_t)row * GDdim;
    float sk = 0.f;
    for (int t = lane; t < HDdim; t += 64) sk = fmaf(h[t], wk[t], sk);
    #pragma unroll
    for (int o = 32; o > 0; o >>= 1) sk += __shfl_down(sk, o);
    if (lane == 0) k[row] = sk;
}

// ---------------------------------------------------------------------------
// Fused GAT attention for one batch b (q, gat_b cancel in softmax).
// V combined: cols 0..299 = V0, 300..599 = V1, row stride 600 (n-major rows).
// ---------------------------------------------------------------------------
__global__ __launch_bounds__(256) void gat_fused(
    const float* __restrict__ kbuf, const uint8_t* __restrict__ adj,
    const int* __restrict__ smask,
    const float* __restrict__ V,
    float* __restrict__ Mout)
{
    __shared__ float P0[96][98];
    __shared__ float P1[96][98];
    __shared__ float Vs0[96][96];
    __shared__ float Vs1[96][96];
    __shared__ float ek[96];
    __shared__ float rden[96];
    __shared__ float red[256];
    const int b = blockIdx.x;
    const int tid = threadIdx.x;

    float kj = (tid < Ndim) ? kbuf[tid * Bdim + b] : -1e30f;
    red[tid] = kj;
    __syncthreads();
    #pragma unroll
    for (int s = 128; s > 0; s >>= 1) {
        if (tid < s) red[tid] = fmaxf(red[tid], red[tid + s]);
        __syncthreads();
    }
    float kmax = red[0];
    if (tid < Ndim) ek[tid] = expf(kj - kmax);
    __syncthreads();
    if (tid < Ndim) {
        const uint8_t* ar = adj + ((size_t)b * Ndim + tid) * Ndim;
        float s = 0.f;
        for (int j = 0; j < Ndim; ++j) if (ar[j]) s += ek[j];
        rden[tid] = 1.f / s;   // diagonal always allowed -> s > 0
    }
    __syncthreads();
    for (int idx = tid; idx < Ndim * Ndim; idx += 256) {
        int i = idx / Ndim, j = idx - i * Ndim;
        float a = adj[((size_t)b * Ndim + i) * Ndim + j] ? ek[j] * rden[i] : 0.f;
        int s = smask[((size_t)b * Ndim + i) * Ndim + j];
        P0[i][j] = s ? a : 0.f;
        P1[i][j] = s ? 0.f : a;
    }
    __syncthreads();

    const int ti = tid >> 4, td = tid & 15;
    const int i0 = ti * 6, dbase = td * 6;
    for (int p = 0; p < 4; ++p) {
        const int d0 = p * 96;
        const int dw = (p == 3) ? (HDdim - 288) : 96;
        for (int idx = tid; idx < 96 * 24; idx += 256) {
            int j = idx / 24, q4 = (idx - j * 24) * 4;
            if (q4 < dw) {
                size_t g = ((size_t)(j * Bdim + b)) * (2 * HDdim) + d0 + q4;
                *(float4*)&Vs0[j][q4] = *(const float4*)(V + g);
                *(float4*)&Vs1[j][q4] = *(const float4*)(V + g + HDdim);
            }
        }
        __syncthreads();
        float acc[6][6];
        #pragma unroll
        for (int ii = 0; ii < 6; ++ii)
            #pragma unroll
            for (int dd = 0; dd < 6; ++dd) acc[ii][dd] = 0.f;
        for (int j = 0; j < Ndim; j += 2) {
            float2 pa[6], pb[6];
            #pragma unroll
            for (int ii = 0; ii < 6; ++ii) {
                pa[ii] = *(const float2*)&P0[i0 + ii][j];
                pb[ii] = *(const float2*)&P1[i0 + ii][j];
            }
            float2 v0a[3], v0b[3], v1a[3], v1b[3];
            #pragma unroll
            for (int dd = 0; dd < 3; ++dd) {
                v0a[dd] = *(const float2*)&Vs0[j][dbase + 2 * dd];
                v0b[dd] = *(const float2*)&Vs0[j + 1][dbase + 2 * dd];
                v1a[dd] = *(const float2*)&Vs1[j][dbase + 2 * dd];
                v1b[dd] = *(const float2*)&Vs1[j + 1][dbase + 2 * dd];
            }
            #pragma unroll
            for (int ii = 0; ii < 6; ++ii)
                #pragma unroll
                for (int dd = 0; dd < 3; ++dd) {
                    acc[ii][2*dd]   += pa[ii].x * v0a[dd].x + pb[ii].x * v1a[dd].x
                                     + pa[ii].y * v0b[dd].x + pb[ii].y * v1b[dd].x;
                    acc[ii][2*dd+1] += pa[ii].x * v0a[dd].y + pb[ii].x * v1a[dd].y
                                     + pa[ii].y * v0b[dd].y + pb[ii].y * v1b[dd].y;
                }
        }
        __syncthreads();
        #pragma unroll
        for (int ii = 0; ii < 6; ++ii) {
            #pragma unroll
            for (int dd = 0; dd < 6; ++dd) {
                int d = dbase + dd;
                if (d < dw)
                    Mout[((size_t)((i0 + ii) * Bdim + b)) * GDdim + d0 + d] = acc[ii][dd];
            }
        }
    }
}

// ---------------------------------------------------------------------------
// Per-step LSTM (round-13 proven: double-buffered LDS, one barrier per
// k-chunk) + T14 async-split + Hlstm-slice ping-pong (round 15 verified).
// Tile 32 batch x 64 gate-cols, grid (8,38).
// ---------------------------------------------------------------------------
__global__ __launch_bounds__(256) void lstm_mfma3(
    const u16* __restrict__ hH, const u16* __restrict__ hL,
    const float* __restrict__ cin,
    const u16* __restrict__ WH, const u16* __restrict__ WL,   // (2432 x 608)
    const float* __restrict__ zt,
    u16* __restrict__ hHo, u16* __restrict__ hLo,
    float* __restrict__ cout)
{
    __shared__ u16 AsH[2][4][256];
    __shared__ u16 AsL[2][4][256];
    __shared__ u16 WsH[2][4][512];
    __shared__ u16 WsL[2][4][512];
    __shared__ __align__(16) float gates[32][68];
    const int tid = threadIdx.x;
    const int bm = blockIdx.x * 32;
    const int bn = blockIdx.y * 64;
    const int wv = tid >> 6;
    const int lane = tid & 63;
    const int l15 = lane & 15;
    const int kseg = lane >> 4;
    const float4 fz = make_float4(0.f, 0.f, 0.f, 0.f);

    // --- T14: issue cell-phase loads NOW; consumed after the k-loop ---
    const int prow0 = tid >> 4,        pui0 = tid & 15;
    const int prow1 = (tid + 256) >> 4, pui1 = tid & 15;     // cell1 = tid+256
    const int pn0 = bn + pui0 * 4,  pn1 = bn + pui1 * 4;
    const int pu0 = pn0 >> 2,       pu1 = pn1 >> 2;
    const bool ok0 = (pu0 < LHdim), ok1 = (pu1 < LHdim);
    const int bb0 = bm + prow0,     bb1 = bm + prow1;
    float4 z0 = ok0 ? *(const float4*)(zt + (size_t)bb0 * (4 * LHdim) + pn0) : fz;
    float4 z1 = ok1 ? *(const float4*)(zt + (size_t)bb1 * (4 * LHdim) + pn1) : fz;
    float ci0 = ok0 ? cin[bb0 * LHdim + pu0] : 0.f;
    float ci1 = ok1 ? cin[bb1 * LHdim + pu1] : 0.f;

    // A staging: tid<128 -> AsH, else AsL; each thread one bf16x8
    const int av = tid & 127;
    const int arow = av >> 2, akc = av & 3;
    const u16* asrc = ((tid < 128) ? hH : hL) + (size_t)(bm + arow) * 608 + akc * 8;
    const int aoff = akc * 256 + arow * 8;
    // W staging: each thread one bf16x8 of WsH and WsL
    const int wrow = tid >> 2, wkc = tid & 3;
    const u16* wsrcH = WH + (size_t)(bn + wrow) * 608 + wkc * 8;
    const u16* wsrcL = WL + (size_t)(bn + wrow) * 608 + wkc * 8;
    const int woff2 = wrow * 8;

    f32x4 acc[2];
    acc[0] = (f32x4){0.f,0.f,0.f,0.f};
    acc[1] = (f32x4){0.f,0.f,0.f,0.f};

    // preload chunk 0
    bf16x8 ra  = *(const bf16x8*)(asrc);
    bf16x8 rwh = *(const bf16x8*)(wsrcH);
    bf16x8 rwl = *(const bf16x8*)(wsrcL);

    #pragma unroll
    for (int kc = 0; kc < 19; ++kc) {
        const int buf = kc & 1;
        *(bf16x8*)(((tid < 128) ? &AsH[buf][0][0] : &AsL[buf][0][0]) + aoff) = ra;
        *(bf16x8*)(&WsH[buf][wkc][woff2]) = rwh;
        *(bf16x8*)(&WsL[buf][wkc][woff2]) = rwl;
        if (kc + 1 < 19) {                      // prefetch next chunk
            ra  = *(const bf16x8*)(asrc + (kc + 1) * 32);
            rwh = *(const bf16x8*)(wsrcH + (kc + 1) * 32);
            rwl = *(const bf16x8*)(wsrcL + (kc + 1) * 32);
        }
        __syncthreads();                        // single barrier per chunk
        bf16x8 aH[2], aL[2], bH, bL;
        #pragma unroll
        for (int i = 0; i < 2; ++i) {
            int arr = i * 16 + l15;
            aH[i] = *(const bf16x8*)&AsH[buf][kseg][arr * 8];
            aL[i] = *(const bf16x8*)&AsL[buf][kseg][arr * 8];
        }
        {
            int br = wv * 16 + l15;
            bH = *(const bf16x8*)&WsH[buf][kseg][br * 8];
            bL = *(const bf16x8*)&WsL[buf][kseg][br * 8];
        }
        #pragma unroll
        for (int i = 0; i < 2; ++i) {
            acc[i] = __builtin_amdgcn_mfma_f32_16x16x32_bf16(aH[i], bH, acc[i], 0, 0, 0);
            acc[i] = __builtin_amdgcn_mfma_f32_16x16x32_bf16(aH[i], bL, acc[i], 0, 0, 0);
            acc[i] = __builtin_amdgcn_mfma_f32_16x16x32_bf16(aL[i], bH, acc[i], 0, 0, 0);
        }
    }

    const int r4 = (lane >> 4) * 4;
    __syncthreads();
    #pragma unroll
    for (int i = 0; i < 2; ++i)
        #pragma unroll
        for (int rr = 0; rr < 4; ++rr)
            gates[i * 16 + r4 + rr][wv * 16 + l15] = acc[i][rr];
    __syncthreads();

    // fused cell: 2 cells per thread, using prefetched z/c
    if (ok0) {
        float4 g = *(const float4*)&gates[prow0][pui0 * 4];
        float gi = g.x + z0.x;
        float gf = g.y + z0.y;
        float gg = g.z + z0.z;
        float go = g.w + z0.w;
        float si = 1.f / (1.f + expf(-gi));
        float sf = 1.f / (1.f + expf(-gf));
        float so = 1.f / (1.f + expf(-go));
        float cn = sf * ci0 + si * tanhf(gg);
        float hn = so * tanhf(cn);
        cout[bb0 * LHdim + pu0] = cn;
        u16 hh = f2bf(hn);
        hHo[(size_t)bb0 * 608 + pu0] = hh;
        hLo[(size_t)bb0 * 608 + pu0] = f2bf(hn - bf2f(hh));
    }
    if (ok1) {
        float4 g = *(const float4*)&gates[prow1][pui1 * 4];
        float gi = g.x + z1.x;
        float gf = g.y + z1.y;
        float gg = g.z + z1.z;
        float go = g.w + z1.w;
        float si = 1.f / (1.f + expf(-gi));
        float sf = 1.f / (1.f + expf(-gf));
        float so = 1.f / (1.f + expf(-go));
        float cn = sf * ci1 + si * tanhf(gg);
        float hn = so * tanhf(cn);
        cout[bb1 * LHdim + pu1] = cn;
        u16 hh = f2bf(hn);
        hHo[(size_t)bb1 * 608 + pu1] = hh;
        hLo[(size_t)bb1 * 608 + pu1] = f2bf(hn - bf2f(hh));
    }
}

__global__ __launch_bounds__(256) void out_kernel(
    const float* __restrict__ x, int ldx, const float* __restrict__ ow,
    const float* __restrict__ ob, float* __restrict__ out)
{
    int r    = blockIdx.x * 4 + (threadIdx.x >> 6);
    int lane = threadIdx.x & 63;
    const float* xr = x + (size_t)r * ldx;
    float acc[NCdim];
    #pragma unroll
    for (int n = 0; n < NCdim; ++n) acc[n] = 0.f;
    for (int t = lane; t < HDdim; t += 64) {
        float xv = xr[t];
        #pragma unroll
        for (int n = 0; n < NCdim; ++n) acc[n] = fmaf(xv, ow[n * HDdim + t], acc[n]);
    }
    #pragma unroll
    for (int o = 32; o > 0; o >>= 1)
        #pragma unroll
        for (int n = 0; n < NCdim; ++n) acc[n] += __shfl_down(acc[n], o);
    if (lane == 0) {
        int b = r & 255, nn = r >> 8;
        #pragma unroll
        for (int n = 0; n < NCdim; ++n) out[((size_t)b * Ndim + nn) * NCdim + n] = acc[n] + ob[n];
    }
}

// ---------------------------------------------------------------------------
extern "C" void kernel_launch(void* const* d_in, const int* in_sizes, int n_in,
                              void* d_out, int out_size, void* d_ws, size_t ws_size,
                              hipStream_t stream)
{
    const float*  features  = (const float*)d_in[0];
    const int*    s_mask    = (const int*)  d_in[1];
    const float*  entro     = (const float*)d_in[2];
    const float*  alpha     = (const float*)d_in[3];
    const float*  threshold = (const float*)d_in[4];
    const float*  fc1_w     = (const float*)d_in[5];
    const float*  fc1_b     = (const float*)d_in[6];
    const float*  gat_w     = (const float*)d_in[7];
    const float*  gat_b     = (const float*)d_in[8];
    const float*  wr0       = (const float*)d_in[9];
    const float*  wr1       = (const float*)d_in[10];
    const float*  enhance_w = (const float*)d_in[11];
    const float*  enhance_b = (const float*)d_in[12];
    const float*  prelu_a   = (const float*)d_in[13];
    const float*  lstm_w_ih = (const float*)d_in[14];
    const float*  lstm_w_hh = (const float*)d_in[15];
    const float*  lstm_b_ih = (const float*)d_in[16];
    const float*  lstm_b_hh = (const float*)d_in[17];
    const float*  mlp_w0    = (const float*)d_in[18];
    const float*  mlp_b0    = (const float*)d_in[19];
    const float*  mlp_a0    = (const float*)d_in[20];
    const float*  mlp_w1    = (const float*)d_in[21];
    const float*  mlp_b1    = (const float*)d_in[22];
    const float*  mlp_a1    = (const float*)d_in[23];
    const float*  out_w     = (const float*)d_in[24];
    const float*  out_b     = (const float*)d_in[25];
    float* out = (float*)d_out;
    char* ws = (char*)d_ws;
    (void)gat_b;

    // ---- fixed workspace layout (bytes, 256-aligned) ----
    uint8_t* adj   = (uint8_t*)(ws + 0);               //  2,359,296
    float*   invn  = (float*)(ws + 2359296);
    float*   kbuf  = (float*)(ws + 2555904);
    float*   biasP = (float*)(ws + 2654208);
    float*   c0    = (float*)(ws + 2663936);           //    614,400
    float*   c1    = (float*)(ws + 3278336);
    u16*     WhhPH = (u16*)(ws + 5137920);             //  2,957,312 (2432 x 608)
    u16*     WhhPL = (u16*)(ws + 8095232);
    u16*     WihPH = (u16*)(ws + 11052544);            //  9,494,528 (2432 x 1952)
    u16*     WihPL = (u16*)(ws + 20547072);
    u16*     EwH   = (u16*)(ws + 30041600);            //  2,097,152 (1024 x 1024)
    u16*     EwL   = (u16*)(ws + 32138752);
    u16*     Fc1H  = (u16*)(ws + 34235904);            //    786,432 (384 x 1024)
    u16*     Fc1L  = (u16*)(ws + 35022336);
    float*   Wr2f  = (float*)(ws + 35808768);          //  1,440,256 (2 x 600 x 300)
    u16*     Wr2H  = (u16*)(ws + 37249024);            //    819,200 (2 x 640 x 320)
    u16*     Wr2L  = (u16*)(ws + 38068224);
    u16*     Wm0H  = (u16*)(ws + 38887424);            //    524,288 (384 x 608)
    u16*     Wm0L  = (u16*)(ws + 39411712);
    u16*     Wm1H  = (u16*)(ws + 39936000);            //    262,144 (384 x 320)
    u16*     Wm1L  = (u16*)(ws + 40198144);
    u16*     FfH   = (u16*)(ws + 40460288);            // 50,331,648 (ROWS x 1024)
    u16*     FfL   = (u16*)(ws + 90791936);
    float*   Hcat  = (float*)(ws + 141123584);         // 88,473,600 (ROWS,900) n-major
    u16*     HsH   = (u16*)(ws + 229597184);           // 15,728,640 (ROWS x 320)
    u16*     HsL   = (u16*)(ws + 245325824);
    // V (GAT, fp32 ROWSx600) aliases Hlstm (97 slices x 256 x 608 split bf16)
    float*   V      = (float*)(ws + 261054464);        // 58,982,400
    u16*     HlstmH = (u16*)(ws + 261054464);          // 30,195,712 (97 slices)
    u16*     HlstmL = (u16*)(ws + 291250176);          // 30,195,712 -> 321,445,888
    // MLP scratch aliases Hcat (dead after last Hcat split)
    u16*     x1H   = (u16*)Hcat;                       // 15,728,640 (ROWS x 320)
    u16*     x1L   = (u16*)(ws + 141123584 + 15728640);
    float*   x2    = (float*)(ws + 141123584 + 31457280);   // 29,884,416 (ROWS x 304)

    // ---- tier selection for chunked seq/zin region ----
    const size_t fixedNeed = 321445888ull;
    const size_t perT = 4456448ull;                    // zin(2,457,600)+seqH/L(1,998,848)
    int T;
    if      (ws_size >= fixedNeed + 96ull * perT) T = 96;
    else if (ws_size >= fixedNeed + 48ull * perT) T = 48;
    else if (ws_size >= fixedNeed + 32ull * perT) T = 32;
    else if (ws_size >= fixedNeed + 16ull * perT) T = 16;
    else if (ws_size >= fixedNeed +  8ull * perT) T = 8;
    else return;                                       // visible failure, no OOB
    char* cr = ws + fixedNeed;
    float* zin  = (float*)cr;                                // (Mc,2400)
    u16*   seqH = (u16*)(cr + (size_t)T * 2457600);          // (Mc,1952)
    u16*   seqL = (u16*)(cr + (size_t)T * 2457600 + (size_t)T * 999424);

    // 1) norms + adjacency
    norm_kernel<<<ROWS / 4, 256, 0, stream>>>(features, invn);
    simadj_kernel<<<Bdim, 256, 0, stream>>>(features, invn, entro, alpha, threshold, adj);

    // 2) weight/activation conversions
    split_rows8<<<dim3(2, ROWS / 4), 256, 0, stream>>>(            // features n-major full
        features, Edim, 255, Ndim, 8, 1, 0, FfH, FfL, Edim, Edim, Edim, ROWS);
    split_rows8<<<dim3(2, 96), 256, 0, stream>>>(                  // fc1_w (384x1024)
        fc1_w, Edim, IDP, Fc1H, Fc1L, Edim, Edim, Edim, HDdim);
    split_rows8<<<dim3(2, 256), 256, 0, stream>>>(                 // enhance_w
        enhance_w, Edim, IDP, EwH, EwL, Edim, Edim, Edim, Edim);
    split_rows8<<<dim3(4, 608), 256, 0, stream>>>(                 // Wih gate-interleaved
        lstm_w_ih, Edim + GDdim, 3, LHdim, 2, 1, 0, WihPH, WihPL, 1952, 1952, 1924, 2400);
    split_rows8<<<dim3(2, 608), 256, 0, stream>>>(                 // Whh gate-interleaved
        lstm_w_hh, LHdim, 3, LHdim, 2, 1, 0, WhhPH, WhhPL, 608, 608, LHdim, 2400);
    split_rows8<<<dim3(2, 96), 256, 0, stream>>>(                  // mlp_w0 (384x608)
        mlp_w0, LHdim, IDP, Wm0H, Wm0L, 608, 608, LHdim, HDdim);
    split_rows8<<<dim3(1, 96), 256, 0, stream>>>(                  // mlp_w1 (384x320)
        mlp_w1, HDdim, IDP, Wm1H, Wm1L, 320, 320, HDdim, HDdim);
    wr_cat<<<dim3(2, 2 * Ldim * HDdim), 256, 0, stream>>>(wr0, wr1, Wr2f);
    for (int l = 0; l < Ldim; ++l)
        split_rows8<<<dim3(1, 160), 256, 0, stream>>>(             // Wr2 (640x320 per layer)
            Wr2f + (size_t)l * 2 * HDdim * HDdim, HDdim, IDP,
            Wr2H + (size_t)l * 640 * 320, Wr2L + (size_t)l * 640 * 320,
            320, 320, HDdim, 2 * HDdim);
    bias_perm<<<10, 256, 0, stream>>>(lstm_b_ih, lstm_b_hh, biasP);
    zero_range<<<1200, 256, 0, stream>>>(c0, 307200);              // c0, c1

    // 3) H0 = prelu(features @ fc1_w^T + fc1_b) -> Hcat[:, 0:300] (MFMA)
    gemm_mfma3<0,1,3><<<dim3(ROWS/128, 3), 256, 0, stream>>>(
        FfH, FfL, Edim, Fc1H, Fc1L, Edim,
        Hcat, nullptr, nullptr, GDdim, ROWS, HDdim, Edim, fc1_b, prelu_a);

    // 4) GAT layers (MFMA V projection, fused softmax+aggregation)
    for (int l = 0; l < Ldim; ++l) {
        const float* Hsrc = Hcat + l * HDdim;
        k_kernel<<<ROWS / 4, 256, 0, stream>>>(Hsrc, gat_w + l * 2 * HDdim + HDdim, kbuf);
        split_rows8<<<dim3(1, ROWS / 4), 256, 0, stream>>>(        // Hsrc -> split (K=320)
            Hsrc, GDdim, IDP, HsH, HsL, 320, 320, HDdim, ROWS);
        gemm_mfma3<0,0,3><<<dim3(ROWS/128, 5), 256, 0, stream>>>(
            HsH, HsL, 320, Wr2H + (size_t)l * 640 * 320, Wr2L + (size_t)l * 640 * 320, 320,
            V, nullptr, nullptr, 2 * HDdim, ROWS, 2 * HDdim, 320, nullptr, nullptr);
        gat_fused<<<Bdim, 256, 0, stream>>>(
            kbuf, adj, s_mask, V, Hcat + (l + 1) * HDdim);
    }

    // 5) zero Hlstm split region (pads + slice 0 = h_0; aliased V until now)
    zero_range<<<58976, 256, 0, stream>>>((float*)HlstmH, 15097856);

    // 6) chunked: enhance MFMA -> Hcat split -> zin MFMA (bf16x2 W-side) -> LSTM
    int cur = 0;
    float* cb_[2] = {c0, c1};
    for (int t0 = 0; t0 < Ndim; t0 += T) {
        int Mc = T * Bdim;
        gemm_mfma3<1,1,3><<<dim3(Mc/128, 8), 256, 0, stream>>>(
            FfH + (size_t)t0 * Bdim * Edim, FfL + (size_t)t0 * Bdim * Edim, Edim,
            EwH, EwL, Edim,
            nullptr, seqH, seqL, 1952, Mc, Edim, Edim, enhance_b, prelu_a);
        split_rows8<<<dim3(2, Mc / 4), 256, 0, stream>>>(
            Hcat, GDdim, 0x7FFFFFFF, 1, 30, 0, t0 * Bdim,
            seqH + 1024, seqL + 1024, 1952, 928, GDdim, Mc);
        gemm_mfma3<0,0,2><<<dim3(Mc/128, 19), 256, 0, stream>>>(   // W single-bf16
            seqH, seqL, 1952, WihPH, WihPL, 1952,
            zin, nullptr, nullptr, 4 * LHdim, Mc, 4 * LHdim, 1952, biasP, nullptr);
        for (int tl = 0; tl < T; ++tl) {
            const int g = t0 + tl;                    // global step, 0-based
            lstm_mfma3<<<dim3(8, 38), 256, 0, stream>>>(
                HlstmH + (size_t)g * HSLICE, HlstmL + (size_t)g * HSLICE,
                cb_[cur], WhhPH, WhhPL,
                zin + (size_t)tl * Bdim * 4 * LHdim,
                HlstmH + (size_t)(g + 1) * HSLICE, HlstmL + (size_t)(g + 1) * HSLICE,
                cb_[cur ^ 1]);
            cur ^= 1;
        }
    }

    // 7) MLP head (MFMA, A = Hlstm slices 1..96) + output
    zero_range<<<30720, 256, 0, stream>>>((float*)x1H, 7864320);   // x1 pads must be 0
    gemm_mfma3<1,1,3><<<dim3(ROWS/128, 3), 256, 0, stream>>>(
        HlstmH + HSLICE, HlstmL + HSLICE, 608, Wm0H, Wm0L, 608,
        nullptr, x1H, x1L, 320, ROWS, HDdim, 608, mlp_b0, mlp_a0);
    gemm_mfma3<0,1,3><<<dim3(ROWS/128, 3), 256, 0, stream>>>(
        x1H, x1L, 320, Wm1H, Wm1L, 320,
        x2, nullptr, nullptr, 304, ROWS, HDdim, 320, mlp_b1, mlp_a1);
    out_kernel<<<ROWS / 4, 256, 0, stream>>>(x2, 304, out_w, out_b, out);
}

// Round 17
// 4043.948 us; speedup vs baseline: 1.1468x; 1.1468x over previous
//
#include <hip/hip_runtime.h>
#include <cstdint>
#include <cstddef>

#define Bdim 256
#define Ndim 96
#define Edim 1024
#define HDdim 300
#define Ldim 2
#define LHdim 600
#define NCdim 7
#define GDdim 900              // HD*(L+1)
#define ROWS (Bdim*Ndim)       // 24576
#define HSLICE 155648          // 256*608 elements per Hlstm time-slice

typedef unsigned short u16;
typedef float f32x4 __attribute__((ext_vector_type(4)));
typedef short bf16x8 __attribute__((ext_vector_type(8)));

// Identity row-perm constants
#define IDP 0x7FFFFFFF, 1, 30, 0, 0

__device__ inline u16 f2bf(float x) {
    unsigned int u = __builtin_bit_cast(unsigned int, x);
    unsigned int r = (u + 0x7fffu + ((u >> 16) & 1u)) >> 16;   // RNE
    return (u16)r;
}
__device__ inline float bf2f(u16 h) {
    unsigned int u = ((unsigned int)h) << 16;
    return __builtin_bit_cast(float, u);
}

// ---------------------------------------------------------------------------
// bf16x3 split MFMA GEMM, bx-major bijective XCD swizzle (A-tile L2-resident
// per XCD). reg->LDS staging. C = act(sum_k (Ah+Al)[m,k]*(Wh+Wl)[n,k] + bias).
// K mult of 32; lda/ldw mult 8. W must have gridDim.y*128 rows alloc (pads 0).
// OUT: 0 -> fp32 C; 1 -> split bf16 (Ch,Cl). ACT: 1 -> prelu(aptr).
// ---------------------------------------------------------------------------
template<int OUT, int ACT>
__global__ __launch_bounds__(256) void gemm_mfma3(
    const u16* __restrict__ Ah, const u16* __restrict__ Al, int lda,
    const u16* __restrict__ Wh, const u16* __restrict__ Wl, int ldw,
    float* __restrict__ C, u16* __restrict__ Ch, u16* __restrict__ Cl, int ldc,
    int M, int Nd, int K,
    const float* __restrict__ bias, const float* __restrict__ aptr)
{
    __shared__ u16 AtH[4][1024];
    __shared__ u16 AtL[4][1024];
    __shared__ u16 WtH[4][1024];
    __shared__ u16 WtL[4][1024];
    const int tid  = threadIdx.x;
    const int ny  = gridDim.y;
    const int nwg = gridDim.x * ny;
    const int lin = blockIdx.y * gridDim.x + blockIdx.x;
    const int q = nwg >> 3, r8 = nwg & 7;
    const int xcd = lin & 7, off = lin >> 3;
    const int swz = (xcd < r8) ? xcd * (q + 1) + off
                               : r8 * (q + 1) + (xcd - r8) * q + off;
    const int bm   = (swz / ny) * 128;
    const int bn   = (swz % ny) * 128;
    const int wv   = tid >> 6;
    const int lane = tid & 63;
    const int wr   = (wv >> 1) * 64;
    const int wc   = (wv & 1) * 64;
    const int l15  = lane & 15;
    const int kseg = lane >> 4;

    f32x4 acc[4][4];
    #pragma unroll
    for (int i = 0; i < 4; ++i)
        #pragma unroll
        for (int j = 0; j < 4; ++j) acc[i][j] = (f32x4){0.f,0.f,0.f,0.f};

    const int srow = tid & 127;
    const bool isA = (tid < 128);
    const int gr   = isA ? (bm + srow) : (bn + srow);
    const int glim = isA ? M : 0x7FFFFFFF;
    const u16* pHbase = (isA ? Ah : Wh) + (size_t)gr * (isA ? lda : ldw);
    const u16* pLbase = (isA ? Al : Wl) + (size_t)gr * (isA ? lda : ldw);
    u16* dH = isA ? &AtH[0][0] : &WtH[0][0];
    u16* dL = isA ? &AtL[0][0] : &WtL[0][0];

    for (int k0 = 0; k0 < K; k0 += 32) {
        __syncthreads();
        {
            const bool ok = (gr < glim);
            #pragma unroll
            for (int s = 0; s < 4; ++s) {
                bf16x8 vH = {0,0,0,0,0,0,0,0};
                bf16x8 vL = {0,0,0,0,0,0,0,0};
                if (ok) {
                    vH = *(const bf16x8*)(pHbase + k0 + s * 8);
                    vL = *(const bf16x8*)(pLbase + k0 + s * 8);
                }
                *(bf16x8*)(dH + s * 1024 + srow * 8) = vH;
                *(bf16x8*)(dL + s * 1024 + srow * 8) = vL;
            }
        }
        __syncthreads();
        bf16x8 aH[4], aL[4], bH[4], bL[4];
        #pragma unroll
        for (int f = 0; f < 4; ++f) {
            int ar = wr + f * 16 + l15;
            int br = wc + f * 16 + l15;
            aH[f] = *(const bf16x8*)&AtH[kseg][ar * 8];
            aL[f] = *(const bf16x8*)&AtL[kseg][ar * 8];
            bH[f] = *(const bf16x8*)&WtH[kseg][br * 8];
            bL[f] = *(const bf16x8*)&WtL[kseg][br * 8];
        }
        #pragma unroll
        for (int i = 0; i < 4; ++i)
            #pragma unroll
            for (int j = 0; j < 4; ++j)
                acc[i][j] = __builtin_amdgcn_mfma_f32_16x16x32_bf16(aH[i], bH[j], acc[i][j], 0, 0, 0);
        #pragma unroll
        for (int i = 0; i < 4; ++i)
            #pragma unroll
            for (int j = 0; j < 4; ++j)
                acc[i][j] = __builtin_amdgcn_mfma_f32_16x16x32_bf16(aH[i], bL[j], acc[i][j], 0, 0, 0);
        #pragma unroll
        for (int i = 0; i < 4; ++i)
            #pragma unroll
            for (int j = 0; j < 4; ++j)
                acc[i][j] = __builtin_amdgcn_mfma_f32_16x16x32_bf16(aL[i], bH[j], acc[i][j], 0, 0, 0);
    }

    const float av = (ACT == 1) ? *aptr : 0.f;
    const int r4 = (lane >> 4) * 4;
    #pragma unroll
    for (int j = 0; j < 4; ++j) {
        int col = bn + wc + j * 16 + l15;
        if (col >= Nd) continue;
        float bv = bias ? bias[col] : 0.f;
        #pragma unroll
        for (int i = 0; i < 4; ++i) {
            #pragma unroll
            for (int rr = 0; rr < 4; ++rr) {
                int row = bm + wr + i * 16 + r4 + rr;
                if (row >= M) continue;
                float v = acc[i][j][rr] + bv;
                if (ACT == 1) v = (v >= 0.f) ? v : av * v;
                if (OUT == 0) {
                    C[(size_t)row * ldc + col] = v;
                } else {
                    u16 h = f2bf(v);
                    Ch[(size_t)row * ldc + col] = h;
                    Cl[(size_t)row * ldc + col] = f2bf(v - bf2f(h));
                }
            }
        }
    }
}

// ---------------------------------------------------------------------------
// split fp32 -> bf16 hi/lo, vectorized: 4 rows/block, 8 cols/thread.
// ---------------------------------------------------------------------------
__global__ __launch_bounds__(256) void split_rows8(
    const float* __restrict__ src, int srcld,
    int pmask, int pmul1, int pshift, int pmul2, int padd,
    u16* __restrict__ dstH, u16* __restrict__ dstL, int dstld,
    int wcols, int validK, int validRows)
{
    const int r = blockIdx.y * 4 + (threadIdx.x >> 6);
    const int c = (blockIdx.x * 64 + (threadIdx.x & 63)) * 8;
    if (c >= wcols) return;
    const int sr = (r & pmask) * pmul1 + (r >> pshift) * pmul2 + padd;
    const float* s = src + (size_t)sr * srcld;
    const bool rok = (r < validRows);
    float v[8];
    if (rok && c + 8 <= validK) {
        *(float4*)&v[0] = *(const float4*)(s + c);
        *(float4*)&v[4] = *(const float4*)(s + c + 4);
    } else {
        #pragma unroll
        for (int u = 0; u < 8; ++u) v[u] = (rok && c + u < validK) ? s[c + u] : 0.f;
    }
    bf16x8 H8, L8;
    #pragma unroll
    for (int u = 0; u < 8; ++u) {
        u16 h = f2bf(v[u]);
        H8[u] = (short)h;
        L8[u] = (short)f2bf(v[u] - bf2f(h));
    }
    *(bf16x8*)(dstH + (size_t)r * dstld + c) = H8;
    *(bf16x8*)(dstL + (size_t)r * dstld + c) = L8;
}

// biasP[n'] = b_ih[orig]+b_hh[orig], orig = (n'&3)*600+(n'>>2)
__global__ __launch_bounds__(256) void bias_perm(
    const float* __restrict__ bih, const float* __restrict__ bhh, float* __restrict__ dst)
{
    int n = blockIdx.x * 256 + threadIdx.x;
    if (n >= 4 * LHdim) return;
    int o = (n & 3) * LHdim + (n >> 2);
    dst[n] = bih[o] + bhh[o];
}

// Wr2f[l][r][c]: r<300 -> wr0[l][r][c], else wr1[l][r-300][c]
__global__ __launch_bounds__(256) void wr_cat(
    const float* __restrict__ wr0, const float* __restrict__ wr1, float* __restrict__ dst)
{
    int c = blockIdx.x * 256 + threadIdx.x;
    if (c >= HDdim) return;
    int lr = blockIdx.y;
    int l = lr / (2 * HDdim), r = lr % (2 * HDdim);
    const float* src = (r < HDdim)
        ? wr0 + ((size_t)l * HDdim + r) * HDdim
        : wr1 + ((size_t)l * HDdim + (r - HDdim)) * HDdim;
    dst[(size_t)lr * HDdim + c] = src[c];
}

__global__ __launch_bounds__(256) void zero_range(float* __restrict__ p, int n)
{
    int i = blockIdx.x * 256 + threadIdx.x;
    if (i < n) p[i] = 0.f;
}

// ---------------------------------------------------------------------------
__global__ __launch_bounds__(256) void norm_kernel(const float* __restrict__ f, float* __restrict__ invn)
{
    int row  = blockIdx.x * 4 + (threadIdx.x >> 6);
    int lane = threadIdx.x & 63;
    const float* fr = f + (size_t)row * Edim;
    float ss = 0.f;
    for (int t = lane; t < Edim; t += 64) { float v = fr[t]; ss = fmaf(v, v, ss); }
    #pragma unroll
    for (int o = 32; o > 0; o >>= 1) ss += __shfl_down(ss, o);
    if (lane == 0) invn[row] = 1.f / (sqrtf(ss) + 1e-8f);
}

__global__ __launch_bounds__(256) void simadj_kernel(
    const float* __restrict__ f, const float* __restrict__ invn,
    const float* __restrict__ entro, const float* __restrict__ alphap,
    const float* __restrict__ thrp, uint8_t* __restrict__ adj)
{
    int b = blockIdx.x;
    __shared__ float S[16][100];
    int tid = threadIdx.x;
    int i0 = (tid >> 4) * 6, j0 = (tid & 15) * 6;
    float acc[6][6];
    #pragma unroll
    for (int i = 0; i < 6; ++i)
        #pragma unroll
        for (int j = 0; j < 6; ++j) acc[i][j] = 0.f;
    const float* fb = f + (size_t)b * Ndim * Edim;

    for (int k0 = 0; k0 < Edim; k0 += 16) {
        __syncthreads();
        #pragma unroll
        for (int r = 0; r < 6; ++r) {
            int n = (tid >> 4) + r * 16;
            S[tid & 15][n] = fb[(size_t)n * Edim + k0 + (tid & 15)];
        }
        __syncthreads();
        #pragma unroll
        for (int kk = 0; kk < 16; ++kk) {
            float a[6], bb[6];
            #pragma unroll
            for (int u = 0; u < 6; ++u) a[u] = S[kk][i0 + u];
            #pragma unroll
            for (int u = 0; u < 6; ++u) bb[u] = S[kk][j0 + u];
            #pragma unroll
            for (int i = 0; i < 6; ++i)
                #pragma unroll
                for (int j = 0; j < 6; ++j)
                    acc[i][j] = fmaf(a[i], bb[j], acc[i][j]);
        }
    }

    float alpha = *alphap, thr = *thrp;
    float onem = 1.f - alpha;
    #pragma unroll
    for (int i = 0; i < 6; ++i) {
        int ii = i0 + i;
        float inv_i = invn[b * Ndim + ii];
        #pragma unroll
        for (int j = 0; j < 6; ++j) {
            int jj = j0 + j;
            float simv = acc[i][j] * inv_i * invn[b * Ndim + jj];
            float comb = alpha * entro[b * Ndim + jj] + onem * simv;
            adj[((size_t)b * Ndim + ii) * Ndim + jj] = (comb > thr) ? 1 : 0;
        }
    }
}

// k[r] = H[r,:300] . wk   (q cancels in the adjacency softmax; not computed)
__global__ __launch_bounds__(256) void k_kernel(
    const float* __restrict__ Hsrc, const float* __restrict__ wk,
    float* __restrict__ k)
{
    int row  = blockIdx.x * 4 + (threadIdx.x >> 6);
    int lane = threadIdx.x & 63;
    const float* h = Hsrc + (size_t)row * GDdim;
    float sk = 0.f;
    for (int t = lane; t < HDdim; t += 64) sk = fmaf(h[t], wk[t], sk);
    #pragma unroll
    for (int o = 32; o > 0; o >>= 1) sk += __shfl_down(sk, o);
    if (lane == 0) k[row] = sk;
}

// ---------------------------------------------------------------------------
// Fused GAT attention for one batch b (q, gat_b cancel in softmax).
// V combined: cols 0..299 = V0, 300..599 = V1, row stride 600 (n-major rows).
// ---------------------------------------------------------------------------
__global__ __launch_bounds__(256) void gat_fused(
    const float* __restrict__ kbuf, const uint8_t* __restrict__ adj,
    const int* __restrict__ smask,
    const float* __restrict__ V,
    float* __restrict__ Mout)
{
    __shared__ float P0[96][98];
    __shared__ float P1[96][98];
    __shared__ float Vs0[96][96];
    __shared__ float Vs1[96][96];
    __shared__ float ek[96];
    __shared__ float rden[96];
    __shared__ float red[256];
    const int b = blockIdx.x;
    const int tid = threadIdx.x;

    float kj = (tid < Ndim) ? kbuf[tid * Bdim + b] : -1e30f;
    red[tid] = kj;
    __syncthreads();
    #pragma unroll
    for (int s = 128; s > 0; s >>= 1) {
        if (tid < s) red[tid] = fmaxf(red[tid], red[tid + s]);
        __syncthreads();
    }
    float kmax = red[0];
    if (tid < Ndim) ek[tid] = expf(kj - kmax);
    __syncthreads();
    if (tid < Ndim) {
        const uint8_t* ar = adj + ((size_t)b * Ndim + tid) * Ndim;
        float s = 0.f;
        for (int j = 0; j < Ndim; ++j) if (ar[j]) s += ek[j];
        rden[tid] = 1.f / s;   // diagonal always allowed -> s > 0
    }
    __syncthreads();
    for (int idx = tid; idx < Ndim * Ndim; idx += 256) {
        int i = idx / Ndim, j = idx - i * Ndim;
        float a = adj[((size_t)b * Ndim + i) * Ndim + j] ? ek[j] * rden[i] : 0.f;
        int s = smask[((size_t)b * Ndim + i) * Ndim + j];
        P0[i][j] = s ? a : 0.f;
        P1[i][j] = s ? 0.f : a;
    }
    __syncthreads();

    const int ti = tid >> 4, td = tid & 15;
    const int i0 = ti * 6, dbase = td * 6;
    for (int p = 0; p < 4; ++p) {
        const int d0 = p * 96;
        const int dw = (p == 3) ? (HDdim - 288) : 96;
        for (int idx = tid; idx < 96 * 24; idx += 256) {
            int j = idx / 24, q4 = (idx - j * 24) * 4;
            if (q4 < dw) {
                size_t g = ((size_t)(j * Bdim + b)) * (2 * HDdim) + d0 + q4;
                *(float4*)&Vs0[j][q4] = *(const float4*)(V + g);
                *(float4*)&Vs1[j][q4] = *(const float4*)(V + g + HDdim);
            }
        }
        __syncthreads();
        float acc[6][6];
        #pragma unroll
        for (int ii = 0; ii < 6; ++ii)
            #pragma unroll
            for (int dd = 0; dd < 6; ++dd) acc[ii][dd] = 0.f;
        for (int j = 0; j < Ndim; j += 2) {
            float2 pa[6], pb[6];
            #pragma unroll
            for (int ii = 0; ii < 6; ++ii) {
                pa[ii] = *(const float2*)&P0[i0 + ii][j];
                pb[ii] = *(const float2*)&P1[i0 + ii][j];
            }
            float2 v0a[3], v0b[3], v1a[3], v1b[3];
            #pragma unroll
            for (int dd = 0; dd < 3; ++dd) {
                v0a[dd] = *(const float2*)&Vs0[j][dbase + 2 * dd];
                v0b[dd] = *(const float2*)&Vs0[j + 1][dbase + 2 * dd];
                v1a[dd] = *(const float2*)&Vs1[j][dbase + 2 * dd];
                v1b[dd] = *(const float2*)&Vs1[j + 1][dbase + 2 * dd];
            }
            #pragma unroll
            for (int ii = 0; ii < 6; ++ii)
                #pragma unroll
                for (int dd = 0; dd < 3; ++dd) {
                    acc[ii][2*dd]   += pa[ii].x * v0a[dd].x + pb[ii].x * v1a[dd].x
                                     + pa[ii].y * v0b[dd].x + pb[ii].y * v1b[dd].x;
                    acc[ii][2*dd+1] += pa[ii].x * v0a[dd].y + pb[ii].x * v1a[dd].y
                                     + pa[ii].y * v0b[dd].y + pb[ii].y * v1b[dd].y;
                }
        }
        __syncthreads();
        #pragma unroll
        for (int ii = 0; ii < 6; ++ii) {
            #pragma unroll
            for (int dd = 0; dd < 6; ++dd) {
                int d = dbase + dd;
                if (d < dw)
                    Mout[((size_t)((i0 + ii) * Bdim + b)) * GDdim + d0 + d] = acc[ii][dd];
            }
        }
    }
}

// ---------------------------------------------------------------------------
// Per-step LSTM (round-13 proven: double-buffered LDS, one barrier per
// k-chunk) + T14 async-split + Hlstm-slice ping-pong (round 15 verified).
// Tile 32 batch x 64 gate-cols, grid (8,38).
// ---------------------------------------------------------------------------
__global__ __launch_bounds__(256) void lstm_mfma3(
    const u16* __restrict__ hH, const u16* __restrict__ hL,
    const float* __restrict__ cin,
    const u16* __restrict__ WH, const u16* __restrict__ WL,   // (2432 x 608)
    const float* __restrict__ zt,
    u16* __restrict__ hHo, u16* __restrict__ hLo,
    float* __restrict__ cout)
{
    __shared__ u16 AsH[2][4][256];
    __shared__ u16 AsL[2][4][256];
    __shared__ u16 WsH[2][4][512];
    __shared__ u16 WsL[2][4][512];
    __shared__ __align__(16) float gates[32][68];
    const int tid = threadIdx.x;
    const int bm = blockIdx.x * 32;
    const int bn = blockIdx.y * 64;
    const int wv = tid >> 6;
    const int lane = tid & 63;
    const int l15 = lane & 15;
    const int kseg = lane >> 4;
    const float4 fz = make_float4(0.f, 0.f, 0.f, 0.f);

    // --- T14: issue cell-phase loads NOW; consumed after the k-loop ---
    const int prow0 = tid >> 4,        pui0 = tid & 15;
    const int prow1 = (tid + 256) >> 4, pui1 = tid & 15;     // cell1 = tid+256
    const int pn0 = bn + pui0 * 4,  pn1 = bn + pui1 * 4;
    const int pu0 = pn0 >> 2,       pu1 = pn1 >> 2;
    const bool ok0 = (pu0 < LHdim), ok1 = (pu1 < LHdim);
    const int bb0 = bm + prow0,     bb1 = bm + prow1;
    float4 z0 = ok0 ? *(const float4*)(zt + (size_t)bb0 * (4 * LHdim) + pn0) : fz;
    float4 z1 = ok1 ? *(const float4*)(zt + (size_t)bb1 * (4 * LHdim) + pn1) : fz;
    float ci0 = ok0 ? cin[bb0 * LHdim + pu0] : 0.f;
    float ci1 = ok1 ? cin[bb1 * LHdim + pu1] : 0.f;

    // A staging: tid<128 -> AsH, else AsL; each thread one bf16x8
    const int av = tid & 127;
    const int arow = av >> 2, akc = av & 3;
    const u16* asrc = ((tid < 128) ? hH : hL) + (size_t)(bm + arow) * 608 + akc * 8;
    const int aoff = akc * 256 + arow * 8;
    // W staging: each thread one bf16x8 of WsH and WsL
    const int wrow = tid >> 2, wkc = tid & 3;
    const u16* wsrcH = WH + (size_t)(bn + wrow) * 608 + wkc * 8;
    const u16* wsrcL = WL + (size_t)(bn + wrow) * 608 + wkc * 8;
    const int woff2 = wrow * 8;

    f32x4 acc[2];
    acc[0] = (f32x4){0.f,0.f,0.f,0.f};
    acc[1] = (f32x4){0.f,0.f,0.f,0.f};

    // preload chunk 0
    bf16x8 ra  = *(const bf16x8*)(asrc);
    bf16x8 rwh = *(const bf16x8*)(wsrcH);
    bf16x8 rwl = *(const bf16x8*)(wsrcL);

    #pragma unroll
    for (int kc = 0; kc < 19; ++kc) {
        const int buf = kc & 1;
        *(bf16x8*)(((tid < 128) ? &AsH[buf][0][0] : &AsL[buf][0][0]) + aoff) = ra;
        *(bf16x8*)(&WsH[buf][wkc][woff2]) = rwh;
        *(bf16x8*)(&WsL[buf][wkc][woff2]) = rwl;
        if (kc + 1 < 19) {                      // prefetch next chunk
            ra  = *(const bf16x8*)(asrc + (kc + 1) * 32);
            rwh = *(const bf16x8*)(wsrcH + (kc + 1) * 32);
            rwl = *(const bf16x8*)(wsrcL + (kc + 1) * 32);
        }
        __syncthreads();                        // single barrier per chunk
        bf16x8 aH[2], aL[2], bH, bL;
        #pragma unroll
        for (int i = 0; i < 2; ++i) {
            int arr = i * 16 + l15;
            aH[i] = *(const bf16x8*)&AsH[buf][kseg][arr * 8];
            aL[i] = *(const bf16x8*)&AsL[buf][kseg][arr * 8];
        }
        {
            int br = wv * 16 + l15;
            bH = *(const bf16x8*)&WsH[buf][kseg][br * 8];
            bL = *(const bf16x8*)&WsL[buf][kseg][br * 8];
        }
        #pragma unroll
        for (int i = 0; i < 2; ++i) {
            acc[i] = __builtin_amdgcn_mfma_f32_16x16x32_bf16(aH[i], bH, acc[i], 0, 0, 0);
            acc[i] = __builtin_amdgcn_mfma_f32_16x16x32_bf16(aH[i], bL, acc[i], 0, 0, 0);
            acc[i] = __builtin_amdgcn_mfma_f32_16x16x32_bf16(aL[i], bH, acc[i], 0, 0, 0);
        }
    }

    const int r4 = (lane >> 4) * 4;
    __syncthreads();
    #pragma unroll
    for (int i = 0; i < 2; ++i)
        #pragma unroll
        for (int rr = 0; rr < 4; ++rr)
            gates[i * 16 + r4 + rr][wv * 16 + l15] = acc[i][rr];
    __syncthreads();

    // fused cell: 2 cells per thread, using prefetched z/c
    if (ok0) {
        float4 g = *(const float4*)&gates[prow0][pui0 * 4];
        float gi = g.x + z0.x;
        float gf = g.y + z0.y;
        float gg = g.z + z0.z;
        float go = g.w + z0.w;
        float si = 1.f / (1.f + expf(-gi));
        float sf = 1.f / (1.f + expf(-gf));
        float so = 1.f / (1.f + expf(-go));
        float cn = sf * ci0 + si * tanhf(gg);
        float hn = so * tanhf(cn);
        cout[bb0 * LHdim + pu0] = cn;
        u16 hh = f2bf(hn);
        hHo[(size_t)bb0 * 608 + pu0] = hh;
        hLo[(size_t)bb0 * 608 + pu0] = f2bf(hn - bf2f(hh));
    }
    if (ok1) {
        float4 g = *(const float4*)&gates[prow1][pui1 * 4];
        float gi = g.x + z1.x;
        float gf = g.y + z1.y;
        float gg = g.z + z1.z;
        float go = g.w + z1.w;
        float si = 1.f / (1.f + expf(-gi));
        float sf = 1.f / (1.f + expf(-gf));
        float so = 1.f / (1.f + expf(-go));
        float cn = sf * ci1 + si * tanhf(gg);
        float hn = so * tanhf(cn);
        cout[bb1 * LHdim + pu1] = cn;
        u16 hh = f2bf(hn);
        hHo[(size_t)bb1 * 608 + pu1] = hh;
        hLo[(size_t)bb1 * 608 + pu1] = f2bf(hn - bf2f(hh));
    }
}

__global__ __launch_bounds__(256) void out_kernel(
    const float* __restrict__ x, int ldx, const float* __restrict__ ow,
    const float* __restrict__ ob, float* __restrict__ out)
{
    int r    = blockIdx.x * 4 + (threadIdx.x >> 6);
    int lane = threadIdx.x & 63;
    const float* xr = x + (size_t)r * ldx;
    float acc[NCdim];
    #pragma unroll
    for (int n = 0; n < NCdim; ++n) acc[n] = 0.f;
    for (int t = lane; t < HDdim; t += 64) {
        float xv = xr[t];
        #pragma unroll
        for (int n = 0; n < NCdim; ++n) acc[n] = fmaf(xv, ow[n * HDdim + t], acc[n]);
    }
    #pragma unroll
    for (int o = 32; o > 0; o >>= 1)
        #pragma unroll
        for (int n = 0; n < NCdim; ++n) acc[n] += __shfl_down(acc[n], o);
    if (lane == 0) {
        int b = r & 255, nn = r >> 8;
        #pragma unroll
        for (int n = 0; n < NCdim; ++n) out[((size_t)b * Ndim + nn) * NCdim + n] = acc[n] + ob[n];
    }
}

// ---------------------------------------------------------------------------
extern "C" void kernel_launch(void* const* d_in, const int* in_sizes, int n_in,
                              void* d_out, int out_size, void* d_ws, size_t ws_size,
                              hipStream_t stream)
{
    const float*  features  = (const float*)d_in[0];
    const int*    s_mask    = (const int*)  d_in[1];
    const float*  entro     = (const float*)d_in[2];
    const float*  alpha     = (const float*)d_in[3];
    const float*  threshold = (const float*)d_in[4];
    const float*  fc1_w     = (const float*)d_in[5];
    const float*  fc1_b     = (const float*)d_in[6];
    const float*  gat_w     = (const float*)d_in[7];
    const float*  gat_b     = (const float*)d_in[8];
    const float*  wr0       = (const float*)d_in[9];
    const float*  wr1       = (const float*)d_in[10];
    const float*  enhance_w = (const float*)d_in[11];
    const float*  enhance_b = (const float*)d_in[12];
    const float*  prelu_a   = (const float*)d_in[13];
    const float*  lstm_w_ih = (const float*)d_in[14];
    const float*  lstm_w_hh = (const float*)d_in[15];
    const float*  lstm_b_ih = (const float*)d_in[16];
    const float*  lstm_b_hh = (const float*)d_in[17];
    const float*  mlp_w0    = (const float*)d_in[18];
    const float*  mlp_b0    = (const float*)d_in[19];
    const float*  mlp_a0    = (const float*)d_in[20];
    const float*  mlp_w1    = (const float*)d_in[21];
    const float*  mlp_b1    = (const float*)d_in[22];
    const float*  mlp_a1    = (const float*)d_in[23];
    const float*  out_w     = (const float*)d_in[24];
    const float*  out_b     = (const float*)d_in[25];
    float* out = (float*)d_out;
    char* ws = (char*)d_ws;
    (void)gat_b;

    // ---- fixed workspace layout (bytes, 256-aligned) ----
    uint8_t* adj   = (uint8_t*)(ws + 0);               //  2,359,296
    float*   invn  = (float*)(ws + 2359296);
    float*   kbuf  = (float*)(ws + 2555904);
    float*   biasP = (float*)(ws + 2654208);
    float*   c0    = (float*)(ws + 2663936);           //    614,400
    float*   c1    = (float*)(ws + 3278336);
    u16*     WhhPH = (u16*)(ws + 5137920);             //  2,957,312 (2432 x 608)
    u16*     WhhPL = (u16*)(ws + 8095232);
    u16*     WihPH = (u16*)(ws + 11052544);            //  9,494,528 (2432 x 1952)
    u16*     WihPL = (u16*)(ws + 20547072);
    u16*     EwH   = (u16*)(ws + 30041600);            //  2,097,152 (1024 x 1024)
    u16*     EwL   = (u16*)(ws + 32138752);
    u16*     Fc1H  = (u16*)(ws + 34235904);            //    786,432 (384 x 1024)
    u16*     Fc1L  = (u16*)(ws + 35022336);
    float*   Wr2f  = (float*)(ws + 35808768);          //  1,440,256 (2 x 600 x 300)
    u16*     Wr2H  = (u16*)(ws + 37249024);            //    819,200 (2 x 640 x 320)
    u16*     Wr2L  = (u16*)(ws + 38068224);
    u16*     Wm0H  = (u16*)(ws + 38887424);            //    524,288 (384 x 608)
    u16*     Wm0L  = (u16*)(ws + 39411712);
    u16*     Wm1H  = (u16*)(ws + 39936000);            //    262,144 (384 x 320)
    u16*     Wm1L  = (u16*)(ws + 40198144);
    u16*     FfH   = (u16*)(ws + 40460288);            // 50,331,648 (ROWS x 1024)
    u16*     FfL   = (u16*)(ws + 90791936);
    float*   Hcat  = (float*)(ws + 141123584);         // 88,473,600 (ROWS,900) n-major
    u16*     HsH   = (u16*)(ws + 229597184);           // 15,728,640 (ROWS x 320)
    u16*     HsL   = (u16*)(ws + 245325824);
    // V (GAT, fp32 ROWSx600) aliases Hlstm (97 slices x 256 x 608 split bf16)
    float*   V      = (float*)(ws + 261054464);        // 58,982,400
    u16*     HlstmH = (u16*)(ws + 261054464);          // 30,195,712 (97 slices)
    u16*     HlstmL = (u16*)(ws + 291250176);          // 30,195,712 -> 321,445,888
    // MLP scratch aliases Hcat (dead after last Hcat split)
    u16*     x1H   = (u16*)Hcat;                       // 15,728,640 (ROWS x 320)
    u16*     x1L   = (u16*)(ws + 141123584 + 15728640);
    float*   x2    = (float*)(ws + 141123584 + 31457280);   // 29,884,416 (ROWS x 304)

    // ---- tier selection for chunked seq/zin region ----
    const size_t fixedNeed = 321445888ull;
    const size_t perT = 4456448ull;                    // zin(2,457,600)+seqH/L(1,998,848)
    int T;
    if      (ws_size >= fixedNeed + 96ull * perT) T = 96;
    else if (ws_size >= fixedNeed + 48ull * perT) T = 48;
    else if (ws_size >= fixedNeed + 32ull * perT) T = 32;
    else if (ws_size >= fixedNeed + 16ull * perT) T = 16;
    else if (ws_size >= fixedNeed +  8ull * perT) T = 8;
    else return;                                       // visible failure, no OOB
    char* cr = ws + fixedNeed;
    float* zin  = (float*)cr;                                // (Mc,2400)
    u16*   seqH = (u16*)(cr + (size_t)T * 2457600);          // (Mc,1952)
    u16*   seqL = (u16*)(cr + (size_t)T * 2457600 + (size_t)T * 999424);

    // 1) norms + adjacency
    norm_kernel<<<ROWS / 4, 256, 0, stream>>>(features, invn);
    simadj_kernel<<<Bdim, 256, 0, stream>>>(features, invn, entro, alpha, threshold, adj);

    // 2) weight/activation conversions
    split_rows8<<<dim3(2, ROWS / 4), 256, 0, stream>>>(            // features n-major full
        features, Edim, 255, Ndim, 8, 1, 0, FfH, FfL, Edim, Edim, Edim, ROWS);
    split_rows8<<<dim3(2, 96), 256, 0, stream>>>(                  // fc1_w (384x1024)
        fc1_w, Edim, IDP, Fc1H, Fc1L, Edim, Edim, Edim, HDdim);
    split_rows8<<<dim3(2, 256), 256, 0, stream>>>(                 // enhance_w
        enhance_w, Edim, IDP, EwH, EwL, Edim, Edim, Edim, Edim);
    split_rows8<<<dim3(4, 608), 256, 0, stream>>>(                 // Wih gate-interleaved
        lstm_w_ih, Edim + GDdim, 3, LHdim, 2, 1, 0, WihPH, WihPL, 1952, 1952, 1924, 2400);
    split_rows8<<<dim3(2, 608), 256, 0, stream>>>(                 // Whh gate-interleaved
        lstm_w_hh, LHdim, 3, LHdim, 2, 1, 0, WhhPH, WhhPL, 608, 608, LHdim, 2400);
    split_rows8<<<dim3(2, 96), 256, 0, stream>>>(                  // mlp_w0 (384x608)
        mlp_w0, LHdim, IDP, Wm0H, Wm0L, 608, 608, LHdim, HDdim);
    split_rows8<<<dim3(1, 96), 256, 0, stream>>>(                  // mlp_w1 (384x320)
        mlp_w1, HDdim, IDP, Wm1H, Wm1L, 320, 320, HDdim, HDdim);
    wr_cat<<<dim3(2, 2 * Ldim * HDdim), 256, 0, stream>>>(wr0, wr1, Wr2f);
    for (int l = 0; l < Ldim; ++l)
        split_rows8<<<dim3(1, 160), 256, 0, stream>>>(             // Wr2 (640x320 per layer)
            Wr2f + (size_t)l * 2 * HDdim * HDdim, HDdim, IDP,
            Wr2H + (size_t)l * 640 * 320, Wr2L + (size_t)l * 640 * 320,
            320, 320, HDdim, 2 * HDdim);
    bias_perm<<<10, 256, 0, stream>>>(lstm_b_ih, lstm_b_hh, biasP);
    zero_range<<<1200, 256, 0, stream>>>(c0, 307200);              // c0, c1

    // 3) H0 = prelu(features @ fc1_w^T + fc1_b) -> Hcat[:, 0:300] (MFMA)
    gemm_mfma3<0,1><<<dim3(ROWS/128, 3), 256, 0, stream>>>(
        FfH, FfL, Edim, Fc1H, Fc1L, Edim,
        Hcat, nullptr, nullptr, GDdim, ROWS, HDdim, Edim, fc1_b, prelu_a);

    // 4) GAT layers (MFMA V projection, fused softmax+aggregation)
    for (int l = 0; l < Ldim; ++l) {
        const float* Hsrc = Hcat + l * HDdim;
        k_kernel<<<ROWS / 4, 256, 0, stream>>>(Hsrc, gat_w + l * 2 * HDdim + HDdim, kbuf);
        split_rows8<<<dim3(1, ROWS / 4), 256, 0, stream>>>(        // Hsrc -> split (K=320)
            Hsrc, GDdim, IDP, HsH, HsL, 320, 320, HDdim, ROWS);
        gemm_mfma3<0,0><<<dim3(ROWS/128, 5), 256, 0, stream>>>(
            HsH, HsL, 320, Wr2H + (size_t)l * 640 * 320, Wr2L + (size_t)l * 640 * 320, 320,
            V, nullptr, nullptr, 2 * HDdim, ROWS, 2 * HDdim, 320, nullptr, nullptr);
        gat_fused<<<Bdim, 256, 0, stream>>>(
            kbuf, adj, s_mask, V, Hcat + (l + 1) * HDdim);
    }

    // 5) zero Hlstm split region (pads + slice 0 = h_0; aliased V until now)
    zero_range<<<58976, 256, 0, stream>>>((float*)HlstmH, 15097856);

    // 6) chunked: enhance MFMA -> Hcat split -> zin MFMA -> per-step LSTM
    int cur = 0;
    float* cb_[2] = {c0, c1};
    for (int t0 = 0; t0 < Ndim; t0 += T) {
        int Mc = T * Bdim;
        gemm_mfma3<1,1><<<dim3(Mc/128, 8), 256, 0, stream>>>(
            FfH + (size_t)t0 * Bdim * Edim, FfL + (size_t)t0 * Bdim * Edim, Edim,
            EwH, EwL, Edim,
            nullptr, seqH, seqL, 1952, Mc, Edim, Edim, enhance_b, prelu_a);
        split_rows8<<<dim3(2, Mc / 4), 256, 0, stream>>>(
            Hcat, GDdim, 0x7FFFFFFF, 1, 30, 0, t0 * Bdim,
            seqH + 1024, seqL + 1024, 1952, 928, GDdim, Mc);
        gemm_mfma3<0,0><<<dim3(Mc/128, 19), 256, 0, stream>>>(
            seqH, seqL, 1952, WihPH, WihPL, 1952,
            zin, nullptr, nullptr, 4 * LHdim, Mc, 4 * LHdim, 1952, biasP, nullptr);
        for (int tl = 0; tl < T; ++tl) {
            const int g = t0 + tl;                    // global step, 0-based
            lstm_mfma3<<<dim3(8, 38), 256, 0, stream>>>(
                HlstmH + (size_t)g * HSLICE, HlstmL + (size_t)g * HSLICE,
                cb_[cur], WhhPH, WhhPL,
                zin + (size_t)tl * Bdim * 4 * LHdim,
                HlstmH + (size_t)(g + 1) * HSLICE, HlstmL + (size_t)(g + 1) * HSLICE,
                cb_[cur ^ 1]);
            cur ^= 1;
        }
    }

    // 7) MLP head (MFMA, A = Hlstm slices 1..96) + output
    zero_range<<<30720, 256, 0, stream>>>((float*)x1H, 7864320);   // x1 pads must be 0
    gemm_mfma3<1,1><<<dim3(ROWS/128, 3), 256, 0, stream>>>(
        HlstmH + HSLICE, HlstmL + HSLICE, 608, Wm0H, Wm0L, 608,
        nullptr, x1H, x1L, 320, ROWS, HDdim, 608, mlp_b0, mlp_a0);
    gemm_mfma3<0,1><<<dim3(ROWS/128, 3), 256, 0, stream>>>(
        x1H, x1L, 320, Wm1H, Wm1L, 320,
        x2, nullptr, nullptr, 304, ROWS, HDdim, 320, mlp_b1, mlp_a1);
    out_kernel<<<ROWS / 4, 256, 0, stream>>>(x2, 304, out_w, out_b, out);
}

// Round 18
// 3325.932 us; speedup vs baseline: 1.3944x; 1.2159x over previous
//
#include <hip/hip_runtime.h>
#include <cstdint>
#include <cstddef>

#define Bdim 256
#define Ndim 96
#define Edim 1024
#define HDdim 300
#define Ldim 2
#define LHdim 600
#define NCdim 7
#define GDdim 900              // HD*(L+1)
#define ROWS (Bdim*Ndim)       // 24576
#define HSLICE 155648          // 256*608 elements per Hlstm time-slice

typedef unsigned short u16;
typedef float f32x4 __attribute__((ext_vector_type(4)));
typedef short bf16x8 __attribute__((ext_vector_type(8)));

// Identity row-perm constants
#define IDP 0x7FFFFFFF, 1, 30, 0, 0

__device__ inline u16 f2bf(float x) {
    unsigned int u = __builtin_bit_cast(unsigned int, x);
    unsigned int r = (u + 0x7fffu + ((u >> 16) & 1u)) >> 16;   // RNE
    return (u16)r;
}
__device__ inline float bf2f(u16 h) {
    unsigned int u = ((unsigned int)h) << 16;
    return __builtin_bit_cast(float, u);
}

// ---------------------------------------------------------------------------
// bf16x3 split MFMA GEMM, bx-major bijective XCD swizzle (A-tile L2-resident
// per XCD). reg->LDS staging. C = act(sum_k (Ah+Al)[m,k]*(Wh+Wl)[n,k] + bias).
// K mult of 32; lda/ldw mult 8. W must have gridDim.y*128 rows alloc (pads 0).
// OUT: 0 -> fp32 C; 1 -> split bf16 (Ch,Cl). ACT: 1 -> prelu(aptr).
// ---------------------------------------------------------------------------
template<int OUT, int ACT>
__global__ __launch_bounds__(256) void gemm_mfma3(
    const u16* __restrict__ Ah, const u16* __restrict__ Al, int lda,
    const u16* __restrict__ Wh, const u16* __restrict__ Wl, int ldw,
    float* __restrict__ C, u16* __restrict__ Ch, u16* __restrict__ Cl, int ldc,
    int M, int Nd, int K,
    const float* __restrict__ bias, const float* __restrict__ aptr)
{
    __shared__ u16 AtH[4][1024];
    __shared__ u16 AtL[4][1024];
    __shared__ u16 WtH[4][1024];
    __shared__ u16 WtL[4][1024];
    const int tid  = threadIdx.x;
    const int ny  = gridDim.y;
    const int nwg = gridDim.x * ny;
    const int lin = blockIdx.y * gridDim.x + blockIdx.x;
    const int q = nwg >> 3, r8 = nwg & 7;
    const int xcd = lin & 7, off = lin >> 3;
    const int swz = (xcd < r8) ? xcd * (q + 1) + off
                               : r8 * (q + 1) + (xcd - r8) * q + off;
    const int bm   = (swz / ny) * 128;
    const int bn   = (swz % ny) * 128;
    const int wv   = tid >> 6;
    const int lane = tid & 63;
    const int wr   = (wv >> 1) * 64;
    const int wc   = (wv & 1) * 64;
    const int l15  = lane & 15;
    const int kseg = lane >> 4;

    f32x4 acc[4][4];
    #pragma unroll
    for (int i = 0; i < 4; ++i)
        #pragma unroll
        for (int j = 0; j < 4; ++j) acc[i][j] = (f32x4){0.f,0.f,0.f,0.f};

    const int srow = tid & 127;
    const bool isA = (tid < 128);
    const int gr   = isA ? (bm + srow) : (bn + srow);
    const int glim = isA ? M : 0x7FFFFFFF;
    const u16* pHbase = (isA ? Ah : Wh) + (size_t)gr * (isA ? lda : ldw);
    const u16* pLbase = (isA ? Al : Wl) + (size_t)gr * (isA ? lda : ldw);
    u16* dH = isA ? &AtH[0][0] : &WtH[0][0];
    u16* dL = isA ? &AtL[0][0] : &WtL[0][0];

    for (int k0 = 0; k0 < K; k0 += 32) {
        __syncthreads();
        {
            const bool ok = (gr < glim);
            #pragma unroll
            for (int s = 0; s < 4; ++s) {
                bf16x8 vH = {0,0,0,0,0,0,0,0};
                bf16x8 vL = {0,0,0,0,0,0,0,0};
                if (ok) {
                    vH = *(const bf16x8*)(pHbase + k0 + s * 8);
                    vL = *(const bf16x8*)(pLbase + k0 + s * 8);
                }
                *(bf16x8*)(dH + s * 1024 + srow * 8) = vH;
                *(bf16x8*)(dL + s * 1024 + srow * 8) = vL;
            }
        }
        __syncthreads();
        bf16x8 aH[4], aL[4], bH[4], bL[4];
        #pragma unroll
        for (int f = 0; f < 4; ++f) {
            int ar = wr + f * 16 + l15;
            int br = wc + f * 16 + l15;
            aH[f] = *(const bf16x8*)&AtH[kseg][ar * 8];
            aL[f] = *(const bf16x8*)&AtL[kseg][ar * 8];
            bH[f] = *(const bf16x8*)&WtH[kseg][br * 8];
            bL[f] = *(const bf16x8*)&WtL[kseg][br * 8];
        }
        #pragma unroll
        for (int i = 0; i < 4; ++i)
            #pragma unroll
            for (int j = 0; j < 4; ++j)
                acc[i][j] = __builtin_amdgcn_mfma_f32_16x16x32_bf16(aH[i], bH[j], acc[i][j], 0, 0, 0);
        #pragma unroll
        for (int i = 0; i < 4; ++i)
            #pragma unroll
            for (int j = 0; j < 4; ++j)
                acc[i][j] = __builtin_amdgcn_mfma_f32_16x16x32_bf16(aH[i], bL[j], acc[i][j], 0, 0, 0);
        #pragma unroll
        for (int i = 0; i < 4; ++i)
            #pragma unroll
            for (int j = 0; j < 4; ++j)
                acc[i][j] = __builtin_amdgcn_mfma_f32_16x16x32_bf16(aL[i], bH[j], acc[i][j], 0, 0, 0);
    }

    const float av = (ACT == 1) ? *aptr : 0.f;
    const int r4 = (lane >> 4) * 4;
    #pragma unroll
    for (int j = 0; j < 4; ++j) {
        int col = bn + wc + j * 16 + l15;
        if (col >= Nd) continue;
        float bv = bias ? bias[col] : 0.f;
        #pragma unroll
        for (int i = 0; i < 4; ++i) {
            #pragma unroll
            for (int rr = 0; rr < 4; ++rr) {
                int row = bm + wr + i * 16 + r4 + rr;
                if (row >= M) continue;
                float v = acc[i][j][rr] + bv;
                if (ACT == 1) v = (v >= 0.f) ? v : av * v;
                if (OUT == 0) {
                    C[(size_t)row * ldc + col] = v;
                } else {
                    u16 h = f2bf(v);
                    Ch[(size_t)row * ldc + col] = h;
                    Cl[(size_t)row * ldc + col] = f2bf(v - bf2f(h));
                }
            }
        }
    }
}

// ---------------------------------------------------------------------------
// Pure single-bf16 MFMA GEMM (m97-style: 2 LDS tiles, 16 MFMA/chunk).
// C = A·W^T + bias, fp32 out. Same swizzle/staging as gemm_mfma3 but only
// the H operands. Used for zin (precision probe: W-lo contribution measured
// zero in round 16; A-lo predicted ~1e-4 at output, under threshold).
// ---------------------------------------------------------------------------
__global__ __launch_bounds__(256) void gemm_bf16(
    const u16* __restrict__ Ah, int lda,
    const u16* __restrict__ Wh, int ldw,
    float* __restrict__ C, int ldc,
    int M, int Nd, int K,
    const float* __restrict__ bias)
{
    __shared__ u16 At[4][1024];
    __shared__ u16 Wt[4][1024];
    const int tid  = threadIdx.x;
    const int ny  = gridDim.y;
    const int nwg = gridDim.x * ny;
    const int lin = blockIdx.y * gridDim.x + blockIdx.x;
    const int q = nwg >> 3, r8 = nwg & 7;
    const int xcd = lin & 7, off = lin >> 3;
    const int swz = (xcd < r8) ? xcd * (q + 1) + off
                               : r8 * (q + 1) + (xcd - r8) * q + off;
    const int bm   = (swz / ny) * 128;
    const int bn   = (swz % ny) * 128;
    const int wv   = tid >> 6;
    const int lane = tid & 63;
    const int wr   = (wv >> 1) * 64;
    const int wc   = (wv & 1) * 64;
    const int l15  = lane & 15;
    const int kseg = lane >> 4;

    f32x4 acc[4][4];
    #pragma unroll
    for (int i = 0; i < 4; ++i)
        #pragma unroll
        for (int j = 0; j < 4; ++j) acc[i][j] = (f32x4){0.f,0.f,0.f,0.f};

    const int srow = tid & 127;
    const bool isA = (tid < 128);
    const int gr   = isA ? (bm + srow) : (bn + srow);
    const int glim = isA ? M : 0x7FFFFFFF;        // W pad rows allocated+zeroed
    const u16* pbase = (isA ? Ah : Wh) + (size_t)gr * (isA ? lda : ldw);
    u16* dst = isA ? &At[0][0] : &Wt[0][0];

    for (int k0 = 0; k0 < K; k0 += 32) {
        __syncthreads();
        {
            const bool ok = (gr < glim);
            #pragma unroll
            for (int s = 0; s < 4; ++s) {
                bf16x8 v = {0,0,0,0,0,0,0,0};
                if (ok) v = *(const bf16x8*)(pbase + k0 + s * 8);
                *(bf16x8*)(dst + s * 1024 + srow * 8) = v;
            }
        }
        __syncthreads();
        bf16x8 a[4], b[4];
        #pragma unroll
        for (int f = 0; f < 4; ++f) {
            int ar = wr + f * 16 + l15;
            int br = wc + f * 16 + l15;
            a[f] = *(const bf16x8*)&At[kseg][ar * 8];
            b[f] = *(const bf16x8*)&Wt[kseg][br * 8];
        }
        #pragma unroll
        for (int i = 0; i < 4; ++i)
            #pragma unroll
            for (int j = 0; j < 4; ++j)
                acc[i][j] = __builtin_amdgcn_mfma_f32_16x16x32_bf16(a[i], b[j], acc[i][j], 0, 0, 0);
    }

    const int r4 = (lane >> 4) * 4;
    #pragma unroll
    for (int j = 0; j < 4; ++j) {
        int col = bn + wc + j * 16 + l15;
        if (col >= Nd) continue;
        float bv = bias ? bias[col] : 0.f;
        #pragma unroll
        for (int i = 0; i < 4; ++i) {
            #pragma unroll
            for (int rr = 0; rr < 4; ++rr) {
                int row = bm + wr + i * 16 + r4 + rr;
                if (row >= M) continue;
                C[(size_t)row * ldc + col] = acc[i][j][rr] + bv;
            }
        }
    }
}

// ---------------------------------------------------------------------------
// split fp32 -> bf16 hi/lo, vectorized: 4 rows/block, 8 cols/thread.
// ---------------------------------------------------------------------------
__global__ __launch_bounds__(256) void split_rows8(
    const float* __restrict__ src, int srcld,
    int pmask, int pmul1, int pshift, int pmul2, int padd,
    u16* __restrict__ dstH, u16* __restrict__ dstL, int dstld,
    int wcols, int validK, int validRows)
{
    const int r = blockIdx.y * 4 + (threadIdx.x >> 6);
    const int c = (blockIdx.x * 64 + (threadIdx.x & 63)) * 8;
    if (c >= wcols) return;
    const int sr = (r & pmask) * pmul1 + (r >> pshift) * pmul2 + padd;
    const float* s = src + (size_t)sr * srcld;
    const bool rok = (r < validRows);
    float v[8];
    if (rok && c + 8 <= validK) {
        *(float4*)&v[0] = *(const float4*)(s + c);
        *(float4*)&v[4] = *(const float4*)(s + c + 4);
    } else {
        #pragma unroll
        for (int u = 0; u < 8; ++u) v[u] = (rok && c + u < validK) ? s[c + u] : 0.f;
    }
    bf16x8 H8, L8;
    #pragma unroll
    for (int u = 0; u < 8; ++u) {
        u16 h = f2bf(v[u]);
        H8[u] = (short)h;
        L8[u] = (short)f2bf(v[u] - bf2f(h));
    }
    *(bf16x8*)(dstH + (size_t)r * dstld + c) = H8;
    *(bf16x8*)(dstL + (size_t)r * dstld + c) = L8;
}

// biasP[n'] = b_ih[orig]+b_hh[orig], orig = (n'&3)*600+(n'>>2)
__global__ __launch_bounds__(256) void bias_perm(
    const float* __restrict__ bih, const float* __restrict__ bhh, float* __restrict__ dst)
{
    int n = blockIdx.x * 256 + threadIdx.x;
    if (n >= 4 * LHdim) return;
    int o = (n & 3) * LHdim + (n >> 2);
    dst[n] = bih[o] + bhh[o];
}

// Wr2f[l][r][c]: r<300 -> wr0[l][r][c], else wr1[l][r-300][c]
__global__ __launch_bounds__(256) void wr_cat(
    const float* __restrict__ wr0, const float* __restrict__ wr1, float* __restrict__ dst)
{
    int c = blockIdx.x * 256 + threadIdx.x;
    if (c >= HDdim) return;
    int lr = blockIdx.y;
    int l = lr / (2 * HDdim), r = lr % (2 * HDdim);
    const float* src = (r < HDdim)
        ? wr0 + ((size_t)l * HDdim + r) * HDdim
        : wr1 + ((size_t)l * HDdim + (r - HDdim)) * HDdim;
    dst[(size_t)lr * HDdim + c] = src[c];
}

__global__ __launch_bounds__(256) void zero_range(float* __restrict__ p, int n)
{
    int i = blockIdx.x * 256 + threadIdx.x;
    if (i < n) p[i] = 0.f;
}

// ---------------------------------------------------------------------------
__global__ __launch_bounds__(256) void norm_kernel(const float* __restrict__ f, float* __restrict__ invn)
{
    int row  = blockIdx.x * 4 + (threadIdx.x >> 6);
    int lane = threadIdx.x & 63;
    const float* fr = f + (size_t)row * Edim;
    float ss = 0.f;
    for (int t = lane; t < Edim; t += 64) { float v = fr[t]; ss = fmaf(v, v, ss); }
    #pragma unroll
    for (int o = 32; o > 0; o >>= 1) ss += __shfl_down(ss, o);
    if (lane == 0) invn[row] = 1.f / (sqrtf(ss) + 1e-8f);
}

__global__ __launch_bounds__(256) void simadj_kernel(
    const float* __restrict__ f, const float* __restrict__ invn,
    const float* __restrict__ entro, const float* __restrict__ alphap,
    const float* __restrict__ thrp, uint8_t* __restrict__ adj)
{
    int b = blockIdx.x;
    __shared__ float S[16][100];
    int tid = threadIdx.x;
    int i0 = (tid >> 4) * 6, j0 = (tid & 15) * 6;
    float acc[6][6];
    #pragma unroll
    for (int i = 0; i < 6; ++i)
        #pragma unroll
        for (int j = 0; j < 6; ++j) acc[i][j] = 0.f;
    const float* fb = f + (size_t)b * Ndim * Edim;

    for (int k0 = 0; k0 < Edim; k0 += 16) {
        __syncthreads();
        #pragma unroll
        for (int r = 0; r < 6; ++r) {
            int n = (tid >> 4) + r * 16;
            S[tid & 15][n] = fb[(size_t)n * Edim + k0 + (tid & 15)];
        }
        __syncthreads();
        #pragma unroll
        for (int kk = 0; kk < 16; ++kk) {
            float a[6], bb[6];
            #pragma unroll
            for (int u = 0; u < 6; ++u) a[u] = S[kk][i0 + u];
            #pragma unroll
            for (int u = 0; u < 6; ++u) bb[u] = S[kk][j0 + u];
            #pragma unroll
            for (int i = 0; i < 6; ++i)
                #pragma unroll
                for (int j = 0; j < 6; ++j)
                    acc[i][j] = fmaf(a[i], bb[j], acc[i][j]);
        }
    }

    float alpha = *alphap, thr = *thrp;
    float onem = 1.f - alpha;
    #pragma unroll
    for (int i = 0; i < 6; ++i) {
        int ii = i0 + i;
        float inv_i = invn[b * Ndim + ii];
        #pragma unroll
        for (int j = 0; j < 6; ++j) {
            int jj = j0 + j;
            float simv = acc[i][j] * inv_i * invn[b * Ndim + jj];
            float comb = alpha * entro[b * Ndim + jj] + onem * simv;
            adj[((size_t)b * Ndim + ii) * Ndim + jj] = (comb > thr) ? 1 : 0;
        }
    }
}

// k[r] = H[r,:300] . wk   (q cancels in the adjacency softmax; not computed)
__global__ __launch_bounds__(256) void k_kernel(
    const float* __restrict__ Hsrc, const float* __restrict__ wk,
    float* __restrict__ k)
{
    int row  = blockIdx.x * 4 + (threadIdx.x >> 6);
    int lane = threadIdx.x & 63;
    const float* h = Hsrc + (size_t)row * GDdim;
    float sk = 0.f;
    for (int t = lane; t < HDdim; t += 64) sk = fmaf(h[t], wk[t], sk);
    #pragma unroll
    for (int o = 32; o > 0; o >>= 1) sk += __shfl_down(sk, o);
    if (lane == 0) k[row] = sk;
}

// ---------------------------------------------------------------------------
// Fused GAT attention for one batch b (q, gat_b cancel in softmax).
// V combined: cols 0..299 = V0, 300..599 = V1, row stride 600 (n-major rows).
// ---------------------------------------------------------------------------
__global__ __launch_bounds__(256) void gat_fused(
    const float* __restrict__ kbuf, const uint8_t* __restrict__ adj,
    const int* __restrict__ smask,
    const float* __restrict__ V,
    float* __restrict__ Mout)
{
    __shared__ float P0[96][98];
    __shared__ float P1[96][98];
    __shared__ float Vs0[96][96];
    __shared__ float Vs1[96][96];
    __shared__ float ek[96];
    __shared__ float rden[96];
    __shared__ float red[256];
    const int b = blockIdx.x;
    const int tid = threadIdx.x;

    float kj = (tid < Ndim) ? kbuf[tid * Bdim + b] : -1e30f;
    red[tid] = kj;
    __syncthreads();
    #pragma unroll
    for (int s = 128; s > 0; s >>= 1) {
        if (tid < s) red[tid] = fmaxf(red[tid], red[tid + s]);
        __syncthreads();
    }
    float kmax = red[0];
    if (tid < Ndim) ek[tid] = expf(kj - kmax);
    __syncthreads();
    if (tid < Ndim) {
        const uint8_t* ar = adj + ((size_t)b * Ndim + tid) * Ndim;
        float s = 0.f;
        for (int j = 0; j < Ndim; ++j) if (ar[j]) s += ek[j];
        rden[tid] = 1.f / s;   // diagonal always allowed -> s > 0
    }
    __syncthreads();
    for (int idx = tid; idx < Ndim * Ndim; idx += 256) {
        int i = idx / Ndim, j = idx - i * Ndim;
        float a = adj[((size_t)b * Ndim + i) * Ndim + j] ? ek[j] * rden[i] : 0.f;
        int s = smask[((size_t)b * Ndim + i) * Ndim + j];
        P0[i][j] = s ? a : 0.f;
        P1[i][j] = s ? 0.f : a;
    }
    __syncthreads();

    const int ti = tid >> 4, td = tid & 15;
    const int i0 = ti * 6, dbase = td * 6;
    for (int p = 0; p < 4; ++p) {
        const int d0 = p * 96;
        const int dw = (p == 3) ? (HDdim - 288) : 96;
        for (int idx = tid; idx < 96 * 24; idx += 256) {
            int j = idx / 24, q4 = (idx - j * 24) * 4;
            if (q4 < dw) {
                size_t g = ((size_t)(j * Bdim + b)) * (2 * HDdim) + d0 + q4;
                *(float4*)&Vs0[j][q4] = *(const float4*)(V + g);
                *(float4*)&Vs1[j][q4] = *(const float4*)(V + g + HDdim);
            }
        }
        __syncthreads();
        float acc[6][6];
        #pragma unroll
        for (int ii = 0; ii < 6; ++ii)
            #pragma unroll
            for (int dd = 0; dd < 6; ++dd) acc[ii][dd] = 0.f;
        for (int j = 0; j < Ndim; j += 2) {
            float2 pa[6], pb[6];
            #pragma unroll
            for (int ii = 0; ii < 6; ++ii) {
                pa[ii] = *(const float2*)&P0[i0 + ii][j];
                pb[ii] = *(const float2*)&P1[i0 + ii][j];
            }
            float2 v0a[3], v0b[3], v1a[3], v1b[3];
            #pragma unroll
            for (int dd = 0; dd < 3; ++dd) {
                v0a[dd] = *(const float2*)&Vs0[j][dbase + 2 * dd];
                v0b[dd] = *(const float2*)&Vs0[j + 1][dbase + 2 * dd];
                v1a[dd] = *(const float2*)&Vs1[j][dbase + 2 * dd];
                v1b[dd] = *(const float2*)&Vs1[j + 1][dbase + 2 * dd];
            }
            #pragma unroll
            for (int ii = 0; ii < 6; ++ii)
                #pragma unroll
                for (int dd = 0; dd < 3; ++dd) {
                    acc[ii][2*dd]   += pa[ii].x * v0a[dd].x + pb[ii].x * v1a[dd].x
                                     + pa[ii].y * v0b[dd].x + pb[ii].y * v1b[dd].x;
                    acc[ii][2*dd+1] += pa[ii].x * v0a[dd].y + pb[ii].x * v1a[dd].y
                                     + pa[ii].y * v0b[dd].y + pb[ii].y * v1b[dd].y;
                }
        }
        __syncthreads();
        #pragma unroll
        for (int ii = 0; ii < 6; ++ii) {
            #pragma unroll
            for (int dd = 0; dd < 6; ++dd) {
                int d = dbase + dd;
                if (d < dw)
                    Mout[((size_t)((i0 + ii) * Bdim + b)) * GDdim + d0 + d] = acc[ii][dd];
            }
        }
    }
}

// ---------------------------------------------------------------------------
// Per-step LSTM (round-13 proven: double-buffered LDS, one barrier per
// k-chunk) + T14 async-split + Hlstm-slice ping-pong (round 15 verified).
// Tile 32 batch x 64 gate-cols, grid (8,38).
// ---------------------------------------------------------------------------
__global__ __launch_bounds__(256) void lstm_mfma3(
    const u16* __restrict__ hH, const u16* __restrict__ hL,
    const float* __restrict__ cin,
    const u16* __restrict__ WH, const u16* __restrict__ WL,   // (2432 x 608)
    const float* __restrict__ zt,
    u16* __restrict__ hHo, u16* __restrict__ hLo,
    float* __restrict__ cout)
{
    __shared__ u16 AsH[2][4][256];
    __shared__ u16 AsL[2][4][256];
    __shared__ u16 WsH[2][4][512];
    __shared__ u16 WsL[2][4][512];
    __shared__ __align__(16) float gates[32][68];
    const int tid = threadIdx.x;
    const int bm = blockIdx.x * 32;
    const int bn = blockIdx.y * 64;
    const int wv = tid >> 6;
    const int lane = tid & 63;
    const int l15 = lane & 15;
    const int kseg = lane >> 4;
    const float4 fz = make_float4(0.f, 0.f, 0.f, 0.f);

    // --- T14: issue cell-phase loads NOW; consumed after the k-loop ---
    const int prow0 = tid >> 4,        pui0 = tid & 15;
    const int prow1 = (tid + 256) >> 4, pui1 = tid & 15;     // cell1 = tid+256
    const int pn0 = bn + pui0 * 4,  pn1 = bn + pui1 * 4;
    const int pu0 = pn0 >> 2,       pu1 = pn1 >> 2;
    const bool ok0 = (pu0 < LHdim), ok1 = (pu1 < LHdim);
    const int bb0 = bm + prow0,     bb1 = bm + prow1;
    float4 z0 = ok0 ? *(const float4*)(zt + (size_t)bb0 * (4 * LHdim) + pn0) : fz;
    float4 z1 = ok1 ? *(const float4*)(zt + (size_t)bb1 * (4 * LHdim) + pn1) : fz;
    float ci0 = ok0 ? cin[bb0 * LHdim + pu0] : 0.f;
    float ci1 = ok1 ? cin[bb1 * LHdim + pu1] : 0.f;

    // A staging: tid<128 -> AsH, else AsL; each thread one bf16x8
    const int av = tid & 127;
    const int arow = av >> 2, akc = av & 3;
    const u16* asrc = ((tid < 128) ? hH : hL) + (size_t)(bm + arow) * 608 + akc * 8;
    const int aoff = akc * 256 + arow * 8;
    // W staging: each thread one bf16x8 of WsH and WsL
    const int wrow = tid >> 2, wkc = tid & 3;
    const u16* wsrcH = WH + (size_t)(bn + wrow) * 608 + wkc * 8;
    const u16* wsrcL = WL + (size_t)(bn + wrow) * 608 + wkc * 8;
    const int woff2 = wrow * 8;

    f32x4 acc[2];
    acc[0] = (f32x4){0.f,0.f,0.f,0.f};
    acc[1] = (f32x4){0.f,0.f,0.f,0.f};

    // preload chunk 0
    bf16x8 ra  = *(const bf16x8*)(asrc);
    bf16x8 rwh = *(const bf16x8*)(wsrcH);
    bf16x8 rwl = *(const bf16x8*)(wsrcL);

    #pragma unroll
    for (int kc = 0; kc < 19; ++kc) {
        const int buf = kc & 1;
        *(bf16x8*)(((tid < 128) ? &AsH[buf][0][0] : &AsL[buf][0][0]) + aoff) = ra;
        *(bf16x8*)(&WsH[buf][wkc][woff2]) = rwh;
        *(bf16x8*)(&WsL[buf][wkc][woff2]) = rwl;
        if (kc + 1 < 19) {                      // prefetch next chunk
            ra  = *(const bf16x8*)(asrc + (kc + 1) * 32);
            rwh = *(const bf16x8*)(wsrcH + (kc + 1) * 32);
            rwl = *(const bf16x8*)(wsrcL + (kc + 1) * 32);
        }
        __syncthreads();                        // single barrier per chunk
        bf16x8 aH[2], aL[2], bH, bL;
        #pragma unroll
        for (int i = 0; i < 2; ++i) {
            int arr = i * 16 + l15;
            aH[i] = *(const bf16x8*)&AsH[buf][kseg][arr * 8];
            aL[i] = *(const bf16x8*)&AsL[buf][kseg][arr * 8];
        }
        {
            int br = wv * 16 + l15;
            bH = *(const bf16x8*)&WsH[buf][kseg][br * 8];
            bL = *(const bf16x8*)&WsL[buf][kseg][br * 8];
        }
        #pragma unroll
        for (int i = 0; i < 2; ++i) {
            acc[i] = __builtin_amdgcn_mfma_f32_16x16x32_bf16(aH[i], bH, acc[i], 0, 0, 0);
            acc[i] = __builtin_amdgcn_mfma_f32_16x16x32_bf16(aH[i], bL, acc[i], 0, 0, 0);
            acc[i] = __builtin_amdgcn_mfma_f32_16x16x32_bf16(aL[i], bH, acc[i], 0, 0, 0);
        }
    }

    const int r4 = (lane >> 4) * 4;
    __syncthreads();
    #pragma unroll
    for (int i = 0; i < 2; ++i)
        #pragma unroll
        for (int rr = 0; rr < 4; ++rr)
            gates[i * 16 + r4 + rr][wv * 16 + l15] = acc[i][rr];
    __syncthreads();

    // fused cell: 2 cells per thread, using prefetched z/c
    if (ok0) {
        float4 g = *(const float4*)&gates[prow0][pui0 * 4];
        float gi = g.x + z0.x;
        float gf = g.y + z0.y;
        float gg = g.z + z0.z;
        float go = g.w + z0.w;
        float si = 1.f / (1.f + expf(-gi));
        float sf = 1.f / (1.f + expf(-gf));
        float so = 1.f / (1.f + expf(-go));
        float cn = sf * ci0 + si * tanhf(gg);
        float hn = so * tanhf(cn);
        cout[bb0 * LHdim + pu0] = cn;
        u16 hh = f2bf(hn);
        hHo[(size_t)bb0 * 608 + pu0] = hh;
        hLo[(size_t)bb0 * 608 + pu0] = f2bf(hn - bf2f(hh));
    }
    if (ok1) {
        float4 g = *(const float4*)&gates[prow1][pui1 * 4];
        float gi = g.x + z1.x;
        float gf = g.y + z1.y;
        float gg = g.z + z1.z;
        float go = g.w + z1.w;
        float si = 1.f / (1.f + expf(-gi));
        float sf = 1.f / (1.f + expf(-gf));
        float so = 1.f / (1.f + expf(-go));
        float cn = sf * ci1 + si * tanhf(gg);
        float hn = so * tanhf(cn);
        cout[bb1 * LHdim + pu1] = cn;
        u16 hh = f2bf(hn);
        hHo[(size_t)bb1 * 608 + pu1] = hh;
        hLo[(size_t)bb1 * 608 + pu1] = f2bf(hn - bf2f(hh));
    }
}

__global__ __launch_bounds__(256) void out_kernel(
    const float* __restrict__ x, int ldx, const float* __restrict__ ow,
    const float* __restrict__ ob, float* __restrict__ out)
{
    int r    = blockIdx.x * 4 + (threadIdx.x >> 6);
    int lane = threadIdx.x & 63;
    const float* xr = x + (size_t)r * ldx;
    float acc[NCdim];
    #pragma unroll
    for (int n = 0; n < NCdim; ++n) acc[n] = 0.f;
    for (int t = lane; t < HDdim; t += 64) {
        float xv = xr[t];
        #pragma unroll
        for (int n = 0; n < NCdim; ++n) acc[n] = fmaf(xv, ow[n * HDdim + t], acc[n]);
    }
    #pragma unroll
    for (int o = 32; o > 0; o >>= 1)
        #pragma unroll
        for (int n = 0; n < NCdim; ++n) acc[n] += __shfl_down(acc[n], o);
    if (lane == 0) {
        int b = r & 255, nn = r >> 8;
        #pragma unroll
        for (int n = 0; n < NCdim; ++n) out[((size_t)b * Ndim + nn) * NCdim + n] = acc[n] + ob[n];
    }
}

// ---------------------------------------------------------------------------
extern "C" void kernel_launch(void* const* d_in, const int* in_sizes, int n_in,
                              void* d_out, int out_size, void* d_ws, size_t ws_size,
                              hipStream_t stream)
{
    const float*  features  = (const float*)d_in[0];
    const int*    s_mask    = (const int*)  d_in[1];
    const float*  entro     = (const float*)d_in[2];
    const float*  alpha     = (const float*)d_in[3];
    const float*  threshold = (const float*)d_in[4];
    const float*  fc1_w     = (const float*)d_in[5];
    const float*  fc1_b     = (const float*)d_in[6];
    const float*  gat_w     = (const float*)d_in[7];
    const float*  gat_b     = (const float*)d_in[8];
    const float*  wr0       = (const float*)d_in[9];
    const float*  wr1       = (const float*)d_in[10];
    const float*  enhance_w = (const float*)d_in[11];
    const float*  enhance_b = (const float*)d_in[12];
    const float*  prelu_a   = (const float*)d_in[13];
    const float*  lstm_w_ih = (const float*)d_in[14];
    const float*  lstm_w_hh = (const float*)d_in[15];
    const float*  lstm_b_ih = (const float*)d_in[16];
    const float*  lstm_b_hh = (const float*)d_in[17];
    const float*  mlp_w0    = (const float*)d_in[18];
    const float*  mlp_b0    = (const float*)d_in[19];
    const float*  mlp_a0    = (const float*)d_in[20];
    const float*  mlp_w1    = (const float*)d_in[21];
    const float*  mlp_b1    = (const float*)d_in[22];
    const float*  mlp_a1    = (const float*)d_in[23];
    const float*  out_w     = (const float*)d_in[24];
    const float*  out_b     = (const float*)d_in[25];
    float* out = (float*)d_out;
    char* ws = (char*)d_ws;
    (void)gat_b;

    // ---- fixed workspace layout (bytes, 256-aligned) ----
    uint8_t* adj   = (uint8_t*)(ws + 0);               //  2,359,296
    float*   invn  = (float*)(ws + 2359296);
    float*   kbuf  = (float*)(ws + 2555904);
    float*   biasP = (float*)(ws + 2654208);
    float*   c0    = (float*)(ws + 2663936);           //    614,400
    float*   c1    = (float*)(ws + 3278336);
    u16*     WhhPH = (u16*)(ws + 5137920);             //  2,957,312 (2432 x 608)
    u16*     WhhPL = (u16*)(ws + 8095232);
    u16*     WihPH = (u16*)(ws + 11052544);            //  9,494,528 (2432 x 1952)
    u16*     WihPL = (u16*)(ws + 20547072);
    u16*     EwH   = (u16*)(ws + 30041600);            //  2,097,152 (1024 x 1024)
    u16*     EwL   = (u16*)(ws + 32138752);
    u16*     Fc1H  = (u16*)(ws + 34235904);            //    786,432 (384 x 1024)
    u16*     Fc1L  = (u16*)(ws + 35022336);
    float*   Wr2f  = (float*)(ws + 35808768);          //  1,440,256 (2 x 600 x 300)
    u16*     Wr2H  = (u16*)(ws + 37249024);            //    819,200 (2 x 640 x 320)
    u16*     Wr2L  = (u16*)(ws + 38068224);
    u16*     Wm0H  = (u16*)(ws + 38887424);            //    524,288 (384 x 608)
    u16*     Wm0L  = (u16*)(ws + 39411712);
    u16*     Wm1H  = (u16*)(ws + 39936000);            //    262,144 (384 x 320)
    u16*     Wm1L  = (u16*)(ws + 40198144);
    u16*     FfH   = (u16*)(ws + 40460288);            // 50,331,648 (ROWS x 1024)
    u16*     FfL   = (u16*)(ws + 90791936);
    float*   Hcat  = (float*)(ws + 141123584);         // 88,473,600 (ROWS,900) n-major
    u16*     HsH   = (u16*)(ws + 229597184);           // 15,728,640 (ROWS x 320)
    u16*     HsL   = (u16*)(ws + 245325824);
    // V (GAT, fp32 ROWSx600) aliases Hlstm (97 slices x 256 x 608 split bf16)
    float*   V      = (float*)(ws + 261054464);        // 58,982,400
    u16*     HlstmH = (u16*)(ws + 261054464);          // 30,195,712 (97 slices)
    u16*     HlstmL = (u16*)(ws + 291250176);          // 30,195,712 -> 321,445,888
    // MLP scratch aliases Hcat (dead after last Hcat split)
    u16*     x1H   = (u16*)Hcat;                       // 15,728,640 (ROWS x 320)
    u16*     x1L   = (u16*)(ws + 141123584 + 15728640);
    float*   x2    = (float*)(ws + 141123584 + 31457280);   // 29,884,416 (ROWS x 304)

    // ---- tier selection for chunked seq/zin region ----
    const size_t fixedNeed = 321445888ull;
    const size_t perT = 4456448ull;                    // zin(2,457,600)+seqH/L(1,998,848)
    int T;
    if      (ws_size >= fixedNeed + 96ull * perT) T = 96;
    else if (ws_size >= fixedNeed + 48ull * perT) T = 48;
    else if (ws_size >= fixedNeed + 32ull * perT) T = 32;
    else if (ws_size >= fixedNeed + 16ull * perT) T = 16;
    else if (ws_size >= fixedNeed +  8ull * perT) T = 8;
    else return;                                       // visible failure, no OOB
    char* cr = ws + fixedNeed;
    float* zin  = (float*)cr;                                // (Mc,2400)
    u16*   seqH = (u16*)(cr + (size_t)T * 2457600);          // (Mc,1952)
    u16*   seqL = (u16*)(cr + (size_t)T * 2457600 + (size_t)T * 999424);

    // 1) norms + adjacency
    norm_kernel<<<ROWS / 4, 256, 0, stream>>>(features, invn);
    simadj_kernel<<<Bdim, 256, 0, stream>>>(features, invn, entro, alpha, threshold, adj);

    // 2) weight/activation conversions
    split_rows8<<<dim3(2, ROWS / 4), 256, 0, stream>>>(            // features n-major full
        features, Edim, 255, Ndim, 8, 1, 0, FfH, FfL, Edim, Edim, Edim, ROWS);
    split_rows8<<<dim3(2, 96), 256, 0, stream>>>(                  // fc1_w (384x1024)
        fc1_w, Edim, IDP, Fc1H, Fc1L, Edim, Edim, Edim, HDdim);
    split_rows8<<<dim3(2, 256), 256, 0, stream>>>(                 // enhance_w
        enhance_w, Edim, IDP, EwH, EwL, Edim, Edim, Edim, Edim);
    split_rows8<<<dim3(4, 608), 256, 0, stream>>>(                 // Wih gate-interleaved
        lstm_w_ih, Edim + GDdim, 3, LHdim, 2, 1, 0, WihPH, WihPL, 1952, 1952, 1924, 2400);
    split_rows8<<<dim3(2, 608), 256, 0, stream>>>(                 // Whh gate-interleaved
        lstm_w_hh, LHdim, 3, LHdim, 2, 1, 0, WhhPH, WhhPL, 608, 608, LHdim, 2400);
    split_rows8<<<dim3(2, 96), 256, 0, stream>>>(                  // mlp_w0 (384x608)
        mlp_w0, LHdim, IDP, Wm0H, Wm0L, 608, 608, LHdim, HDdim);
    split_rows8<<<dim3(1, 96), 256, 0, stream>>>(                  // mlp_w1 (384x320)
        mlp_w1, HDdim, IDP, Wm1H, Wm1L, 320, 320, HDdim, HDdim);
    wr_cat<<<dim3(2, 2 * Ldim * HDdim), 256, 0, stream>>>(wr0, wr1, Wr2f);
    for (int l = 0; l < Ldim; ++l)
        split_rows8<<<dim3(1, 160), 256, 0, stream>>>(             // Wr2 (640x320 per layer)
            Wr2f + (size_t)l * 2 * HDdim * HDdim, HDdim, IDP,
            Wr2H + (size_t)l * 640 * 320, Wr2L + (size_t)l * 640 * 320,
            320, 320, HDdim, 2 * HDdim);
    bias_perm<<<10, 256, 0, stream>>>(lstm_b_ih, lstm_b_hh, biasP);
    zero_range<<<1200, 256, 0, stream>>>(c0, 307200);              // c0, c1

    // 3) H0 = prelu(features @ fc1_w^T + fc1_b) -> Hcat[:, 0:300] (MFMA)
    gemm_mfma3<0,1><<<dim3(ROWS/128, 3), 256, 0, stream>>>(
        FfH, FfL, Edim, Fc1H, Fc1L, Edim,
        Hcat, nullptr, nullptr, GDdim, ROWS, HDdim, Edim, fc1_b, prelu_a);

    // 4) GAT layers (MFMA V projection, fused softmax+aggregation)
    for (int l = 0; l < Ldim; ++l) {
        const float* Hsrc = Hcat + l * HDdim;
        k_kernel<<<ROWS / 4, 256, 0, stream>>>(Hsrc, gat_w + l * 2 * HDdim + HDdim, kbuf);
        split_rows8<<<dim3(1, ROWS / 4), 256, 0, stream>>>(        // Hsrc -> split (K=320)
            Hsrc, GDdim, IDP, HsH, HsL, 320, 320, HDdim, ROWS);
        gemm_mfma3<0,0><<<dim3(ROWS/128, 5), 256, 0, stream>>>(
            HsH, HsL, 320, Wr2H + (size_t)l * 640 * 320, Wr2L + (size_t)l * 640 * 320, 320,
            V, nullptr, nullptr, 2 * HDdim, ROWS, 2 * HDdim, 320, nullptr, nullptr);
        gat_fused<<<Bdim, 256, 0, stream>>>(
            kbuf, adj, s_mask, V, Hcat + (l + 1) * HDdim);
    }

    // 5) zero Hlstm split region (pads + slice 0 = h_0; aliased V until now)
    zero_range<<<58976, 256, 0, stream>>>((float*)HlstmH, 15097856);

    // 6) chunked: enhance MFMA -> Hcat split -> zin (pure bf16 MFMA) -> LSTM
    int cur = 0;
    float* cb_[2] = {c0, c1};
    for (int t0 = 0; t0 < Ndim; t0 += T) {
        int Mc = T * Bdim;
        gemm_mfma3<1,1><<<dim3(Mc/128, 8), 256, 0, stream>>>(
            FfH + (size_t)t0 * Bdim * Edim, FfL + (size_t)t0 * Bdim * Edim, Edim,
            EwH, EwL, Edim,
            nullptr, seqH, seqL, 1952, Mc, Edim, Edim, enhance_b, prelu_a);
        split_rows8<<<dim3(2, Mc / 4), 256, 0, stream>>>(
            Hcat, GDdim, 0x7FFFFFFF, 1, 30, 0, t0 * Bdim,
            seqH + 1024, seqL + 1024, 1952, 928, GDdim, Mc);
        gemm_bf16<<<dim3(Mc/128, 19), 256, 0, stream>>>(           // single-bf16 zin
            seqH, 1952, WihPH, 1952,
            zin, 4 * LHdim, Mc, 4 * LHdim, 1952, biasP);
        for (int tl = 0; tl < T; ++tl) {
            const int g = t0 + tl;                    // global step, 0-based
            lstm_mfma3<<<dim3(8, 38), 256, 0, stream>>>(
                HlstmH + (size_t)g * HSLICE, HlstmL + (size_t)g * HSLICE,
                cb_[cur], WhhPH, WhhPL,
                zin + (size_t)tl * Bdim * 4 * LHdim,
                HlstmH + (size_t)(g + 1) * HSLICE, HlstmL + (size_t)(g + 1) * HSLICE,
                cb_[cur ^ 1]);
            cur ^= 1;
        }
    }

    // 7) MLP head (MFMA, A = Hlstm slices 1..96) + output
    zero_range<<<30720, 256, 0, stream>>>((float*)x1H, 7864320);   // x1 pads must be 0
    gemm_mfma3<1,1><<<dim3(ROWS/128, 3), 256, 0, stream>>>(
        HlstmH + HSLICE, HlstmL + HSLICE, 608, Wm0H, Wm0L, 608,
        nullptr, x1H, x1L, 320, ROWS, HDdim, 608, mlp_b0, mlp_a0);
    gemm_mfma3<0,1><<<dim3(ROWS/128, 3), 256, 0, stream>>>(
        x1H, x1L, 320, Wm1H, Wm1L, 320,
        x2, nullptr, nullptr, 304, ROWS, HDdim, 320, mlp_b1, mlp_a1);
    out_kernel<<<ROWS / 4, 256, 0, stream>>>(x2, 304, out_w, out_b, out);
}

// Round 19
// 3178.517 us; speedup vs baseline: 1.4590x; 1.0464x over previous
//
#include <hip/hip_runtime.h>
#include <cstdint>
#include <cstddef>

#define Bdim 256
#define Ndim 96
#define Edim 1024
#define HDdim 300
#define Ldim 2
#define LHdim 600
#define NCdim 7
#define GDdim 900              // HD*(L+1)
#define ROWS (Bdim*Ndim)       // 24576
#define HSLICE 155648          // 256*608 elements per Hlstm time-slice

typedef unsigned short u16;
typedef float f32x4 __attribute__((ext_vector_type(4)));
typedef short bf16x8 __attribute__((ext_vector_type(8)));

// Identity row-perm constants
#define IDP 0x7FFFFFFF, 1, 30, 0, 0

__device__ inline u16 f2bf(float x) {
    unsigned int u = __builtin_bit_cast(unsigned int, x);
    unsigned int r = (u + 0x7fffu + ((u >> 16) & 1u)) >> 16;   // RNE
    return (u16)r;
}
__device__ inline float bf2f(u16 h) {
    unsigned int u = ((unsigned int)h) << 16;
    return __builtin_bit_cast(float, u);
}

// ---------------------------------------------------------------------------
// bf16x3 split MFMA GEMM, bx-major bijective XCD swizzle (A-tile L2-resident
// per XCD). reg->LDS staging. C = act(sum_k (Ah+Al)[m,k]*(Wh+Wl)[n,k] + bias).
// K mult of 32; lda/ldw mult 8. W must have gridDim.y*128 rows alloc (pads 0).
// OUT: 0 -> fp32 C; 1 -> split bf16 (Ch,Cl). ACT: 1 -> prelu(aptr).
// ---------------------------------------------------------------------------
template<int OUT, int ACT>
__global__ __launch_bounds__(256) void gemm_mfma3(
    const u16* __restrict__ Ah, const u16* __restrict__ Al, int lda,
    const u16* __restrict__ Wh, const u16* __restrict__ Wl, int ldw,
    float* __restrict__ C, u16* __restrict__ Ch, u16* __restrict__ Cl, int ldc,
    int M, int Nd, int K,
    const float* __restrict__ bias, const float* __restrict__ aptr)
{
    __shared__ u16 AtH[4][1024];
    __shared__ u16 AtL[4][1024];
    __shared__ u16 WtH[4][1024];
    __shared__ u16 WtL[4][1024];
    const int tid  = threadIdx.x;
    const int ny  = gridDim.y;
    const int nwg = gridDim.x * ny;
    const int lin = blockIdx.y * gridDim.x + blockIdx.x;
    const int q = nwg >> 3, r8 = nwg & 7;
    const int xcd = lin & 7, off = lin >> 3;
    const int swz = (xcd < r8) ? xcd * (q + 1) + off
                               : r8 * (q + 1) + (xcd - r8) * q + off;
    const int bm   = (swz / ny) * 128;
    const int bn   = (swz % ny) * 128;
    const int wv   = tid >> 6;
    const int lane = tid & 63;
    const int wr   = (wv >> 1) * 64;
    const int wc   = (wv & 1) * 64;
    const int l15  = lane & 15;
    const int kseg = lane >> 4;

    f32x4 acc[4][4];
    #pragma unroll
    for (int i = 0; i < 4; ++i)
        #pragma unroll
        for (int j = 0; j < 4; ++j) acc[i][j] = (f32x4){0.f,0.f,0.f,0.f};

    const int srow = tid & 127;
    const bool isA = (tid < 128);
    const int gr   = isA ? (bm + srow) : (bn + srow);
    const int glim = isA ? M : 0x7FFFFFFF;
    const u16* pHbase = (isA ? Ah : Wh) + (size_t)gr * (isA ? lda : ldw);
    const u16* pLbase = (isA ? Al : Wl) + (size_t)gr * (isA ? lda : ldw);
    u16* dH = isA ? &AtH[0][0] : &WtH[0][0];
    u16* dL = isA ? &AtL[0][0] : &WtL[0][0];

    for (int k0 = 0; k0 < K; k0 += 32) {
        __syncthreads();
        {
            const bool ok = (gr < glim);
            #pragma unroll
            for (int s = 0; s < 4; ++s) {
                bf16x8 vH = {0,0,0,0,0,0,0,0};
                bf16x8 vL = {0,0,0,0,0,0,0,0};
                if (ok) {
                    vH = *(const bf16x8*)(pHbase + k0 + s * 8);
                    vL = *(const bf16x8*)(pLbase + k0 + s * 8);
                }
                *(bf16x8*)(dH + s * 1024 + srow * 8) = vH;
                *(bf16x8*)(dL + s * 1024 + srow * 8) = vL;
            }
        }
        __syncthreads();
        bf16x8 aH[4], aL[4], bH[4], bL[4];
        #pragma unroll
        for (int f = 0; f < 4; ++f) {
            int ar = wr + f * 16 + l15;
            int br = wc + f * 16 + l15;
            aH[f] = *(const bf16x8*)&AtH[kseg][ar * 8];
            aL[f] = *(const bf16x8*)&AtL[kseg][ar * 8];
            bH[f] = *(const bf16x8*)&WtH[kseg][br * 8];
            bL[f] = *(const bf16x8*)&WtL[kseg][br * 8];
        }
        #pragma unroll
        for (int i = 0; i < 4; ++i)
            #pragma unroll
            for (int j = 0; j < 4; ++j)
                acc[i][j] = __builtin_amdgcn_mfma_f32_16x16x32_bf16(aH[i], bH[j], acc[i][j], 0, 0, 0);
        #pragma unroll
        for (int i = 0; i < 4; ++i)
            #pragma unroll
            for (int j = 0; j < 4; ++j)
                acc[i][j] = __builtin_amdgcn_mfma_f32_16x16x32_bf16(aH[i], bL[j], acc[i][j], 0, 0, 0);
        #pragma unroll
        for (int i = 0; i < 4; ++i)
            #pragma unroll
            for (int j = 0; j < 4; ++j)
                acc[i][j] = __builtin_amdgcn_mfma_f32_16x16x32_bf16(aL[i], bH[j], acc[i][j], 0, 0, 0);
    }

    const float av = (ACT == 1) ? *aptr : 0.f;
    const int r4 = (lane >> 4) * 4;
    #pragma unroll
    for (int j = 0; j < 4; ++j) {
        int col = bn + wc + j * 16 + l15;
        if (col >= Nd) continue;
        float bv = bias ? bias[col] : 0.f;
        #pragma unroll
        for (int i = 0; i < 4; ++i) {
            #pragma unroll
            for (int rr = 0; rr < 4; ++rr) {
                int row = bm + wr + i * 16 + r4 + rr;
                if (row >= M) continue;
                float v = acc[i][j][rr] + bv;
                if (ACT == 1) v = (v >= 0.f) ? v : av * v;
                if (OUT == 0) {
                    C[(size_t)row * ldc + col] = v;
                } else {
                    u16 h = f2bf(v);
                    Ch[(size_t)row * ldc + col] = h;
                    Cl[(size_t)row * ldc + col] = f2bf(v - bf2f(h));
                }
            }
        }
    }
}

// ---------------------------------------------------------------------------
// Pure single-bf16 MFMA GEMM (m97-style: 2 LDS tiles, 16 MFMA/chunk).
// C = act(A·W^T + bias). Same swizzle/staging as gemm_mfma3, H operands only.
// OUT: 0 -> fp32 C; 1 -> split bf16 (Ch,Cl). ACT: 1 -> prelu(aptr).
// (Epilogue-only templating; staging loop is branch-free — round-16 lesson.)
// ---------------------------------------------------------------------------
template<int OUT, int ACT>
__global__ __launch_bounds__(256) void gemm_bf16(
    const u16* __restrict__ Ah, int lda,
    const u16* __restrict__ Wh, int ldw,
    float* __restrict__ C, u16* __restrict__ Ch, u16* __restrict__ Cl, int ldc,
    int M, int Nd, int K,
    const float* __restrict__ bias, const float* __restrict__ aptr)
{
    __shared__ u16 At[4][1024];
    __shared__ u16 Wt[4][1024];
    const int tid  = threadIdx.x;
    const int ny  = gridDim.y;
    const int nwg = gridDim.x * ny;
    const int lin = blockIdx.y * gridDim.x + blockIdx.x;
    const int q = nwg >> 3, r8 = nwg & 7;
    const int xcd = lin & 7, off = lin >> 3;
    const int swz = (xcd < r8) ? xcd * (q + 1) + off
                               : r8 * (q + 1) + (xcd - r8) * q + off;
    const int bm   = (swz / ny) * 128;
    const int bn   = (swz % ny) * 128;
    const int wv   = tid >> 6;
    const int lane = tid & 63;
    const int wr   = (wv >> 1) * 64;
    const int wc   = (wv & 1) * 64;
    const int l15  = lane & 15;
    const int kseg = lane >> 4;

    f32x4 acc[4][4];
    #pragma unroll
    for (int i = 0; i < 4; ++i)
        #pragma unroll
        for (int j = 0; j < 4; ++j) acc[i][j] = (f32x4){0.f,0.f,0.f,0.f};

    const int srow = tid & 127;
    const bool isA = (tid < 128);
    const int gr   = isA ? (bm + srow) : (bn + srow);
    const int glim = isA ? M : 0x7FFFFFFF;        // W pad rows allocated+zeroed
    const u16* pbase = (isA ? Ah : Wh) + (size_t)gr * (isA ? lda : ldw);
    u16* dst = isA ? &At[0][0] : &Wt[0][0];

    for (int k0 = 0; k0 < K; k0 += 32) {
        __syncthreads();
        {
            const bool ok = (gr < glim);
            #pragma unroll
            for (int s = 0; s < 4; ++s) {
                bf16x8 v = {0,0,0,0,0,0,0,0};
                if (ok) v = *(const bf16x8*)(pbase + k0 + s * 8);
                *(bf16x8*)(dst + s * 1024 + srow * 8) = v;
            }
        }
        __syncthreads();
        bf16x8 a[4], b[4];
        #pragma unroll
        for (int f = 0; f < 4; ++f) {
            int ar = wr + f * 16 + l15;
            int br = wc + f * 16 + l15;
            a[f] = *(const bf16x8*)&At[kseg][ar * 8];
            b[f] = *(const bf16x8*)&Wt[kseg][br * 8];
        }
        #pragma unroll
        for (int i = 0; i < 4; ++i)
            #pragma unroll
            for (int j = 0; j < 4; ++j)
                acc[i][j] = __builtin_amdgcn_mfma_f32_16x16x32_bf16(a[i], b[j], acc[i][j], 0, 0, 0);
    }

    const float av = (ACT == 1) ? *aptr : 0.f;
    const int r4 = (lane >> 4) * 4;
    #pragma unroll
    for (int j = 0; j < 4; ++j) {
        int col = bn + wc + j * 16 + l15;
        if (col >= Nd) continue;
        float bv = bias ? bias[col] : 0.f;
        #pragma unroll
        for (int i = 0; i < 4; ++i) {
            #pragma unroll
            for (int rr = 0; rr < 4; ++rr) {
                int row = bm + wr + i * 16 + r4 + rr;
                if (row >= M) continue;
                float v = acc[i][j][rr] + bv;
                if (ACT == 1) v = (v >= 0.f) ? v : av * v;
                if (OUT == 0) {
                    C[(size_t)row * ldc + col] = v;
                } else {
                    u16 h = f2bf(v);
                    Ch[(size_t)row * ldc + col] = h;
                    Cl[(size_t)row * ldc + col] = f2bf(v - bf2f(h));
                }
            }
        }
    }
}

// ---------------------------------------------------------------------------
// split fp32 -> bf16 hi/lo, vectorized: 4 rows/block, 8 cols/thread.
// ---------------------------------------------------------------------------
__global__ __launch_bounds__(256) void split_rows8(
    const float* __restrict__ src, int srcld,
    int pmask, int pmul1, int pshift, int pmul2, int padd,
    u16* __restrict__ dstH, u16* __restrict__ dstL, int dstld,
    int wcols, int validK, int validRows)
{
    const int r = blockIdx.y * 4 + (threadIdx.x >> 6);
    const int c = (blockIdx.x * 64 + (threadIdx.x & 63)) * 8;
    if (c >= wcols) return;
    const int sr = (r & pmask) * pmul1 + (r >> pshift) * pmul2 + padd;
    const float* s = src + (size_t)sr * srcld;
    const bool rok = (r < validRows);
    float v[8];
    if (rok && c + 8 <= validK) {
        *(float4*)&v[0] = *(const float4*)(s + c);
        *(float4*)&v[4] = *(const float4*)(s + c + 4);
    } else {
        #pragma unroll
        for (int u = 0; u < 8; ++u) v[u] = (rok && c + u < validK) ? s[c + u] : 0.f;
    }
    bf16x8 H8, L8;
    #pragma unroll
    for (int u = 0; u < 8; ++u) {
        u16 h = f2bf(v[u]);
        H8[u] = (short)h;
        L8[u] = (short)f2bf(v[u] - bf2f(h));
    }
    *(bf16x8*)(dstH + (size_t)r * dstld + c) = H8;
    *(bf16x8*)(dstL + (size_t)r * dstld + c) = L8;
}

// biasP[n'] = b_ih[orig]+b_hh[orig], orig = (n'&3)*600+(n'>>2)
__global__ __launch_bounds__(256) void bias_perm(
    const float* __restrict__ bih, const float* __restrict__ bhh, float* __restrict__ dst)
{
    int n = blockIdx.x * 256 + threadIdx.x;
    if (n >= 4 * LHdim) return;
    int o = (n & 3) * LHdim + (n >> 2);
    dst[n] = bih[o] + bhh[o];
}

// Wr2f[l][r][c]: r<300 -> wr0[l][r][c], else wr1[l][r-300][c]
__global__ __launch_bounds__(256) void wr_cat(
    const float* __restrict__ wr0, const float* __restrict__ wr1, float* __restrict__ dst)
{
    int c = blockIdx.x * 256 + threadIdx.x;
    if (c >= HDdim) return;
    int lr = blockIdx.y;
    int l = lr / (2 * HDdim), r = lr % (2 * HDdim);
    const float* src = (r < HDdim)
        ? wr0 + ((size_t)l * HDdim + r) * HDdim
        : wr1 + ((size_t)l * HDdim + (r - HDdim)) * HDdim;
    dst[(size_t)lr * HDdim + c] = src[c];
}

__global__ __launch_bounds__(256) void zero_range(float* __restrict__ p, int n)
{
    int i = blockIdx.x * 256 + threadIdx.x;
    if (i < n) p[i] = 0.f;
}

// ---------------------------------------------------------------------------
__global__ __launch_bounds__(256) void norm_kernel(const float* __restrict__ f, float* __restrict__ invn)
{
    int row  = blockIdx.x * 4 + (threadIdx.x >> 6);
    int lane = threadIdx.x & 63;
    const float* fr = f + (size_t)row * Edim;
    float ss = 0.f;
    for (int t = lane; t < Edim; t += 64) { float v = fr[t]; ss = fmaf(v, v, ss); }
    #pragma unroll
    for (int o = 32; o > 0; o >>= 1) ss += __shfl_down(ss, o);
    if (lane == 0) invn[row] = 1.f / (sqrtf(ss) + 1e-8f);
}

__global__ __launch_bounds__(256) void simadj_kernel(
    const float* __restrict__ f, const float* __restrict__ invn,
    const float* __restrict__ entro, const float* __restrict__ alphap,
    const float* __restrict__ thrp, uint8_t* __restrict__ adj)
{
    int b = blockIdx.x;
    __shared__ float S[16][100];
    int tid = threadIdx.x;
    int i0 = (tid >> 4) * 6, j0 = (tid & 15) * 6;
    float acc[6][6];
    #pragma unroll
    for (int i = 0; i < 6; ++i)
        #pragma unroll
        for (int j = 0; j < 6; ++j) acc[i][j] = 0.f;
    const float* fb = f + (size_t)b * Ndim * Edim;

    for (int k0 = 0; k0 < Edim; k0 += 16) {
        __syncthreads();
        #pragma unroll
        for (int r = 0; r < 6; ++r) {
            int n = (tid >> 4) + r * 16;
            S[tid & 15][n] = fb[(size_t)n * Edim + k0 + (tid & 15)];
        }
        __syncthreads();
        #pragma unroll
        for (int kk = 0; kk < 16; ++kk) {
            float a[6], bb[6];
            #pragma unroll
            for (int u = 0; u < 6; ++u) a[u] = S[kk][i0 + u];
            #pragma unroll
            for (int u = 0; u < 6; ++u) bb[u] = S[kk][j0 + u];
            #pragma unroll
            for (int i = 0; i < 6; ++i)
                #pragma unroll
                for (int j = 0; j < 6; ++j)
                    acc[i][j] = fmaf(a[i], bb[j], acc[i][j]);
        }
    }

    float alpha = *alphap, thr = *thrp;
    float onem = 1.f - alpha;
    #pragma unroll
    for (int i = 0; i < 6; ++i) {
        int ii = i0 + i;
        float inv_i = invn[b * Ndim + ii];
        #pragma unroll
        for (int j = 0; j < 6; ++j) {
            int jj = j0 + j;
            float simv = acc[i][j] * inv_i * invn[b * Ndim + jj];
            float comb = alpha * entro[b * Ndim + jj] + onem * simv;
            adj[((size_t)b * Ndim + ii) * Ndim + jj] = (comb > thr) ? 1 : 0;
        }
    }
}

// k[r] = H[r,:300] . wk   (q cancels in the adjacency softmax; not computed)
__global__ __launch_bounds__(256) void k_kernel(
    const float* __restrict__ Hsrc, const float* __restrict__ wk,
    float* __restrict__ k)
{
    int row  = blockIdx.x * 4 + (threadIdx.x >> 6);
    int lane = threadIdx.x & 63;
    const float* h = Hsrc + (size_t)row * GDdim;
    float sk = 0.f;
    for (int t = lane; t < HDdim; t += 64) sk = fmaf(h[t], wk[t], sk);
    #pragma unroll
    for (int o = 32; o > 0; o >>= 1) sk += __shfl_down(sk, o);
    if (lane == 0) k[row] = sk;
}

// ---------------------------------------------------------------------------
// Fused GAT attention for one batch b (q, gat_b cancel in softmax).
// V combined: cols 0..299 = V0, 300..599 = V1, row stride 600 (n-major rows).
// ---------------------------------------------------------------------------
__global__ __launch_bounds__(256) void gat_fused(
    const float* __restrict__ kbuf, const uint8_t* __restrict__ adj,
    const int* __restrict__ smask,
    const float* __restrict__ V,
    float* __restrict__ Mout)
{
    __shared__ float P0[96][98];
    __shared__ float P1[96][98];
    __shared__ float Vs0[96][96];
    __shared__ float Vs1[96][96];
    __shared__ float ek[96];
    __shared__ float rden[96];
    __shared__ float red[256];
    const int b = blockIdx.x;
    const int tid = threadIdx.x;

    float kj = (tid < Ndim) ? kbuf[tid * Bdim + b] : -1e30f;
    red[tid] = kj;
    __syncthreads();
    #pragma unroll
    for (int s = 128; s > 0; s >>= 1) {
        if (tid < s) red[tid] = fmaxf(red[tid], red[tid + s]);
        __syncthreads();
    }
    float kmax = red[0];
    if (tid < Ndim) ek[tid] = expf(kj - kmax);
    __syncthreads();
    if (tid < Ndim) {
        const uint8_t* ar = adj + ((size_t)b * Ndim + tid) * Ndim;
        float s = 0.f;
        for (int j = 0; j < Ndim; ++j) if (ar[j]) s += ek[j];
        rden[tid] = 1.f / s;   // diagonal always allowed -> s > 0
    }
    __syncthreads();
    for (int idx = tid; idx < Ndim * Ndim; idx += 256) {
        int i = idx / Ndim, j = idx - i * Ndim;
        float a = adj[((size_t)b * Ndim + i) * Ndim + j] ? ek[j] * rden[i] : 0.f;
        int s = smask[((size_t)b * Ndim + i) * Ndim + j];
        P0[i][j] = s ? a : 0.f;
        P1[i][j] = s ? 0.f : a;
    }
    __syncthreads();

    const int ti = tid >> 4, td = tid & 15;
    const int i0 = ti * 6, dbase = td * 6;
    for (int p = 0; p < 4; ++p) {
        const int d0 = p * 96;
        const int dw = (p == 3) ? (HDdim - 288) : 96;
        for (int idx = tid; idx < 96 * 24; idx += 256) {
            int j = idx / 24, q4 = (idx - j * 24) * 4;
            if (q4 < dw) {
                size_t g = ((size_t)(j * Bdim + b)) * (2 * HDdim) + d0 + q4;
                *(float4*)&Vs0[j][q4] = *(const float4*)(V + g);
                *(float4*)&Vs1[j][q4] = *(const float4*)(V + g + HDdim);
            }
        }
        __syncthreads();
        float acc[6][6];
        #pragma unroll
        for (int ii = 0; ii < 6; ++ii)
            #pragma unroll
            for (int dd = 0; dd < 6; ++dd) acc[ii][dd] = 0.f;
        for (int j = 0; j < Ndim; j += 2) {
            float2 pa[6], pb[6];
            #pragma unroll
            for (int ii = 0; ii < 6; ++ii) {
                pa[ii] = *(const float2*)&P0[i0 + ii][j];
                pb[ii] = *(const float2*)&P1[i0 + ii][j];
            }
            float2 v0a[3], v0b[3], v1a[3], v1b[3];
            #pragma unroll
            for (int dd = 0; dd < 3; ++dd) {
                v0a[dd] = *(const float2*)&Vs0[j][dbase + 2 * dd];
                v0b[dd] = *(const float2*)&Vs0[j + 1][dbase + 2 * dd];
                v1a[dd] = *(const float2*)&Vs1[j][dbase + 2 * dd];
                v1b[dd] = *(const float2*)&Vs1[j + 1][dbase + 2 * dd];
            }
            #pragma unroll
            for (int ii = 0; ii < 6; ++ii)
                #pragma unroll
                for (int dd = 0; dd < 3; ++dd) {
                    acc[ii][2*dd]   += pa[ii].x * v0a[dd].x + pb[ii].x * v1a[dd].x
                                     + pa[ii].y * v0b[dd].x + pb[ii].y * v1b[dd].x;
                    acc[ii][2*dd+1] += pa[ii].x * v0a[dd].y + pb[ii].x * v1a[dd].y
                                     + pa[ii].y * v0b[dd].y + pb[ii].y * v1b[dd].y;
                }
        }
        __syncthreads();
        #pragma unroll
        for (int ii = 0; ii < 6; ++ii) {
            #pragma unroll
            for (int dd = 0; dd < 6; ++dd) {
                int d = dbase + dd;
                if (d < dw)
                    Mout[((size_t)((i0 + ii) * Bdim + b)) * GDdim + d0 + d] = acc[ii][dd];
            }
        }
    }
}

// ---------------------------------------------------------------------------
// Per-step LSTM (round-13 proven: double-buffered LDS, one barrier per
// k-chunk) + T14 async-split + Hlstm-slice ping-pong (round 15 verified).
// Tile 32 batch x 64 gate-cols, grid (8,38).
// ---------------------------------------------------------------------------
__global__ __launch_bounds__(256) void lstm_mfma3(
    const u16* __restrict__ hH, const u16* __restrict__ hL,
    const float* __restrict__ cin,
    const u16* __restrict__ WH, const u16* __restrict__ WL,   // (2432 x 608)
    const float* __restrict__ zt,
    u16* __restrict__ hHo, u16* __restrict__ hLo,
    float* __restrict__ cout)
{
    __shared__ u16 AsH[2][4][256];
    __shared__ u16 AsL[2][4][256];
    __shared__ u16 WsH[2][4][512];
    __shared__ u16 WsL[2][4][512];
    __shared__ __align__(16) float gates[32][68];
    const int tid = threadIdx.x;
    const int bm = blockIdx.x * 32;
    const int bn = blockIdx.y * 64;
    const int wv = tid >> 6;
    const int lane = tid & 63;
    const int l15 = lane & 15;
    const int kseg = lane >> 4;
    const float4 fz = make_float4(0.f, 0.f, 0.f, 0.f);

    // --- T14: issue cell-phase loads NOW; consumed after the k-loop ---
    const int prow0 = tid >> 4,        pui0 = tid & 15;
    const int prow1 = (tid + 256) >> 4, pui1 = tid & 15;     // cell1 = tid+256
    const int pn0 = bn + pui0 * 4,  pn1 = bn + pui1 * 4;
    const int pu0 = pn0 >> 2,       pu1 = pn1 >> 2;
    const bool ok0 = (pu0 < LHdim), ok1 = (pu1 < LHdim);
    const int bb0 = bm + prow0,     bb1 = bm + prow1;
    float4 z0 = ok0 ? *(const float4*)(zt + (size_t)bb0 * (4 * LHdim) + pn0) : fz;
    float4 z1 = ok1 ? *(const float4*)(zt + (size_t)bb1 * (4 * LHdim) + pn1) : fz;
    float ci0 = ok0 ? cin[bb0 * LHdim + pu0] : 0.f;
    float ci1 = ok1 ? cin[bb1 * LHdim + pu1] : 0.f;

    // A staging: tid<128 -> AsH, else AsL; each thread one bf16x8
    const int av = tid & 127;
    const int arow = av >> 2, akc = av & 3;
    const u16* asrc = ((tid < 128) ? hH : hL) + (size_t)(bm + arow) * 608 + akc * 8;
    const int aoff = akc * 256 + arow * 8;
    // W staging: each thread one bf16x8 of WsH and WsL
    const int wrow = tid >> 2, wkc = tid & 3;
    const u16* wsrcH = WH + (size_t)(bn + wrow) * 608 + wkc * 8;
    const u16* wsrcL = WL + (size_t)(bn + wrow) * 608 + wkc * 8;
    const int woff2 = wrow * 8;

    f32x4 acc[2];
    acc[0] = (f32x4){0.f,0.f,0.f,0.f};
    acc[1] = (f32x4){0.f,0.f,0.f,0.f};

    // preload chunk 0
    bf16x8 ra  = *(const bf16x8*)(asrc);
    bf16x8 rwh = *(const bf16x8*)(wsrcH);
    bf16x8 rwl = *(const bf16x8*)(wsrcL);

    #pragma unroll
    for (int kc = 0; kc < 19; ++kc) {
        const int buf = kc & 1;
        *(bf16x8*)(((tid < 128) ? &AsH[buf][0][0] : &AsL[buf][0][0]) + aoff) = ra;
        *(bf16x8*)(&WsH[buf][wkc][woff2]) = rwh;
        *(bf16x8*)(&WsL[buf][wkc][woff2]) = rwl;
        if (kc + 1 < 19) {                      // prefetch next chunk
            ra  = *(const bf16x8*)(asrc + (kc + 1) * 32);
            rwh = *(const bf16x8*)(wsrcH + (kc + 1) * 32);
            rwl = *(const bf16x8*)(wsrcL + (kc + 1) * 32);
        }
        __syncthreads();                        // single barrier per chunk
        bf16x8 aH[2], aL[2], bH, bL;
        #pragma unroll
        for (int i = 0; i < 2; ++i) {
            int arr = i * 16 + l15;
            aH[i] = *(const bf16x8*)&AsH[buf][kseg][arr * 8];
            aL[i] = *(const bf16x8*)&AsL[buf][kseg][arr * 8];
        }
        {
            int br = wv * 16 + l15;
            bH = *(const bf16x8*)&WsH[buf][kseg][br * 8];
            bL = *(const bf16x8*)&WsL[buf][kseg][br * 8];
        }
        #pragma unroll
        for (int i = 0; i < 2; ++i) {
            acc[i] = __builtin_amdgcn_mfma_f32_16x16x32_bf16(aH[i], bH, acc[i], 0, 0, 0);
            acc[i] = __builtin_amdgcn_mfma_f32_16x16x32_bf16(aH[i], bL, acc[i], 0, 0, 0);
            acc[i] = __builtin_amdgcn_mfma_f32_16x16x32_bf16(aL[i], bH, acc[i], 0, 0, 0);
        }
    }

    const int r4 = (lane >> 4) * 4;
    __syncthreads();
    #pragma unroll
    for (int i = 0; i < 2; ++i)
        #pragma unroll
        for (int rr = 0; rr < 4; ++rr)
            gates[i * 16 + r4 + rr][wv * 16 + l15] = acc[i][rr];
    __syncthreads();

    // fused cell: 2 cells per thread, using prefetched z/c
    if (ok0) {
        float4 g = *(const float4*)&gates[prow0][pui0 * 4];
        float gi = g.x + z0.x;
        float gf = g.y + z0.y;
        float gg = g.z + z0.z;
        float go = g.w + z0.w;
        float si = 1.f / (1.f + expf(-gi));
        float sf = 1.f / (1.f + expf(-gf));
        float so = 1.f / (1.f + expf(-go));
        float cn = sf * ci0 + si * tanhf(gg);
        float hn = so * tanhf(cn);
        cout[bb0 * LHdim + pu0] = cn;
        u16 hh = f2bf(hn);
        hHo[(size_t)bb0 * 608 + pu0] = hh;
        hLo[(size_t)bb0 * 608 + pu0] = f2bf(hn - bf2f(hh));
    }
    if (ok1) {
        float4 g = *(const float4*)&gates[prow1][pui1 * 4];
        float gi = g.x + z1.x;
        float gf = g.y + z1.y;
        float gg = g.z + z1.z;
        float go = g.w + z1.w;
        float si = 1.f / (1.f + expf(-gi));
        float sf = 1.f / (1.f + expf(-gf));
        float so = 1.f / (1.f + expf(-go));
        float cn = sf * ci1 + si * tanhf(gg);
        float hn = so * tanhf(cn);
        cout[bb1 * LHdim + pu1] = cn;
        u16 hh = f2bf(hn);
        hHo[(size_t)bb1 * 608 + pu1] = hh;
        hLo[(size_t)bb1 * 608 + pu1] = f2bf(hn - bf2f(hh));
    }
}

__global__ __launch_bounds__(256) void out_kernel(
    const float* __restrict__ x, int ldx, const float* __restrict__ ow,
    const float* __restrict__ ob, float* __restrict__ out)
{
    int r    = blockIdx.x * 4 + (threadIdx.x >> 6);
    int lane = threadIdx.x & 63;
    const float* xr = x + (size_t)r * ldx;
    float acc[NCdim];
    #pragma unroll
    for (int n = 0; n < NCdim; ++n) acc[n] = 0.f;
    for (int t = lane; t < HDdim; t += 64) {
        float xv = xr[t];
        #pragma unroll
        for (int n = 0; n < NCdim; ++n) acc[n] = fmaf(xv, ow[n * HDdim + t], acc[n]);
    }
    #pragma unroll
    for (int o = 32; o > 0; o >>= 1)
        #pragma unroll
        for (int n = 0; n < NCdim; ++n) acc[n] += __shfl_down(acc[n], o);
    if (lane == 0) {
        int b = r & 255, nn = r >> 8;
        #pragma unroll
        for (int n = 0; n < NCdim; ++n) out[((size_t)b * Ndim + nn) * NCdim + n] = acc[n] + ob[n];
    }
}

// ---------------------------------------------------------------------------
extern "C" void kernel_launch(void* const* d_in, const int* in_sizes, int n_in,
                              void* d_out, int out_size, void* d_ws, size_t ws_size,
                              hipStream_t stream)
{
    const float*  features  = (const float*)d_in[0];
    const int*    s_mask    = (const int*)  d_in[1];
    const float*  entro     = (const float*)d_in[2];
    const float*  alpha     = (const float*)d_in[3];
    const float*  threshold = (const float*)d_in[4];
    const float*  fc1_w     = (const float*)d_in[5];
    const float*  fc1_b     = (const float*)d_in[6];
    const float*  gat_w     = (const float*)d_in[7];
    const float*  gat_b     = (const float*)d_in[8];
    const float*  wr0       = (const float*)d_in[9];
    const float*  wr1       = (const float*)d_in[10];
    const float*  enhance_w = (const float*)d_in[11];
    const float*  enhance_b = (const float*)d_in[12];
    const float*  prelu_a   = (const float*)d_in[13];
    const float*  lstm_w_ih = (const float*)d_in[14];
    const float*  lstm_w_hh = (const float*)d_in[15];
    const float*  lstm_b_ih = (const float*)d_in[16];
    const float*  lstm_b_hh = (const float*)d_in[17];
    const float*  mlp_w0    = (const float*)d_in[18];
    const float*  mlp_b0    = (const float*)d_in[19];
    const float*  mlp_a0    = (const float*)d_in[20];
    const float*  mlp_w1    = (const float*)d_in[21];
    const float*  mlp_b1    = (const float*)d_in[22];
    const float*  mlp_a1    = (const float*)d_in[23];
    const float*  out_w     = (const float*)d_in[24];
    const float*  out_b     = (const float*)d_in[25];
    float* out = (float*)d_out;
    char* ws = (char*)d_ws;
    (void)gat_b;

    // ---- fixed workspace layout (bytes, 256-aligned) ----
    uint8_t* adj   = (uint8_t*)(ws + 0);               //  2,359,296
    float*   invn  = (float*)(ws + 2359296);
    float*   kbuf  = (float*)(ws + 2555904);
    float*   biasP = (float*)(ws + 2654208);
    float*   c0    = (float*)(ws + 2663936);           //    614,400
    float*   c1    = (float*)(ws + 3278336);
    u16*     WhhPH = (u16*)(ws + 5137920);             //  2,957,312 (2432 x 608)
    u16*     WhhPL = (u16*)(ws + 8095232);
    u16*     WihPH = (u16*)(ws + 11052544);            //  9,494,528 (2432 x 1952)
    u16*     WihPL = (u16*)(ws + 20547072);
    u16*     EwH   = (u16*)(ws + 30041600);            //  2,097,152 (1024 x 1024)
    u16*     EwL   = (u16*)(ws + 32138752);
    u16*     Fc1H  = (u16*)(ws + 34235904);            //    786,432 (384 x 1024)
    u16*     Fc1L  = (u16*)(ws + 35022336);
    float*   Wr2f  = (float*)(ws + 35808768);          //  1,440,256 (2 x 600 x 300)
    u16*     Wr2H  = (u16*)(ws + 37249024);            //    819,200 (2 x 640 x 320)
    u16*     Wr2L  = (u16*)(ws + 38068224);
    u16*     Wm0H  = (u16*)(ws + 38887424);            //    524,288 (384 x 608)
    u16*     Wm0L  = (u16*)(ws + 39411712);
    u16*     Wm1H  = (u16*)(ws + 39936000);            //    262,144 (384 x 320)
    u16*     Wm1L  = (u16*)(ws + 40198144);
    u16*     FfH   = (u16*)(ws + 40460288);            // 50,331,648 (ROWS x 1024)
    u16*     FfL   = (u16*)(ws + 90791936);
    float*   Hcat  = (float*)(ws + 141123584);         // 88,473,600 (ROWS,900) n-major
    u16*     HsH   = (u16*)(ws + 229597184);           // 15,728,640 (ROWS x 320)
    u16*     HsL   = (u16*)(ws + 245325824);
    // V (GAT, fp32 ROWSx600) aliases Hlstm (97 slices x 256 x 608 split bf16)
    float*   V      = (float*)(ws + 261054464);        // 58,982,400
    u16*     HlstmH = (u16*)(ws + 261054464);          // 30,195,712 (97 slices)
    u16*     HlstmL = (u16*)(ws + 291250176);          // 30,195,712 -> 321,445,888
    // MLP scratch aliases Hcat (dead after last Hcat split)
    u16*     x1H   = (u16*)Hcat;                       // 15,728,640 (ROWS x 320)
    u16*     x1L   = (u16*)(ws + 141123584 + 15728640);
    float*   x2    = (float*)(ws + 141123584 + 31457280);   // 29,884,416 (ROWS x 304)

    // ---- tier selection for chunked seq/zin region ----
    const size_t fixedNeed = 321445888ull;
    const size_t perT = 4456448ull;                    // zin(2,457,600)+seqH/L(1,998,848)
    int T;
    if      (ws_size >= fixedNeed + 96ull * perT) T = 96;
    else if (ws_size >= fixedNeed + 48ull * perT) T = 48;
    else if (ws_size >= fixedNeed + 32ull * perT) T = 32;
    else if (ws_size >= fixedNeed + 16ull * perT) T = 16;
    else if (ws_size >= fixedNeed +  8ull * perT) T = 8;
    else return;                                       // visible failure, no OOB
    char* cr = ws + fixedNeed;
    float* zin  = (float*)cr;                                // (Mc,2400)
    u16*   seqH = (u16*)(cr + (size_t)T * 2457600);          // (Mc,1952)
    u16*   seqL = (u16*)(cr + (size_t)T * 2457600 + (size_t)T * 999424);

    // 1) norms + adjacency
    norm_kernel<<<ROWS / 4, 256, 0, stream>>>(features, invn);
    simadj_kernel<<<Bdim, 256, 0, stream>>>(features, invn, entro, alpha, threshold, adj);

    // 2) weight/activation conversions
    split_rows8<<<dim3(2, ROWS / 4), 256, 0, stream>>>(            // features n-major full
        features, Edim, 255, Ndim, 8, 1, 0, FfH, FfL, Edim, Edim, Edim, ROWS);
    split_rows8<<<dim3(2, 96), 256, 0, stream>>>(                  // fc1_w (384x1024)
        fc1_w, Edim, IDP, Fc1H, Fc1L, Edim, Edim, Edim, HDdim);
    split_rows8<<<dim3(2, 256), 256, 0, stream>>>(                 // enhance_w
        enhance_w, Edim, IDP, EwH, EwL, Edim, Edim, Edim, Edim);
    split_rows8<<<dim3(4, 608), 256, 0, stream>>>(                 // Wih gate-interleaved
        lstm_w_ih, Edim + GDdim, 3, LHdim, 2, 1, 0, WihPH, WihPL, 1952, 1952, 1924, 2400);
    split_rows8<<<dim3(2, 608), 256, 0, stream>>>(                 // Whh gate-interleaved
        lstm_w_hh, LHdim, 3, LHdim, 2, 1, 0, WhhPH, WhhPL, 608, 608, LHdim, 2400);
    split_rows8<<<dim3(2, 96), 256, 0, stream>>>(                  // mlp_w0 (384x608)
        mlp_w0, LHdim, IDP, Wm0H, Wm0L, 608, 608, LHdim, HDdim);
    split_rows8<<<dim3(1, 96), 256, 0, stream>>>(                  // mlp_w1 (384x320)
        mlp_w1, HDdim, IDP, Wm1H, Wm1L, 320, 320, HDdim, HDdim);
    wr_cat<<<dim3(2, 2 * Ldim * HDdim), 256, 0, stream>>>(wr0, wr1, Wr2f);
    for (int l = 0; l < Ldim; ++l)
        split_rows8<<<dim3(1, 160), 256, 0, stream>>>(             // Wr2 (640x320 per layer)
            Wr2f + (size_t)l * 2 * HDdim * HDdim, HDdim, IDP,
            Wr2H + (size_t)l * 640 * 320, Wr2L + (size_t)l * 640 * 320,
            320, 320, HDdim, 2 * HDdim);
    bias_perm<<<10, 256, 0, stream>>>(lstm_b_ih, lstm_b_hh, biasP);
    zero_range<<<1200, 256, 0, stream>>>(c0, 307200);              // c0, c1

    // 3) H0 = prelu(features @ fc1_w^T + fc1_b) -> Hcat[:, 0:300] (MFMA)
    gemm_mfma3<0,1><<<dim3(ROWS/128, 3), 256, 0, stream>>>(
        FfH, FfL, Edim, Fc1H, Fc1L, Edim,
        Hcat, nullptr, nullptr, GDdim, ROWS, HDdim, Edim, fc1_b, prelu_a);

    // 4) GAT layers (MFMA V projection, fused softmax+aggregation)
    for (int l = 0; l < Ldim; ++l) {
        const float* Hsrc = Hcat + l * HDdim;
        k_kernel<<<ROWS / 4, 256, 0, stream>>>(Hsrc, gat_w + l * 2 * HDdim + HDdim, kbuf);
        split_rows8<<<dim3(1, ROWS / 4), 256, 0, stream>>>(        // Hsrc -> split (K=320)
            Hsrc, GDdim, IDP, HsH, HsL, 320, 320, HDdim, ROWS);
        gemm_mfma3<0,0><<<dim3(ROWS/128, 5), 256, 0, stream>>>(
            HsH, HsL, 320, Wr2H + (size_t)l * 640 * 320, Wr2L + (size_t)l * 640 * 320, 320,
            V, nullptr, nullptr, 2 * HDdim, ROWS, 2 * HDdim, 320, nullptr, nullptr);
        gat_fused<<<Bdim, 256, 0, stream>>>(
            kbuf, adj, s_mask, V, Hcat + (l + 1) * HDdim);
    }

    // 5) zero Hlstm split region (pads + slice 0 = h_0; aliased V until now)
    zero_range<<<58976, 256, 0, stream>>>((float*)HlstmH, 15097856);

    // 6) chunked: enhance (pure bf16) -> Hcat split -> zin (pure bf16) -> LSTM
    int cur = 0;
    float* cb_[2] = {c0, c1};
    for (int t0 = 0; t0 < Ndim; t0 += T) {
        int Mc = T * Bdim;
        gemm_bf16<1,1><<<dim3(Mc/128, 8), 256, 0, stream>>>(       // single-bf16 enhance
            FfH + (size_t)t0 * Bdim * Edim, Edim, EwH, Edim,
            nullptr, seqH, seqL, 1952, Mc, Edim, Edim, enhance_b, prelu_a);
        split_rows8<<<dim3(2, Mc / 4), 256, 0, stream>>>(
            Hcat, GDdim, 0x7FFFFFFF, 1, 30, 0, t0 * Bdim,
            seqH + 1024, seqL + 1024, 1952, 928, GDdim, Mc);
        gemm_bf16<0,0><<<dim3(Mc/128, 19), 256, 0, stream>>>(      // single-bf16 zin
            seqH, 1952, WihPH, 1952,
            zin, nullptr, nullptr, 4 * LHdim, Mc, 4 * LHdim, 1952, biasP, nullptr);
        for (int tl = 0; tl < T; ++tl) {
            const int g = t0 + tl;                    // global step, 0-based
            lstm_mfma3<<<dim3(8, 38), 256, 0, stream>>>(
                HlstmH + (size_t)g * HSLICE, HlstmL + (size_t)g * HSLICE,
                cb_[cur], WhhPH, WhhPL,
                zin + (size_t)tl * Bdim * 4 * LHdim,
                HlstmH + (size_t)(g + 1) * HSLICE, HlstmL + (size_t)(g + 1) * HSLICE,
                cb_[cur ^ 1]);
            cur ^= 1;
        }
    }

    // 7) MLP head (MFMA, A = Hlstm slices 1..96) + output
    zero_range<<<30720, 256, 0, stream>>>((float*)x1H, 7864320);   // x1 pads must be 0
    gemm_mfma3<1,1><<<dim3(ROWS/128, 3), 256, 0, stream>>>(
        HlstmH + HSLICE, HlstmL + HSLICE, 608, Wm0H, Wm0L, 608,
        nullptr, x1H, x1L, 320, ROWS, HDdim, 608, mlp_b0, mlp_a0);
    gemm_mfma3<0,1><<<dim3(ROWS/128, 3), 256, 0, stream>>>(
        x1H, x1L, 320, Wm1H, Wm1L, 320,
        x2, nullptr, nullptr, 304, ROWS, HDdim, 320, mlp_b1, mlp_a1);
    out_kernel<<<ROWS / 4, 256, 0, stream>>>(x2, 304, out_w, out_b, out);
}

// Round 20
// 3018.012 us; speedup vs baseline: 1.5366x; 1.0532x over previous
//
#include <hip/hip_runtime.h>
#include <cstdint>
#include <cstddef>

#define Bdim 256
#define Ndim 96
#define Edim 1024
#define HDdim 300
#define Ldim 2
#define LHdim 600
#define NCdim 7
#define GDdim 900              // HD*(L+1)
#define ROWS (Bdim*Ndim)       // 24576
#define HSLICE 155648          // 256*608 elements per Hlstm time-slice

typedef unsigned short u16;
typedef float f32x4 __attribute__((ext_vector_type(4)));
typedef short bf16x8 __attribute__((ext_vector_type(8)));

// Identity row-perm constants
#define IDP 0x7FFFFFFF, 1, 30, 0, 0

__device__ inline u16 f2bf(float x) {
    unsigned int u = __builtin_bit_cast(unsigned int, x);
    unsigned int r = (u + 0x7fffu + ((u >> 16) & 1u)) >> 16;   // RNE
    return (u16)r;
}
__device__ inline float bf2f(u16 h) {
    unsigned int u = ((unsigned int)h) << 16;
    return __builtin_bit_cast(float, u);
}

// ---------------------------------------------------------------------------
// Pure single-bf16 MFMA GEMM (m97-style: 2 LDS tiles, 16 MFMA/chunk),
// bx-major bijective XCD swizzle, reg->LDS staging.
// C = act(A·W^T + bias). K mult of 32; lda/ldw mult 8; M mult of 128;
// W must have gridDim.y*128 rows allocated (pad rows zeroed).
// OUT: 0 -> fp32 C; 1 -> split bf16 (Ch,Cl). ACT: 1 -> prelu(aptr).
// (Epilogue-only templating; staging loop branch-free — round-16 lesson.)
// ---------------------------------------------------------------------------
template<int OUT, int ACT>
__global__ __launch_bounds__(256) void gemm_bf16(
    const u16* __restrict__ Ah, int lda,
    const u16* __restrict__ Wh, int ldw,
    float* __restrict__ C, u16* __restrict__ Ch, u16* __restrict__ Cl, int ldc,
    int M, int Nd, int K,
    const float* __restrict__ bias, const float* __restrict__ aptr)
{
    __shared__ u16 At[4][1024];
    __shared__ u16 Wt[4][1024];
    const int tid  = threadIdx.x;
    const int ny  = gridDim.y;
    const int nwg = gridDim.x * ny;
    const int lin = blockIdx.y * gridDim.x + blockIdx.x;
    const int q = nwg >> 3, r8 = nwg & 7;
    const int xcd = lin & 7, off = lin >> 3;
    const int swz = (xcd < r8) ? xcd * (q + 1) + off
                               : r8 * (q + 1) + (xcd - r8) * q + off;
    const int bm   = (swz / ny) * 128;
    const int bn   = (swz % ny) * 128;
    const int wv   = tid >> 6;
    const int lane = tid & 63;
    const int wr   = (wv >> 1) * 64;
    const int wc   = (wv & 1) * 64;
    const int l15  = lane & 15;
    const int kseg = lane >> 4;

    f32x4 acc[4][4];
    #pragma unroll
    for (int i = 0; i < 4; ++i)
        #pragma unroll
        for (int j = 0; j < 4; ++j) acc[i][j] = (f32x4){0.f,0.f,0.f,0.f};

    const int srow = tid & 127;
    const bool isA = (tid < 128);
    const int gr   = isA ? (bm + srow) : (bn + srow);
    const int glim = isA ? M : 0x7FFFFFFF;        // W pad rows allocated+zeroed
    const u16* pbase = (isA ? Ah : Wh) + (size_t)gr * (isA ? lda : ldw);
    u16* dst = isA ? &At[0][0] : &Wt[0][0];

    for (int k0 = 0; k0 < K; k0 += 32) {
        __syncthreads();
        {
            const bool ok = (gr < glim);
            #pragma unroll
            for (int s = 0; s < 4; ++s) {
                bf16x8 v = {0,0,0,0,0,0,0,0};
                if (ok) v = *(const bf16x8*)(pbase + k0 + s * 8);
                *(bf16x8*)(dst + s * 1024 + srow * 8) = v;
            }
        }
        __syncthreads();
        bf16x8 a[4], b[4];
        #pragma unroll
        for (int f = 0; f < 4; ++f) {
            int ar = wr + f * 16 + l15;
            int br = wc + f * 16 + l15;
            a[f] = *(const bf16x8*)&At[kseg][ar * 8];
            b[f] = *(const bf16x8*)&Wt[kseg][br * 8];
        }
        #pragma unroll
        for (int i = 0; i < 4; ++i)
            #pragma unroll
            for (int j = 0; j < 4; ++j)
                acc[i][j] = __builtin_amdgcn_mfma_f32_16x16x32_bf16(a[i], b[j], acc[i][j], 0, 0, 0);
    }

    const float av = (ACT == 1) ? *aptr : 0.f;
    const int r4 = (lane >> 4) * 4;
    #pragma unroll
    for (int j = 0; j < 4; ++j) {
        int col = bn + wc + j * 16 + l15;
        if (col >= Nd) continue;
        float bv = bias ? bias[col] : 0.f;
        #pragma unroll
        for (int i = 0; i < 4; ++i) {
            #pragma unroll
            for (int rr = 0; rr < 4; ++rr) {
                int row = bm + wr + i * 16 + r4 + rr;
                if (row >= M) continue;
                float v = acc[i][j][rr] + bv;
                if (ACT == 1) v = (v >= 0.f) ? v : av * v;
                if (OUT == 0) {
                    C[(size_t)row * ldc + col] = v;
                } else {
                    u16 h = f2bf(v);
                    Ch[(size_t)row * ldc + col] = h;
                    Cl[(size_t)row * ldc + col] = f2bf(v - bf2f(h));
                }
            }
        }
    }
}

// ---------------------------------------------------------------------------
// split fp32 -> bf16 hi/lo, vectorized: 4 rows/block, 8 cols/thread.
// ---------------------------------------------------------------------------
__global__ __launch_bounds__(256) void split_rows8(
    const float* __restrict__ src, int srcld,
    int pmask, int pmul1, int pshift, int pmul2, int padd,
    u16* __restrict__ dstH, u16* __restrict__ dstL, int dstld,
    int wcols, int validK, int validRows)
{
    const int r = blockIdx.y * 4 + (threadIdx.x >> 6);
    const int c = (blockIdx.x * 64 + (threadIdx.x & 63)) * 8;
    if (c >= wcols) return;
    const int sr = (r & pmask) * pmul1 + (r >> pshift) * pmul2 + padd;
    const float* s = src + (size_t)sr * srcld;
    const bool rok = (r < validRows);
    float v[8];
    if (rok && c + 8 <= validK) {
        *(float4*)&v[0] = *(const float4*)(s + c);
        *(float4*)&v[4] = *(const float4*)(s + c + 4);
    } else {
        #pragma unroll
        for (int u = 0; u < 8; ++u) v[u] = (rok && c + u < validK) ? s[c + u] : 0.f;
    }
    bf16x8 H8, L8;
    #pragma unroll
    for (int u = 0; u < 8; ++u) {
        u16 h = f2bf(v[u]);
        H8[u] = (short)h;
        L8[u] = (short)f2bf(v[u] - bf2f(h));
    }
    *(bf16x8*)(dstH + (size_t)r * dstld + c) = H8;
    *(bf16x8*)(dstL + (size_t)r * dstld + c) = L8;
}

// biasP[n'] = b_ih[orig]+b_hh[orig], orig = (n'&3)*600+(n'>>2)
__global__ __launch_bounds__(256) void bias_perm(
    const float* __restrict__ bih, const float* __restrict__ bhh, float* __restrict__ dst)
{
    int n = blockIdx.x * 256 + threadIdx.x;
    if (n >= 4 * LHdim) return;
    int o = (n & 3) * LHdim + (n >> 2);
    dst[n] = bih[o] + bhh[o];
}

// Wr2f[l][r][c]: r<300 -> wr0[l][r][c], else wr1[l][r-300][c]
__global__ __launch_bounds__(256) void wr_cat(
    const float* __restrict__ wr0, const float* __restrict__ wr1, float* __restrict__ dst)
{
    int c = blockIdx.x * 256 + threadIdx.x;
    if (c >= HDdim) return;
    int lr = blockIdx.y;
    int l = lr / (2 * HDdim), r = lr % (2 * HDdim);
    const float* src = (r < HDdim)
        ? wr0 + ((size_t)l * HDdim + r) * HDdim
        : wr1 + ((size_t)l * HDdim + (r - HDdim)) * HDdim;
    dst[(size_t)lr * HDdim + c] = src[c];
}

__global__ __launch_bounds__(256) void zero_range(float* __restrict__ p, int n)
{
    int i = blockIdx.x * 256 + threadIdx.x;
    if (i < n) p[i] = 0.f;
}

// ---------------------------------------------------------------------------
__global__ __launch_bounds__(256) void norm_kernel(const float* __restrict__ f, float* __restrict__ invn)
{
    int row  = blockIdx.x * 4 + (threadIdx.x >> 6);
    int lane = threadIdx.x & 63;
    const float* fr = f + (size_t)row * Edim;
    float ss = 0.f;
    for (int t = lane; t < Edim; t += 64) { float v = fr[t]; ss = fmaf(v, v, ss); }
    #pragma unroll
    for (int o = 32; o > 0; o >>= 1) ss += __shfl_down(ss, o);
    if (lane == 0) invn[row] = 1.f / (sqrtf(ss) + 1e-8f);
}

__global__ __launch_bounds__(256) void simadj_kernel(
    const float* __restrict__ f, const float* __restrict__ invn,
    const float* __restrict__ entro, const float* __restrict__ alphap,
    const float* __restrict__ thrp, uint8_t* __restrict__ adj)
{
    int b = blockIdx.x;
    __shared__ float S[16][100];
    int tid = threadIdx.x;
    int i0 = (tid >> 4) * 6, j0 = (tid & 15) * 6;
    float acc[6][6];
    #pragma unroll
    for (int i = 0; i < 6; ++i)
        #pragma unroll
        for (int j = 0; j < 6; ++j) acc[i][j] = 0.f;
    const float* fb = f + (size_t)b * Ndim * Edim;

    for (int k0 = 0; k0 < Edim; k0 += 16) {
        __syncthreads();
        #pragma unroll
        for (int r = 0; r < 6; ++r) {
            int n = (tid >> 4) + r * 16;
            S[tid & 15][n] = fb[(size_t)n * Edim + k0 + (tid & 15)];
        }
        __syncthreads();
        #pragma unroll
        for (int kk = 0; kk < 16; ++kk) {
            float a[6], bb[6];
            #pragma unroll
            for (int u = 0; u < 6; ++u) a[u] = S[kk][i0 + u];
            #pragma unroll
            for (int u = 0; u < 6; ++u) bb[u] = S[kk][j0 + u];
            #pragma unroll
            for (int i = 0; i < 6; ++i)
                #pragma unroll
                for (int j = 0; j < 6; ++j)
                    acc[i][j] = fmaf(a[i], bb[j], acc[i][j]);
        }
    }

    float alpha = *alphap, thr = *thrp;
    float onem = 1.f - alpha;
    #pragma unroll
    for (int i = 0; i < 6; ++i) {
        int ii = i0 + i;
        float inv_i = invn[b * Ndim + ii];
        #pragma unroll
        for (int j = 0; j < 6; ++j) {
            int jj = j0 + j;
            float simv = acc[i][j] * inv_i * invn[b * Ndim + jj];
            float comb = alpha * entro[b * Ndim + jj] + onem * simv;
            adj[((size_t)b * Ndim + ii) * Ndim + jj] = (comb > thr) ? 1 : 0;
        }
    }
}

// k[r] = H[r,:300] . wk   (q cancels in the adjacency softmax; not computed)
__global__ __launch_bounds__(256) void k_kernel(
    const float* __restrict__ Hsrc, const float* __restrict__ wk,
    float* __restrict__ k)
{
    int row  = blockIdx.x * 4 + (threadIdx.x >> 6);
    int lane = threadIdx.x & 63;
    const float* h = Hsrc + (size_t)row * GDdim;
    float sk = 0.f;
    for (int t = lane; t < HDdim; t += 64) sk = fmaf(h[t], wk[t], sk);
    #pragma unroll
    for (int o = 32; o > 0; o >>= 1) sk += __shfl_down(sk, o);
    if (lane == 0) k[row] = sk;
}

// ---------------------------------------------------------------------------
// Fused GAT attention for one batch b (q, gat_b cancel in softmax).
// V combined: cols 0..299 = V0, 300..599 = V1, row stride 600 (n-major rows).
// ---------------------------------------------------------------------------
__global__ __launch_bounds__(256) void gat_fused(
    const float* __restrict__ kbuf, const uint8_t* __restrict__ adj,
    const int* __restrict__ smask,
    const float* __restrict__ V,
    float* __restrict__ Mout)
{
    __shared__ float P0[96][98];
    __shared__ float P1[96][98];
    __shared__ float Vs0[96][96];
    __shared__ float Vs1[96][96];
    __shared__ float ek[96];
    __shared__ float rden[96];
    __shared__ float red[256];
    const int b = blockIdx.x;
    const int tid = threadIdx.x;

    float kj = (tid < Ndim) ? kbuf[tid * Bdim + b] : -1e30f;
    red[tid] = kj;
    __syncthreads();
    #pragma unroll
    for (int s = 128; s > 0; s >>= 1) {
        if (tid < s) red[tid] = fmaxf(red[tid], red[tid + s]);
        __syncthreads();
    }
    float kmax = red[0];
    if (tid < Ndim) ek[tid] = expf(kj - kmax);
    __syncthreads();
    if (tid < Ndim) {
        const uint8_t* ar = adj + ((size_t)b * Ndim + tid) * Ndim;
        float s = 0.f;
        for (int j = 0; j < Ndim; ++j) if (ar[j]) s += ek[j];
        rden[tid] = 1.f / s;   // diagonal always allowed -> s > 0
    }
    __syncthreads();
    for (int idx = tid; idx < Ndim * Ndim; idx += 256) {
        int i = idx / Ndim, j = idx - i * Ndim;
        float a = adj[((size_t)b * Ndim + i) * Ndim + j] ? ek[j] * rden[i] : 0.f;
        int s = smask[((size_t)b * Ndim + i) * Ndim + j];
        P0[i][j] = s ? a : 0.f;
        P1[i][j] = s ? 0.f : a;
    }
    __syncthreads();

    const int ti = tid >> 4, td = tid & 15;
    const int i0 = ti * 6, dbase = td * 6;
    for (int p = 0; p < 4; ++p) {
        const int d0 = p * 96;
        const int dw = (p == 3) ? (HDdim - 288) : 96;
        for (int idx = tid; idx < 96 * 24; idx += 256) {
            int j = idx / 24, q4 = (idx - j * 24) * 4;
            if (q4 < dw) {
                size_t g = ((size_t)(j * Bdim + b)) * (2 * HDdim) + d0 + q4;
                *(float4*)&Vs0[j][q4] = *(const float4*)(V + g);
                *(float4*)&Vs1[j][q4] = *(const float4*)(V + g + HDdim);
            }
        }
        __syncthreads();
        float acc[6][6];
        #pragma unroll
        for (int ii = 0; ii < 6; ++ii)
            #pragma unroll
            for (int dd = 0; dd < 6; ++dd) acc[ii][dd] = 0.f;
        for (int j = 0; j < Ndim; j += 2) {
            float2 pa[6], pb[6];
            #pragma unroll
            for (int ii = 0; ii < 6; ++ii) {
                pa[ii] = *(const float2*)&P0[i0 + ii][j];
                pb[ii] = *(const float2*)&P1[i0 + ii][j];
            }
            float2 v0a[3], v0b[3], v1a[3], v1b[3];
            #pragma unroll
            for (int dd = 0; dd < 3; ++dd) {
                v0a[dd] = *(const float2*)&Vs0[j][dbase + 2 * dd];
                v0b[dd] = *(const float2*)&Vs0[j + 1][dbase + 2 * dd];
                v1a[dd] = *(const float2*)&Vs1[j][dbase + 2 * dd];
                v1b[dd] = *(const float2*)&Vs1[j + 1][dbase + 2 * dd];
            }
            #pragma unroll
            for (int ii = 0; ii < 6; ++ii)
                #pragma unroll
                for (int dd = 0; dd < 3; ++dd) {
                    acc[ii][2*dd]   += pa[ii].x * v0a[dd].x + pb[ii].x * v1a[dd].x
                                     + pa[ii].y * v0b[dd].x + pb[ii].y * v1b[dd].x;
                    acc[ii][2*dd+1] += pa[ii].x * v0a[dd].y + pb[ii].x * v1a[dd].y
                                     + pa[ii].y * v0b[dd].y + pb[ii].y * v1b[dd].y;
                }
        }
        __syncthreads();
        #pragma unroll
        for (int ii = 0; ii < 6; ++ii) {
            #pragma unroll
            for (int dd = 0; dd < 6; ++dd) {
                int d = dbase + dd;
                if (d < dw)
                    Mout[((size_t)((i0 + ii) * Bdim + b)) * GDdim + d0 + d] = acc[ii][dd];
            }
        }
    }
}

// ---------------------------------------------------------------------------
// Per-step LSTM (round-13 proven: double-buffered LDS, one barrier per
// k-chunk) + T14 async-split + Hlstm-slice ping-pong (round 15 verified).
// Tile 32 batch x 64 gate-cols, grid (8,38).
// ---------------------------------------------------------------------------
__global__ __launch_bounds__(256) void lstm_mfma3(
    const u16* __restrict__ hH, const u16* __restrict__ hL,
    const float* __restrict__ cin,
    const u16* __restrict__ WH, const u16* __restrict__ WL,   // (2432 x 608)
    const float* __restrict__ zt,
    u16* __restrict__ hHo, u16* __restrict__ hLo,
    float* __restrict__ cout)
{
    __shared__ u16 AsH[2][4][256];
    __shared__ u16 AsL[2][4][256];
    __shared__ u16 WsH[2][4][512];
    __shared__ u16 WsL[2][4][512];
    __shared__ __align__(16) float gates[32][68];
    const int tid = threadIdx.x;
    const int bm = blockIdx.x * 32;
    const int bn = blockIdx.y * 64;
    const int wv = tid >> 6;
    const int lane = tid & 63;
    const int l15 = lane & 15;
    const int kseg = lane >> 4;
    const float4 fz = make_float4(0.f, 0.f, 0.f, 0.f);

    // --- T14: issue cell-phase loads NOW; consumed after the k-loop ---
    const int prow0 = tid >> 4,        pui0 = tid & 15;
    const int prow1 = (tid + 256) >> 4, pui1 = tid & 15;     // cell1 = tid+256
    const int pn0 = bn + pui0 * 4,  pn1 = bn + pui1 * 4;
    const int pu0 = pn0 >> 2,       pu1 = pn1 >> 2;
    const bool ok0 = (pu0 < LHdim), ok1 = (pu1 < LHdim);
    const int bb0 = bm + prow0,     bb1 = bm + prow1;
    float4 z0 = ok0 ? *(const float4*)(zt + (size_t)bb0 * (4 * LHdim) + pn0) : fz;
    float4 z1 = ok1 ? *(const float4*)(zt + (size_t)bb1 * (4 * LHdim) + pn1) : fz;
    float ci0 = ok0 ? cin[bb0 * LHdim + pu0] : 0.f;
    float ci1 = ok1 ? cin[bb1 * LHdim + pu1] : 0.f;

    // A staging: tid<128 -> AsH, else AsL; each thread one bf16x8
    const int av = tid & 127;
    const int arow = av >> 2, akc = av & 3;
    const u16* asrc = ((tid < 128) ? hH : hL) + (size_t)(bm + arow) * 608 + akc * 8;
    const int aoff = akc * 256 + arow * 8;
    // W staging: each thread one bf16x8 of WsH and WsL
    const int wrow = tid >> 2, wkc = tid & 3;
    const u16* wsrcH = WH + (size_t)(bn + wrow) * 608 + wkc * 8;
    const u16* wsrcL = WL + (size_t)(bn + wrow) * 608 + wkc * 8;
    const int woff2 = wrow * 8;

    f32x4 acc[2];
    acc[0] = (f32x4){0.f,0.f,0.f,0.f};
    acc[1] = (f32x4){0.f,0.f,0.f,0.f};

    // preload chunk 0
    bf16x8 ra  = *(const bf16x8*)(asrc);
    bf16x8 rwh = *(const bf16x8*)(wsrcH);
    bf16x8 rwl = *(const bf16x8*)(wsrcL);

    #pragma unroll
    for (int kc = 0; kc < 19; ++kc) {
        const int buf = kc & 1;
        *(bf16x8*)(((tid < 128) ? &AsH[buf][0][0] : &AsL[buf][0][0]) + aoff) = ra;
        *(bf16x8*)(&WsH[buf][wkc][woff2]) = rwh;
        *(bf16x8*)(&WsL[buf][wkc][woff2]) = rwl;
        if (kc + 1 < 19) {                      // prefetch next chunk
            ra  = *(const bf16x8*)(asrc + (kc + 1) * 32);
            rwh = *(const bf16x8*)(wsrcH + (kc + 1) * 32);
            rwl = *(const bf16x8*)(wsrcL + (kc + 1) * 32);
        }
        __syncthreads();                        // single barrier per chunk
        bf16x8 aH[2], aL[2], bH, bL;
        #pragma unroll
        for (int i = 0; i < 2; ++i) {
            int arr = i * 16 + l15;
            aH[i] = *(const bf16x8*)&AsH[buf][kseg][arr * 8];
            aL[i] = *(const bf16x8*)&AsL[buf][kseg][arr * 8];
        }
        {
            int br = wv * 16 + l15;
            bH = *(const bf16x8*)&WsH[buf][kseg][br * 8];
            bL = *(const bf16x8*)&WsL[buf][kseg][br * 8];
        }
        #pragma unroll
        for (int i = 0; i < 2; ++i) {
            acc[i] = __builtin_amdgcn_mfma_f32_16x16x32_bf16(aH[i], bH, acc[i], 0, 0, 0);
            acc[i] = __builtin_amdgcn_mfma_f32_16x16x32_bf16(aH[i], bL, acc[i], 0, 0, 0);
            acc[i] = __builtin_amdgcn_mfma_f32_16x16x32_bf16(aL[i], bH, acc[i], 0, 0, 0);
        }
    }

    const int r4 = (lane >> 4) * 4;
    __syncthreads();
    #pragma unroll
    for (int i = 0; i < 2; ++i)
        #pragma unroll
        for (int rr = 0; rr < 4; ++rr)
            gates[i * 16 + r4 + rr][wv * 16 + l15] = acc[i][rr];
    __syncthreads();

    // fused cell: 2 cells per thread, using prefetched z/c
    if (ok0) {
        float4 g = *(const float4*)&gates[prow0][pui0 * 4];
        float gi = g.x + z0.x;
        float gf = g.y + z0.y;
        float gg = g.z + z0.z;
        float go = g.w + z0.w;
        float si = 1.f / (1.f + expf(-gi));
        float sf = 1.f / (1.f + expf(-gf));
        float so = 1.f / (1.f + expf(-go));
        float cn = sf * ci0 + si * tanhf(gg);
        float hn = so * tanhf(cn);
        cout[bb0 * LHdim + pu0] = cn;
        u16 hh = f2bf(hn);
        hHo[(size_t)bb0 * 608 + pu0] = hh;
        hLo[(size_t)bb0 * 608 + pu0] = f2bf(hn - bf2f(hh));
    }
    if (ok1) {
        float4 g = *(const float4*)&gates[prow1][pui1 * 4];
        float gi = g.x + z1.x;
        float gf = g.y + z1.y;
        float gg = g.z + z1.z;
        float go = g.w + z1.w;
        float si = 1.f / (1.f + expf(-gi));
        float sf = 1.f / (1.f + expf(-gf));
        float so = 1.f / (1.f + expf(-go));
        float cn = sf * ci1 + si * tanhf(gg);
        float hn = so * tanhf(cn);
        cout[bb1 * LHdim + pu1] = cn;
        u16 hh = f2bf(hn);
        hHo[(size_t)bb1 * 608 + pu1] = hh;
        hLo[(size_t)bb1 * 608 + pu1] = f2bf(hn - bf2f(hh));
    }
}

__global__ __launch_bounds__(256) void out_kernel(
    const float* __restrict__ x, int ldx, const float* __restrict__ ow,
    const float* __restrict__ ob, float* __restrict__ out)
{
    int r    = blockIdx.x * 4 + (threadIdx.x >> 6);
    int lane = threadIdx.x & 63;
    const float* xr = x + (size_t)r * ldx;
    float acc[NCdim];
    #pragma unroll
    for (int n = 0; n < NCdim; ++n) acc[n] = 0.f;
    for (int t = lane; t < HDdim; t += 64) {
        float xv = xr[t];
        #pragma unroll
        for (int n = 0; n < NCdim; ++n) acc[n] = fmaf(xv, ow[n * HDdim + t], acc[n]);
    }
    #pragma unroll
    for (int o = 32; o > 0; o >>= 1)
        #pragma unroll
        for (int n = 0; n < NCdim; ++n) acc[n] += __shfl_down(acc[n], o);
    if (lane == 0) {
        int b = r & 255, nn = r >> 8;
        #pragma unroll
        for (int n = 0; n < NCdim; ++n) out[((size_t)b * Ndim + nn) * NCdim + n] = acc[n] + ob[n];
    }
}

// ---------------------------------------------------------------------------
extern "C" void kernel_launch(void* const* d_in, const int* in_sizes, int n_in,
                              void* d_out, int out_size, void* d_ws, size_t ws_size,
                              hipStream_t stream)
{
    const float*  features  = (const float*)d_in[0];
    const int*    s_mask    = (const int*)  d_in[1];
    const float*  entro     = (const float*)d_in[2];
    const float*  alpha     = (const float*)d_in[3];
    const float*  threshold = (const float*)d_in[4];
    const float*  fc1_w     = (const float*)d_in[5];
    const float*  fc1_b     = (const float*)d_in[6];
    const float*  gat_w     = (const float*)d_in[7];
    const float*  gat_b     = (const float*)d_in[8];
    const float*  wr0       = (const float*)d_in[9];
    const float*  wr1       = (const float*)d_in[10];
    const float*  enhance_w = (const float*)d_in[11];
    const float*  enhance_b = (const float*)d_in[12];
    const float*  prelu_a   = (const float*)d_in[13];
    const float*  lstm_w_ih = (const float*)d_in[14];
    const float*  lstm_w_hh = (const float*)d_in[15];
    const float*  lstm_b_ih = (const float*)d_in[16];
    const float*  lstm_b_hh = (const float*)d_in[17];
    const float*  mlp_w0    = (const float*)d_in[18];
    const float*  mlp_b0    = (const float*)d_in[19];
    const float*  mlp_a0    = (const float*)d_in[20];
    const float*  mlp_w1    = (const float*)d_in[21];
    const float*  mlp_b1    = (const float*)d_in[22];
    const float*  mlp_a1    = (const float*)d_in[23];
    const float*  out_w     = (const float*)d_in[24];
    const float*  out_b     = (const float*)d_in[25];
    float* out = (float*)d_out;
    char* ws = (char*)d_ws;
    (void)gat_b;

    // ---- fixed workspace layout (bytes, 256-aligned) ----
    uint8_t* adj   = (uint8_t*)(ws + 0);               //  2,359,296
    float*   invn  = (float*)(ws + 2359296);
    float*   kbuf  = (float*)(ws + 2555904);
    float*   biasP = (float*)(ws + 2654208);
    float*   c0    = (float*)(ws + 2663936);           //    614,400
    float*   c1    = (float*)(ws + 3278336);
    u16*     WhhPH = (u16*)(ws + 5137920);             //  2,957,312 (2432 x 608)
    u16*     WhhPL = (u16*)(ws + 8095232);
    u16*     WihPH = (u16*)(ws + 11052544);            //  9,494,528 (2432 x 1952)
    u16*     WihPL = (u16*)(ws + 20547072);
    u16*     EwH   = (u16*)(ws + 30041600);            //  2,097,152 (1024 x 1024)
    u16*     EwL   = (u16*)(ws + 32138752);
    u16*     Fc1H  = (u16*)(ws + 34235904);            //    786,432 (384 x 1024)
    u16*     Fc1L  = (u16*)(ws + 35022336);
    float*   Wr2f  = (float*)(ws + 35808768);          //  1,440,256 (2 x 600 x 300)
    u16*     Wr2H  = (u16*)(ws + 37249024);            //    819,200 (2 x 640 x 320)
    u16*     Wr2L  = (u16*)(ws + 38068224);
    u16*     Wm0H  = (u16*)(ws + 38887424);            //    524,288 (384 x 608)
    u16*     Wm0L  = (u16*)(ws + 39411712);
    u16*     Wm1H  = (u16*)(ws + 39936000);            //    262,144 (384 x 320)
    u16*     Wm1L  = (u16*)(ws + 40198144);
    u16*     FfH   = (u16*)(ws + 40460288);            // 50,331,648 (ROWS x 1024)
    u16*     FfL   = (u16*)(ws + 90791936);
    float*   Hcat  = (float*)(ws + 141123584);         // 88,473,600 (ROWS,900) n-major
    u16*     HsH   = (u16*)(ws + 229597184);           // 15,728,640 (ROWS x 320)
    u16*     HsL   = (u16*)(ws + 245325824);
    // V (GAT, fp32 ROWSx600) aliases Hlstm (97 slices x 256 x 608 split bf16)
    float*   V      = (float*)(ws + 261054464);        // 58,982,400
    u16*     HlstmH = (u16*)(ws + 261054464);          // 30,195,712 (97 slices)
    u16*     HlstmL = (u16*)(ws + 291250176);          // 30,195,712 -> 321,445,888
    // MLP scratch aliases Hcat (dead after last Hcat split)
    u16*     x1H   = (u16*)Hcat;                       // 15,728,640 (ROWS x 320)
    u16*     x1L   = (u16*)(ws + 141123584 + 15728640);
    float*   x2    = (float*)(ws + 141123584 + 31457280);   // 29,884,416 (ROWS x 304)

    // ---- tier selection for chunked seq/zin region ----
    const size_t fixedNeed = 321445888ull;
    const size_t perT = 4456448ull;                    // zin(2,457,600)+seqH/L(1,998,848)
    int T;
    if      (ws_size >= fixedNeed + 96ull * perT) T = 96;
    else if (ws_size >= fixedNeed + 48ull * perT) T = 48;
    else if (ws_size >= fixedNeed + 32ull * perT) T = 32;
    else if (ws_size >= fixedNeed + 16ull * perT) T = 16;
    else if (ws_size >= fixedNeed +  8ull * perT) T = 8;
    else return;                                       // visible failure, no OOB
    char* cr = ws + fixedNeed;
    float* zin  = (float*)cr;                                // (Mc,2400)
    u16*   seqH = (u16*)(cr + (size_t)T * 2457600);          // (Mc,1952)
    u16*   seqL = (u16*)(cr + (size_t)T * 2457600 + (size_t)T * 999424);

    // 1) norms + adjacency
    norm_kernel<<<ROWS / 4, 256, 0, stream>>>(features, invn);
    simadj_kernel<<<Bdim, 256, 0, stream>>>(features, invn, entro, alpha, threshold, adj);

    // 2) weight/activation conversions
    split_rows8<<<dim3(2, ROWS / 4), 256, 0, stream>>>(            // features n-major full
        features, Edim, 255, Ndim, 8, 1, 0, FfH, FfL, Edim, Edim, Edim, ROWS);
    split_rows8<<<dim3(2, 96), 256, 0, stream>>>(                  // fc1_w (384x1024)
        fc1_w, Edim, IDP, Fc1H, Fc1L, Edim, Edim, Edim, HDdim);
    split_rows8<<<dim3(2, 256), 256, 0, stream>>>(                 // enhance_w
        enhance_w, Edim, IDP, EwH, EwL, Edim, Edim, Edim, Edim);
    split_rows8<<<dim3(4, 608), 256, 0, stream>>>(                 // Wih gate-interleaved
        lstm_w_ih, Edim + GDdim, 3, LHdim, 2, 1, 0, WihPH, WihPL, 1952, 1952, 1924, 2400);
    split_rows8<<<dim3(2, 608), 256, 0, stream>>>(                 // Whh gate-interleaved
        lstm_w_hh, LHdim, 3, LHdim, 2, 1, 0, WhhPH, WhhPL, 608, 608, LHdim, 2400);
    split_rows8<<<dim3(2, 96), 256, 0, stream>>>(                  // mlp_w0 (384x608)
        mlp_w0, LHdim, IDP, Wm0H, Wm0L, 608, 608, LHdim, HDdim);
    split_rows8<<<dim3(1, 96), 256, 0, stream>>>(                  // mlp_w1 (384x320)
        mlp_w1, HDdim, IDP, Wm1H, Wm1L, 320, 320, HDdim, HDdim);
    wr_cat<<<dim3(2, 2 * Ldim * HDdim), 256, 0, stream>>>(wr0, wr1, Wr2f);
    for (int l = 0; l < Ldim; ++l)
        split_rows8<<<dim3(1, 160), 256, 0, stream>>>(             // Wr2 (640x320 per layer)
            Wr2f + (size_t)l * 2 * HDdim * HDdim, HDdim, IDP,
            Wr2H + (size_t)l * 640 * 320, Wr2L + (size_t)l * 640 * 320,
            320, 320, HDdim, 2 * HDdim);
    bias_perm<<<10, 256, 0, stream>>>(lstm_b_ih, lstm_b_hh, biasP);
    zero_range<<<1200, 256, 0, stream>>>(c0, 307200);              // c0, c1

    // 3) H0 = prelu(features @ fc1_w^T + fc1_b) -> Hcat[:, 0:300] (bf16 MFMA)
    gemm_bf16<0,1><<<dim3(ROWS/128, 3), 256, 0, stream>>>(
        FfH, Edim, Fc1H, Edim,
        Hcat, nullptr, nullptr, GDdim, ROWS, HDdim, Edim, fc1_b, prelu_a);

    // 4) GAT layers (bf16 MFMA V projection, fused softmax+aggregation)
    for (int l = 0; l < Ldim; ++l) {
        const float* Hsrc = Hcat + l * HDdim;
        k_kernel<<<ROWS / 4, 256, 0, stream>>>(Hsrc, gat_w + l * 2 * HDdim + HDdim, kbuf);
        split_rows8<<<dim3(1, ROWS / 4), 256, 0, stream>>>(        // Hsrc -> split (K=320)
            Hsrc, GDdim, IDP, HsH, HsL, 320, 320, HDdim, ROWS);
        gemm_bf16<0,0><<<dim3(ROWS/128, 5), 256, 0, stream>>>(
            HsH, 320, Wr2H + (size_t)l * 640 * 320, 320,
            V, nullptr, nullptr, 2 * HDdim, ROWS, 2 * HDdim, 320, nullptr, nullptr);
        gat_fused<<<Bdim, 256, 0, stream>>>(
            kbuf, adj, s_mask, V, Hcat + (l + 1) * HDdim);
    }

    // 5) zero Hlstm split region (pads + slice 0 = h_0; aliased V until now)
    zero_range<<<58976, 256, 0, stream>>>((float*)HlstmH, 15097856);

    // 6) chunked: enhance (bf16) -> Hcat split -> zin (bf16) -> LSTM
    int cur = 0;
    float* cb_[2] = {c0, c1};
    for (int t0 = 0; t0 < Ndim; t0 += T) {
        int Mc = T * Bdim;
        gemm_bf16<1,1><<<dim3(Mc/128, 8), 256, 0, stream>>>(       // single-bf16 enhance
            FfH + (size_t)t0 * Bdim * Edim, Edim, EwH, Edim,
            nullptr, seqH, seqL, 1952, Mc, Edim, Edim, enhance_b, prelu_a);
        split_rows8<<<dim3(2, Mc / 4), 256, 0, stream>>>(
            Hcat, GDdim, 0x7FFFFFFF, 1, 30, 0, t0 * Bdim,
            seqH + 1024, seqL + 1024, 1952, 928, GDdim, Mc);
        gemm_bf16<0,0><<<dim3(Mc/128, 19), 256, 0, stream>>>(      // single-bf16 zin
            seqH, 1952, WihPH, 1952,
            zin, nullptr, nullptr, 4 * LHdim, Mc, 4 * LHdim, 1952, biasP, nullptr);
        for (int tl = 0; tl < T; ++tl) {
            const int g = t0 + tl;                    // global step, 0-based
            lstm_mfma3<<<dim3(8, 38), 256, 0, stream>>>(
                HlstmH + (size_t)g * HSLICE, HlstmL + (size_t)g * HSLICE,
                cb_[cur], WhhPH, WhhPL,
                zin + (size_t)tl * Bdim * 4 * LHdim,
                HlstmH + (size_t)(g + 1) * HSLICE, HlstmL + (size_t)(g + 1) * HSLICE,
                cb_[cur ^ 1]);
            cur ^= 1;
        }
    }

    // 7) MLP head (bf16 MFMA, A = Hlstm slices 1..96) + output
    zero_range<<<30720, 256, 0, stream>>>((float*)x1H, 7864320);   // x1 pads must be 0
    gemm_bf16<1,1><<<dim3(ROWS/128, 3), 256, 0, stream>>>(
        HlstmH + HSLICE, 608, Wm0H, 608,
        nullptr, x1H, x1L, 320, ROWS, HDdim, 608, mlp_b0, mlp_a0);
    gemm_bf16<0,1><<<dim3(ROWS/128, 3), 256, 0, stream>>>(
        x1H, 320, Wm1H, 320,
        x2, nullptr, nullptr, 304, ROWS, HDdim, 320, mlp_b1, mlp_a1);
    out_kernel<<<ROWS / 4, 256, 0, stream>>>(x2, 304, out_w, out_b, out);
}

// Round 21
// 2794.918 us; speedup vs baseline: 1.6593x; 1.0798x over previous
//
#include <hip/hip_runtime.h>
#include <cstdint>
#include <cstddef>

#define Bdim 256
#define Ndim 96
#define Edim 1024
#define HDdim 300
#define Ldim 2
#define LHdim 600
#define NCdim 7
#define GDdim 900              // HD*(L+1)
#define ROWS (Bdim*Ndim)       // 24576
#define HSLICE 155648          // 256*608 elements per Hlstm time-slice

typedef unsigned short u16;
typedef float f32x4 __attribute__((ext_vector_type(4)));
typedef short bf16x8 __attribute__((ext_vector_type(8)));

// Identity row-perm constants
#define IDP 0x7FFFFFFF, 1, 30, 0, 0

__device__ inline u16 f2bf(float x) {
    unsigned int u = __builtin_bit_cast(unsigned int, x);
    unsigned int r = (u + 0x7fffu + ((u >> 16) & 1u)) >> 16;   // RNE
    return (u16)r;
}
__device__ inline float bf2f(u16 h) {
    unsigned int u = ((unsigned int)h) << 16;
    return __builtin_bit_cast(float, u);
}

// ---------------------------------------------------------------------------
// Pure single-bf16 MFMA GEMM (m97-style: 2 LDS tiles, 16 MFMA/chunk),
// bx-major bijective XCD swizzle, reg->LDS staging.
// C = act(A·W^T + bias). K mult of 32; lda/ldw mult 8; M mult of 128;
// W must have gridDim.y*128 rows allocated (pad rows zeroed).
// OUT: 0 -> fp32 C; 1 -> split bf16 (Ch,Cl). ACT: 1 -> prelu(aptr).
// ---------------------------------------------------------------------------
template<int OUT, int ACT>
__global__ __launch_bounds__(256) void gemm_bf16(
    const u16* __restrict__ Ah, int lda,
    const u16* __restrict__ Wh, int ldw,
    float* __restrict__ C, u16* __restrict__ Ch, u16* __restrict__ Cl, int ldc,
    int M, int Nd, int K,
    const float* __restrict__ bias, const float* __restrict__ aptr)
{
    __shared__ u16 At[4][1024];
    __shared__ u16 Wt[4][1024];
    const int tid  = threadIdx.x;
    const int ny  = gridDim.y;
    const int nwg = gridDim.x * ny;
    const int lin = blockIdx.y * gridDim.x + blockIdx.x;
    const int q = nwg >> 3, r8 = nwg & 7;
    const int xcd = lin & 7, off = lin >> 3;
    const int swz = (xcd < r8) ? xcd * (q + 1) + off
                               : r8 * (q + 1) + (xcd - r8) * q + off;
    const int bm   = (swz / ny) * 128;
    const int bn   = (swz % ny) * 128;
    const int wv   = tid >> 6;
    const int lane = tid & 63;
    const int wr   = (wv >> 1) * 64;
    const int wc   = (wv & 1) * 64;
    const int l15  = lane & 15;
    const int kseg = lane >> 4;

    f32x4 acc[4][4];
    #pragma unroll
    for (int i = 0; i < 4; ++i)
        #pragma unroll
        for (int j = 0; j < 4; ++j) acc[i][j] = (f32x4){0.f,0.f,0.f,0.f};

    const int srow = tid & 127;
    const bool isA = (tid < 128);
    const int gr   = isA ? (bm + srow) : (bn + srow);
    const int glim = isA ? M : 0x7FFFFFFF;        // W pad rows allocated+zeroed
    const u16* pbase = (isA ? Ah : Wh) + (size_t)gr * (isA ? lda : ldw);
    u16* dst = isA ? &At[0][0] : &Wt[0][0];

    for (int k0 = 0; k0 < K; k0 += 32) {
        __syncthreads();
        {
            const bool ok = (gr < glim);
            #pragma unroll
            for (int s = 0; s < 4; ++s) {
                bf16x8 v = {0,0,0,0,0,0,0,0};
                if (ok) v = *(const bf16x8*)(pbase + k0 + s * 8);
                *(bf16x8*)(dst + s * 1024 + srow * 8) = v;
            }
        }
        __syncthreads();
        bf16x8 a[4], b[4];
        #pragma unroll
        for (int f = 0; f < 4; ++f) {
            int ar = wr + f * 16 + l15;
            int br = wc + f * 16 + l15;
            a[f] = *(const bf16x8*)&At[kseg][ar * 8];
            b[f] = *(const bf16x8*)&Wt[kseg][br * 8];
        }
        #pragma unroll
        for (int i = 0; i < 4; ++i)
            #pragma unroll
            for (int j = 0; j < 4; ++j)
                acc[i][j] = __builtin_amdgcn_mfma_f32_16x16x32_bf16(a[i], b[j], acc[i][j], 0, 0, 0);
    }

    const float av = (ACT == 1) ? *aptr : 0.f;
    const int r4 = (lane >> 4) * 4;
    #pragma unroll
    for (int j = 0; j < 4; ++j) {
        int col = bn + wc + j * 16 + l15;
        if (col >= Nd) continue;
        float bv = bias ? bias[col] : 0.f;
        #pragma unroll
        for (int i = 0; i < 4; ++i) {
            #pragma unroll
            for (int rr = 0; rr < 4; ++rr) {
                int row = bm + wr + i * 16 + r4 + rr;
                if (row >= M) continue;
                float v = acc[i][j][rr] + bv;
                if (ACT == 1) v = (v >= 0.f) ? v : av * v;
                if (OUT == 0) {
                    C[(size_t)row * ldc + col] = v;
                } else {
                    u16 h = f2bf(v);
                    Ch[(size_t)row * ldc + col] = h;
                    Cl[(size_t)row * ldc + col] = f2bf(v - bf2f(h));
                }
            }
        }
    }
}

// ---------------------------------------------------------------------------
// split fp32 -> bf16 hi/lo, vectorized: 4 rows/block, 8 cols/thread.
// ---------------------------------------------------------------------------
__global__ __launch_bounds__(256) void split_rows8(
    const float* __restrict__ src, int srcld,
    int pmask, int pmul1, int pshift, int pmul2, int padd,
    u16* __restrict__ dstH, u16* __restrict__ dstL, int dstld,
    int wcols, int validK, int validRows)
{
    const int r = blockIdx.y * 4 + (threadIdx.x >> 6);
    const int c = (blockIdx.x * 64 + (threadIdx.x & 63)) * 8;
    if (c >= wcols) return;
    const int sr = (r & pmask) * pmul1 + (r >> pshift) * pmul2 + padd;
    const float* s = src + (size_t)sr * srcld;
    const bool rok = (r < validRows);
    float v[8];
    if (rok && c + 8 <= validK) {
        *(float4*)&v[0] = *(const float4*)(s + c);
        *(float4*)&v[4] = *(const float4*)(s + c + 4);
    } else {
        #pragma unroll
        for (int u = 0; u < 8; ++u) v[u] = (rok && c + u < validK) ? s[c + u] : 0.f;
    }
    bf16x8 H8, L8;
    #pragma unroll
    for (int u = 0; u < 8; ++u) {
        u16 h = f2bf(v[u]);
        H8[u] = (short)h;
        L8[u] = (short)f2bf(v[u] - bf2f(h));
    }
    *(bf16x8*)(dstH + (size_t)r * dstld + c) = H8;
    *(bf16x8*)(dstL + (size_t)r * dstld + c) = L8;
}

// biasP[n'] = b_ih[orig]+b_hh[orig], orig = (n'&3)*600+(n'>>2)
__global__ __launch_bounds__(256) void bias_perm(
    const float* __restrict__ bih, const float* __restrict__ bhh, float* __restrict__ dst)
{
    int n = blockIdx.x * 256 + threadIdx.x;
    if (n >= 4 * LHdim) return;
    int o = (n & 3) * LHdim + (n >> 2);
    dst[n] = bih[o] + bhh[o];
}

// Wr2f[l][r][c]: r<300 -> wr0[l][r][c], else wr1[l][r-300][c]
__global__ __launch_bounds__(256) void wr_cat(
    const float* __restrict__ wr0, const float* __restrict__ wr1, float* __restrict__ dst)
{
    int c = blockIdx.x * 256 + threadIdx.x;
    if (c >= HDdim) return;
    int lr = blockIdx.y;
    int l = lr / (2 * HDdim), r = lr % (2 * HDdim);
    const float* src = (r < HDdim)
        ? wr0 + ((size_t)l * HDdim + r) * HDdim
        : wr1 + ((size_t)l * HDdim + (r - HDdim)) * HDdim;
    dst[(size_t)lr * HDdim + c] = src[c];
}

__global__ __launch_bounds__(256) void zero_range(float* __restrict__ p, int n)
{
    int i = blockIdx.x * 256 + threadIdx.x;
    if (i < n) p[i] = 0.f;
}

// ---------------------------------------------------------------------------
__global__ __launch_bounds__(256) void norm_kernel(const float* __restrict__ f, float* __restrict__ invn)
{
    int row  = blockIdx.x * 4 + (threadIdx.x >> 6);
    int lane = threadIdx.x & 63;
    const float* fr = f + (size_t)row * Edim;
    float ss = 0.f;
    for (int t = lane; t < Edim; t += 64) { float v = fr[t]; ss = fmaf(v, v, ss); }
    #pragma unroll
    for (int o = 32; o > 0; o >>= 1) ss += __shfl_down(ss, o);
    if (lane == 0) invn[row] = 1.f / (sqrtf(ss) + 1e-8f);
}

__global__ __launch_bounds__(256) void simadj_kernel(
    const float* __restrict__ f, const float* __restrict__ invn,
    const float* __restrict__ entro, const float* __restrict__ alphap,
    const float* __restrict__ thrp, uint8_t* __restrict__ adj)
{
    int b = blockIdx.x;
    __shared__ float S[16][100];
    int tid = threadIdx.x;
    int i0 = (tid >> 4) * 6, j0 = (tid & 15) * 6;
    float acc[6][6];
    #pragma unroll
    for (int i = 0; i < 6; ++i)
        #pragma unroll
        for (int j = 0; j < 6; ++j) acc[i][j] = 0.f;
    const float* fb = f + (size_t)b * Ndim * Edim;

    for (int k0 = 0; k0 < Edim; k0 += 16) {
        __syncthreads();
        #pragma unroll
        for (int r = 0; r < 6; ++r) {
            int n = (tid >> 4) + r * 16;
            S[tid & 15][n] = fb[(size_t)n * Edim + k0 + (tid & 15)];
        }
        __syncthreads();
        #pragma unroll
        for (int kk = 0; kk < 16; ++kk) {
            float a[6], bb[6];
            #pragma unroll
            for (int u = 0; u < 6; ++u) a[u] = S[kk][i0 + u];
            #pragma unroll
            for (int u = 0; u < 6; ++u) bb[u] = S[kk][j0 + u];
            #pragma unroll
            for (int i = 0; i < 6; ++i)
                #pragma unroll
                for (int j = 0; j < 6; ++j)
                    acc[i][j] = fmaf(a[i], bb[j], acc[i][j]);
        }
    }

    float alpha = *alphap, thr = *thrp;
    float onem = 1.f - alpha;
    #pragma unroll
    for (int i = 0; i < 6; ++i) {
        int ii = i0 + i;
        float inv_i = invn[b * Ndim + ii];
        #pragma unroll
        for (int j = 0; j < 6; ++j) {
            int jj = j0 + j;
            float simv = acc[i][j] * inv_i * invn[b * Ndim + jj];
            float comb = alpha * entro[b * Ndim + jj] + onem * simv;
            adj[((size_t)b * Ndim + ii) * Ndim + jj] = (comb > thr) ? 1 : 0;
        }
    }
}

// k[r] = H[r,:300] . wk   (q cancels in the adjacency softmax; not computed)
__global__ __launch_bounds__(256) void k_kernel(
    const float* __restrict__ Hsrc, const float* __restrict__ wk,
    float* __restrict__ k)
{
    int row  = blockIdx.x * 4 + (threadIdx.x >> 6);
    int lane = threadIdx.x & 63;
    const float* h = Hsrc + (size_t)row * GDdim;
    float sk = 0.f;
    for (int t = lane; t < HDdim; t += 64) sk = fmaf(h[t], wk[t], sk);
    #pragma unroll
    for (int o = 32; o > 0; o >>= 1) sk += __shfl_down(sk, o);
    if (lane == 0) k[row] = sk;
}

// ---------------------------------------------------------------------------
// Fused GAT attention for one batch b (q, gat_b cancel in softmax).
// V combined: cols 0..299 = V0, 300..599 = V1, row stride 600 (n-major rows).
// ---------------------------------------------------------------------------
__global__ __launch_bounds__(256) void gat_fused(
    const float* __restrict__ kbuf, const uint8_t* __restrict__ adj,
    const int* __restrict__ smask,
    const float* __restrict__ V,
    float* __restrict__ Mout)
{
    __shared__ float P0[96][98];
    __shared__ float P1[96][98];
    __shared__ float Vs0[96][96];
    __shared__ float Vs1[96][96];
    __shared__ float ek[96];
    __shared__ float rden[96];
    __shared__ float red[256];
    const int b = blockIdx.x;
    const int tid = threadIdx.x;

    float kj = (tid < Ndim) ? kbuf[tid * Bdim + b] : -1e30f;
    red[tid] = kj;
    __syncthreads();
    #pragma unroll
    for (int s = 128; s > 0; s >>= 1) {
        if (tid < s) red[tid] = fmaxf(red[tid], red[tid + s]);
        __syncthreads();
    }
    float kmax = red[0];
    if (tid < Ndim) ek[tid] = expf(kj - kmax);
    __syncthreads();
    if (tid < Ndim) {
        const uint8_t* ar = adj + ((size_t)b * Ndim + tid) * Ndim;
        float s = 0.f;
        for (int j = 0; j < Ndim; ++j) if (ar[j]) s += ek[j];
        rden[tid] = 1.f / s;   // diagonal always allowed -> s > 0
    }
    __syncthreads();
    for (int idx = tid; idx < Ndim * Ndim; idx += 256) {
        int i = idx / Ndim, j = idx - i * Ndim;
        float a = adj[((size_t)b * Ndim + i) * Ndim + j] ? ek[j] * rden[i] : 0.f;
        int s = smask[((size_t)b * Ndim + i) * Ndim + j];
        P0[i][j] = s ? a : 0.f;
        P1[i][j] = s ? 0.f : a;
    }
    __syncthreads();

    const int ti = tid >> 4, td = tid & 15;
    const int i0 = ti * 6, dbase = td * 6;
    for (int p = 0; p < 4; ++p) {
        const int d0 = p * 96;
        const int dw = (p == 3) ? (HDdim - 288) : 96;
        for (int idx = tid; idx < 96 * 24; idx += 256) {
            int j = idx / 24, q4 = (idx - j * 24) * 4;
            if (q4 < dw) {
                size_t g = ((size_t)(j * Bdim + b)) * (2 * HDdim) + d0 + q4;
                *(float4*)&Vs0[j][q4] = *(const float4*)(V + g);
                *(float4*)&Vs1[j][q4] = *(const float4*)(V + g + HDdim);
            }
        }
        __syncthreads();
        float acc[6][6];
        #pragma unroll
        for (int ii = 0; ii < 6; ++ii)
            #pragma unroll
            for (int dd = 0; dd < 6; ++dd) acc[ii][dd] = 0.f;
        for (int j = 0; j < Ndim; j += 2) {
            float2 pa[6], pb[6];
            #pragma unroll
            for (int ii = 0; ii < 6; ++ii) {
                pa[ii] = *(const float2*)&P0[i0 + ii][j];
                pb[ii] = *(const float2*)&P1[i0 + ii][j];
            }
            float2 v0a[3], v0b[3], v1a[3], v1b[3];
            #pragma unroll
            for (int dd = 0; dd < 3; ++dd) {
                v0a[dd] = *(const float2*)&Vs0[j][dbase + 2 * dd];
                v0b[dd] = *(const float2*)&Vs0[j + 1][dbase + 2 * dd];
                v1a[dd] = *(const float2*)&Vs1[j][dbase + 2 * dd];
                v1b[dd] = *(const float2*)&Vs1[j + 1][dbase + 2 * dd];
            }
            #pragma unroll
            for (int ii = 0; ii < 6; ++ii)
                #pragma unroll
                for (int dd = 0; dd < 3; ++dd) {
                    acc[ii][2*dd]   += pa[ii].x * v0a[dd].x + pb[ii].x * v1a[dd].x
                                     + pa[ii].y * v0b[dd].x + pb[ii].y * v1b[dd].x;
                    acc[ii][2*dd+1] += pa[ii].x * v0a[dd].y + pb[ii].x * v1a[dd].y
                                     + pa[ii].y * v0b[dd].y + pb[ii].y * v1b[dd].y;
                }
        }
        __syncthreads();
        #pragma unroll
        for (int ii = 0; ii < 6; ++ii) {
            #pragma unroll
            for (int dd = 0; dd < 6; ++dd) {
                int d = dbase + dd;
                if (d < dw)
                    Mout[((size_t)((i0 + ii) * Bdim + b)) * GDdim + d0 + d] = acc[ii][dd];
            }
        }
    }
}

// ---------------------------------------------------------------------------
// Per-step LSTM, SINGLE-bf16 h and W (precision probe: h-lo fed only the
// recurrence A-operand; contractive recurrence bounds the feedback error).
// Round-13 schedule: double-buffered LDS, one barrier per k-chunk; T14
// prefetch; Hlstm-slice ping-pong. 2 MFMA/chunk. Tile 32b x 64g, grid (8,38).
// ---------------------------------------------------------------------------
__global__ __launch_bounds__(256) void lstm_bf16(
    const u16* __restrict__ hH,
    const float* __restrict__ cin,
    const u16* __restrict__ WH,                  // (2432 x 608), pads zero
    const float* __restrict__ zt,
    u16* __restrict__ hHo,
    float* __restrict__ cout)
{
    __shared__ u16 As[2][4][256];
    __shared__ u16 Ws[2][4][512];
    __shared__ __align__(16) float gates[32][68];
    const int tid = threadIdx.x;
    const int bm = blockIdx.x * 32;
    const int bn = blockIdx.y * 64;
    const int wv = tid >> 6;
    const int lane = tid & 63;
    const int l15 = lane & 15;
    const int kseg = lane >> 4;
    const float4 fz = make_float4(0.f, 0.f, 0.f, 0.f);

    // --- T14: issue cell-phase loads NOW; consumed after the k-loop ---
    const int prow0 = tid >> 4,        pui0 = tid & 15;
    const int prow1 = (tid + 256) >> 4, pui1 = tid & 15;     // cell1 = tid+256
    const int pn0 = bn + pui0 * 4,  pn1 = bn + pui1 * 4;
    const int pu0 = pn0 >> 2,       pu1 = pn1 >> 2;
    const bool ok0 = (pu0 < LHdim), ok1 = (pu1 < LHdim);
    const int bb0 = bm + prow0,     bb1 = bm + prow1;
    float4 z0 = ok0 ? *(const float4*)(zt + (size_t)bb0 * (4 * LHdim) + pn0) : fz;
    float4 z1 = ok1 ? *(const float4*)(zt + (size_t)bb1 * (4 * LHdim) + pn1) : fz;
    float ci0 = ok0 ? cin[bb0 * LHdim + pu0] : 0.f;
    float ci1 = ok1 ? cin[bb1 * LHdim + pu1] : 0.f;

    // A staging: threads 0..127, one bf16x8 each (wave-uniform split)
    const int av = tid & 127;
    const int arow = av >> 2, akc = av & 3;
    const u16* asrc = hH + (size_t)(bm + arow) * 608 + akc * 8;
    const int aoff = akc * 256 + arow * 8;
    const bool doA = (tid < 128);
    // W staging: all 256 threads, one bf16x8 each
    const int wrow = tid >> 2, wkc = tid & 3;
    const u16* wsrc = WH + (size_t)(bn + wrow) * 608 + wkc * 8;
    const int woff2 = wrow * 8;

    f32x4 acc[2];
    acc[0] = (f32x4){0.f,0.f,0.f,0.f};
    acc[1] = (f32x4){0.f,0.f,0.f,0.f};

    // preload chunk 0 (upper threads load duplicate A addrs; store is guarded)
    bf16x8 ra = *(const bf16x8*)(asrc);
    bf16x8 rw = *(const bf16x8*)(wsrc);

    #pragma unroll
    for (int kc = 0; kc < 19; ++kc) {
        const int buf = kc & 1;
        if (doA) *(bf16x8*)(&As[buf][0][0] + aoff) = ra;
        *(bf16x8*)(&Ws[buf][wkc][woff2]) = rw;
        if (kc + 1 < 19) {                      // prefetch next chunk
            ra = *(const bf16x8*)(asrc + (kc + 1) * 32);
            rw = *(const bf16x8*)(wsrc + (kc + 1) * 32);
        }
        __syncthreads();                        // single barrier per chunk
        bf16x8 a0, a1, b;
        a0 = *(const bf16x8*)&As[buf][kseg][(l15) * 8];
        a1 = *(const bf16x8*)&As[buf][kseg][(16 + l15) * 8];
        b  = *(const bf16x8*)&Ws[buf][kseg][(wv * 16 + l15) * 8];
        acc[0] = __builtin_amdgcn_mfma_f32_16x16x32_bf16(a0, b, acc[0], 0, 0, 0);
        acc[1] = __builtin_amdgcn_mfma_f32_16x16x32_bf16(a1, b, acc[1], 0, 0, 0);
    }

    const int r4 = (lane >> 4) * 4;
    __syncthreads();
    #pragma unroll
    for (int i = 0; i < 2; ++i)
        #pragma unroll
        for (int rr = 0; rr < 4; ++rr)
            gates[i * 16 + r4 + rr][wv * 16 + l15] = acc[i][rr];
    __syncthreads();

    // fused cell: 2 cells per thread, using prefetched z/c
    if (ok0) {
        float4 g = *(const float4*)&gates[prow0][pui0 * 4];
        float gi = g.x + z0.x;
        float gf = g.y + z0.y;
        float gg = g.z + z0.z;
        float go = g.w + z0.w;
        float si = 1.f / (1.f + expf(-gi));
        float sf = 1.f / (1.f + expf(-gf));
        float so = 1.f / (1.f + expf(-go));
        float cn = sf * ci0 + si * tanhf(gg);
        float hn = so * tanhf(cn);
        cout[bb0 * LHdim + pu0] = cn;
        hHo[(size_t)bb0 * 608 + pu0] = f2bf(hn);
    }
    if (ok1) {
        float4 g = *(const float4*)&gates[prow1][pui1 * 4];
        float gi = g.x + z1.x;
        float gf = g.y + z1.y;
        float gg = g.z + z1.z;
        float go = g.w + z1.w;
        float si = 1.f / (1.f + expf(-gi));
        float sf = 1.f / (1.f + expf(-gf));
        float so = 1.f / (1.f + expf(-go));
        float cn = sf * ci1 + si * tanhf(gg);
        float hn = so * tanhf(cn);
        cout[bb1 * LHdim + pu1] = cn;
        hHo[(size_t)bb1 * 608 + pu1] = f2bf(hn);
    }
}

__global__ __launch_bounds__(256) void out_kernel(
    const float* __restrict__ x, int ldx, const float* __restrict__ ow,
    const float* __restrict__ ob, float* __restrict__ out)
{
    int r    = blockIdx.x * 4 + (threadIdx.x >> 6);
    int lane = threadIdx.x & 63;
    const float* xr = x + (size_t)r * ldx;
    float acc[NCdim];
    #pragma unroll
    for (int n = 0; n < NCdim; ++n) acc[n] = 0.f;
    for (int t = lane; t < HDdim; t += 64) {
        float xv = xr[t];
        #pragma unroll
        for (int n = 0; n < NCdim; ++n) acc[n] = fmaf(xv, ow[n * HDdim + t], acc[n]);
    }
    #pragma unroll
    for (int o = 32; o > 0; o >>= 1)
        #pragma unroll
        for (int n = 0; n < NCdim; ++n) acc[n] += __shfl_down(acc[n], o);
    if (lane == 0) {
        int b = r & 255, nn = r >> 8;
        #pragma unroll
        for (int n = 0; n < NCdim; ++n) out[((size_t)b * Ndim + nn) * NCdim + n] = acc[n] + ob[n];
    }
}

// ---------------------------------------------------------------------------
extern "C" void kernel_launch(void* const* d_in, const int* in_sizes, int n_in,
                              void* d_out, int out_size, void* d_ws, size_t ws_size,
                              hipStream_t stream)
{
    const float*  features  = (const float*)d_in[0];
    const int*    s_mask    = (const int*)  d_in[1];
    const float*  entro     = (const float*)d_in[2];
    const float*  alpha     = (const float*)d_in[3];
    const float*  threshold = (const float*)d_in[4];
    const float*  fc1_w     = (const float*)d_in[5];
    const float*  fc1_b     = (const float*)d_in[6];
    const float*  gat_w     = (const float*)d_in[7];
    const float*  gat_b     = (const float*)d_in[8];
    const float*  wr0       = (const float*)d_in[9];
    const float*  wr1       = (const float*)d_in[10];
    const float*  enhance_w = (const float*)d_in[11];
    const float*  enhance_b = (const float*)d_in[12];
    const float*  prelu_a   = (const float*)d_in[13];
    const float*  lstm_w_ih = (const float*)d_in[14];
    const float*  lstm_w_hh = (const float*)d_in[15];
    const float*  lstm_b_ih = (const float*)d_in[16];
    const float*  lstm_b_hh = (const float*)d_in[17];
    const float*  mlp_w0    = (const float*)d_in[18];
    const float*  mlp_b0    = (const float*)d_in[19];
    const float*  mlp_a0    = (const float*)d_in[20];
    const float*  mlp_w1    = (const float*)d_in[21];
    const float*  mlp_b1    = (const float*)d_in[22];
    const float*  mlp_a1    = (const float*)d_in[23];
    const float*  out_w     = (const float*)d_in[24];
    const float*  out_b     = (const float*)d_in[25];
    float* out = (float*)d_out;
    char* ws = (char*)d_ws;
    (void)gat_b;

    // ---- fixed workspace layout (bytes, 256-aligned) ----
    uint8_t* adj   = (uint8_t*)(ws + 0);               //  2,359,296
    float*   invn  = (float*)(ws + 2359296);
    float*   kbuf  = (float*)(ws + 2555904);
    float*   biasP = (float*)(ws + 2654208);
    float*   c0    = (float*)(ws + 2663936);           //    614,400
    float*   c1    = (float*)(ws + 3278336);
    u16*     WhhPH = (u16*)(ws + 5137920);             //  2,957,312 (2432 x 608)
    u16*     WhhPL = (u16*)(ws + 8095232);
    u16*     WihPH = (u16*)(ws + 11052544);            //  9,494,528 (2432 x 1952)
    u16*     WihPL = (u16*)(ws + 20547072);
    u16*     EwH   = (u16*)(ws + 30041600);            //  2,097,152 (1024 x 1024)
    u16*     EwL   = (u16*)(ws + 32138752);
    u16*     Fc1H  = (u16*)(ws + 34235904);            //    786,432 (384 x 1024)
    u16*     Fc1L  = (u16*)(ws + 35022336);
    float*   Wr2f  = (float*)(ws + 35808768);          //  1,440,256 (2 x 600 x 300)
    u16*     Wr2H  = (u16*)(ws + 37249024);            //    819,200 (2 x 640 x 320)
    u16*     Wr2L  = (u16*)(ws + 38068224);
    u16*     Wm0H  = (u16*)(ws + 38887424);            //    524,288 (384 x 608)
    u16*     Wm0L  = (u16*)(ws + 39411712);
    u16*     Wm1H  = (u16*)(ws + 39936000);            //    262,144 (384 x 320)
    u16*     Wm1L  = (u16*)(ws + 40198144);
    u16*     FfH   = (u16*)(ws + 40460288);            // 50,331,648 (ROWS x 1024)
    u16*     FfL   = (u16*)(ws + 90791936);
    float*   Hcat  = (float*)(ws + 141123584);         // 88,473,600 (ROWS,900) n-major
    u16*     HsH   = (u16*)(ws + 229597184);           // 15,728,640 (ROWS x 320)
    u16*     HsL   = (u16*)(ws + 245325824);
    // V (GAT, fp32 ROWSx600) aliases Hlstm (97 slices x 256 x 608 bf16 H-only)
    float*   V      = (float*)(ws + 261054464);        // 58,982,400
    u16*     HlstmH = (u16*)(ws + 261054464);          // 30,195,712 (97 slices)
    // MLP scratch aliases Hcat (dead after last Hcat split)
    u16*     x1H   = (u16*)Hcat;                       // 15,728,640 (ROWS x 320)
    u16*     x1L   = (u16*)(ws + 141123584 + 15728640);
    float*   x2    = (float*)(ws + 141123584 + 31457280);   // 29,884,416 (ROWS x 304)

    // ---- tier selection for chunked seq/zin region ----
    const size_t fixedNeed = 321445888ull;
    const size_t perT = 4456448ull;                    // zin(2,457,600)+seqH/L(1,998,848)
    int T;
    if      (ws_size >= fixedNeed + 96ull * perT) T = 96;
    else if (ws_size >= fixedNeed + 48ull * perT) T = 48;
    else if (ws_size >= fixedNeed + 32ull * perT) T = 32;
    else if (ws_size >= fixedNeed + 16ull * perT) T = 16;
    else if (ws_size >= fixedNeed +  8ull * perT) T = 8;
    else return;                                       // visible failure, no OOB
    char* cr = ws + fixedNeed;
    float* zin  = (float*)cr;                                // (Mc,2400)
    u16*   seqH = (u16*)(cr + (size_t)T * 2457600);          // (Mc,1952)
    u16*   seqL = (u16*)(cr + (size_t)T * 2457600 + (size_t)T * 999424);

    // 1) norms + adjacency
    norm_kernel<<<ROWS / 4, 256, 0, stream>>>(features, invn);
    simadj_kernel<<<Bdim, 256, 0, stream>>>(features, invn, entro, alpha, threshold, adj);

    // 2) weight/activation conversions
    split_rows8<<<dim3(2, ROWS / 4), 256, 0, stream>>>(            // features n-major full
        features, Edim, 255, Ndim, 8, 1, 0, FfH, FfL, Edim, Edim, Edim, ROWS);
    split_rows8<<<dim3(2, 96), 256, 0, stream>>>(                  // fc1_w (384x1024)
        fc1_w, Edim, IDP, Fc1H, Fc1L, Edim, Edim, Edim, HDdim);
    split_rows8<<<dim3(2, 256), 256, 0, stream>>>(                 // enhance_w
        enhance_w, Edim, IDP, EwH, EwL, Edim, Edim, Edim, Edim);
    split_rows8<<<dim3(4, 608), 256, 0, stream>>>(                 // Wih gate-interleaved
        lstm_w_ih, Edim + GDdim, 3, LHdim, 2, 1, 0, WihPH, WihPL, 1952, 1952, 1924, 2400);
    split_rows8<<<dim3(2, 608), 256, 0, stream>>>(                 // Whh gate-interleaved
        lstm_w_hh, LHdim, 3, LHdim, 2, 1, 0, WhhPH, WhhPL, 608, 608, LHdim, 2400);
    split_rows8<<<dim3(2, 96), 256, 0, stream>>>(                  // mlp_w0 (384x608)
        mlp_w0, LHdim, IDP, Wm0H, Wm0L, 608, 608, LHdim, HDdim);
    split_rows8<<<dim3(1, 96), 256, 0, stream>>>(                  // mlp_w1 (384x320)
        mlp_w1, HDdim, IDP, Wm1H, Wm1L, 320, 320, HDdim, HDdim);
    wr_cat<<<dim3(2, 2 * Ldim * HDdim), 256, 0, stream>>>(wr0, wr1, Wr2f);
    for (int l = 0; l < Ldim; ++l)
        split_rows8<<<dim3(1, 160), 256, 0, stream>>>(             // Wr2 (640x320 per layer)
            Wr2f + (size_t)l * 2 * HDdim * HDdim, HDdim, IDP,
            Wr2H + (size_t)l * 640 * 320, Wr2L + (size_t)l * 640 * 320,
            320, 320, HDdim, 2 * HDdim);
    bias_perm<<<10, 256, 0, stream>>>(lstm_b_ih, lstm_b_hh, biasP);
    zero_range<<<1200, 256, 0, stream>>>(c0, 307200);              // c0, c1

    // 3) H0 = prelu(features @ fc1_w^T + fc1_b) -> Hcat[:, 0:300] (bf16 MFMA)
    gemm_bf16<0,1><<<dim3(ROWS/128, 3), 256, 0, stream>>>(
        FfH, Edim, Fc1H, Edim,
        Hcat, nullptr, nullptr, GDdim, ROWS, HDdim, Edim, fc1_b, prelu_a);

    // 4) GAT layers (bf16 MFMA V projection, fused softmax+aggregation)
    for (int l = 0; l < Ldim; ++l) {
        const float* Hsrc = Hcat + l * HDdim;
        k_kernel<<<ROWS / 4, 256, 0, stream>>>(Hsrc, gat_w + l * 2 * HDdim + HDdim, kbuf);
        split_rows8<<<dim3(1, ROWS / 4), 256, 0, stream>>>(        // Hsrc -> split (K=320)
            Hsrc, GDdim, IDP, HsH, HsL, 320, 320, HDdim, ROWS);
        gemm_bf16<0,0><<<dim3(ROWS/128, 5), 256, 0, stream>>>(
            HsH, 320, Wr2H + (size_t)l * 640 * 320, 320,
            V, nullptr, nullptr, 2 * HDdim, ROWS, 2 * HDdim, 320, nullptr, nullptr);
        gat_fused<<<Bdim, 256, 0, stream>>>(
            kbuf, adj, s_mask, V, Hcat + (l + 1) * HDdim);
    }

    // 5) zero Hlstm H region (pads + slice 0 = h_0; aliased V until now)
    zero_range<<<29489, 256, 0, stream>>>((float*)HlstmH, 7548928);

    // 6) chunked: enhance (bf16) -> Hcat split -> zin (bf16) -> LSTM (bf16)
    int cur = 0;
    float* cb_[2] = {c0, c1};
    for (int t0 = 0; t0 < Ndim; t0 += T) {
        int Mc = T * Bdim;
        gemm_bf16<1,1><<<dim3(Mc/128, 8), 256, 0, stream>>>(       // single-bf16 enhance
            FfH + (size_t)t0 * Bdim * Edim, Edim, EwH, Edim,
            nullptr, seqH, seqL, 1952, Mc, Edim, Edim, enhance_b, prelu_a);
        split_rows8<<<dim3(2, Mc / 4), 256, 0, stream>>>(
            Hcat, GDdim, 0x7FFFFFFF, 1, 30, 0, t0 * Bdim,
            seqH + 1024, seqL + 1024, 1952, 928, GDdim, Mc);
        gemm_bf16<0,0><<<dim3(Mc/128, 19), 256, 0, stream>>>(      // single-bf16 zin
            seqH, 1952, WihPH, 1952,
            zin, nullptr, nullptr, 4 * LHdim, Mc, 4 * LHdim, 1952, biasP, nullptr);
        for (int tl = 0; tl < T; ++tl) {
            const int g = t0 + tl;                    // global step, 0-based
            lstm_bf16<<<dim3(8, 38), 256, 0, stream>>>(
                HlstmH + (size_t)g * HSLICE, cb_[cur], WhhPH,
                zin + (size_t)tl * Bdim * 4 * LHdim,
                HlstmH + (size_t)(g + 1) * HSLICE, cb_[cur ^ 1]);
            cur ^= 1;
        }
    }

    // 7) MLP head (bf16 MFMA, A = Hlstm slices 1..96) + output
    zero_range<<<30720, 256, 0, stream>>>((float*)x1H, 7864320);   // x1 pads must be 0
    gemm_bf16<1,1><<<dim3(ROWS/128, 3), 256, 0, stream>>>(
        HlstmH + HSLICE, 608, Wm0H, 608,
        nullptr, x1H, x1L, 320, ROWS, HDdim, 608, mlp_b0, mlp_a0);
    gemm_bf16<0,1><<<dim3(ROWS/128, 3), 256, 0, stream>>>(
        x1H, 320, Wm1H, 320,
        x2, nullptr, nullptr, 304, ROWS, HDdim, 320, mlp_b1, mlp_a1);
    out_kernel<<<ROWS / 4, 256, 0, stream>>>(x2, 304, out_w, out_b, out);
}

// Round 22
// 2752.290 us; speedup vs baseline: 1.6850x; 1.0155x over previous
//
#include <hip/hip_runtime.h>
#include <cstdint>
#include <cstddef>

#define Bdim 256
#define Ndim 96
#define Edim 1024
#define HDdim 300
#define Ldim 2
#define LHdim 600
#define NCdim 7
#define GDdim 900              // HD*(L+1)
#define ROWS (Bdim*Ndim)       // 24576
#define HSLICE 155648          // 256*608 elements per Hlstm time-slice

typedef unsigned short u16;
typedef unsigned int   u32;
typedef float f32x4 __attribute__((ext_vector_type(4)));
typedef short bf16x8 __attribute__((ext_vector_type(8)));
typedef unsigned short u16x4 __attribute__((ext_vector_type(4)));

// Identity row-perm constants
#define IDP 0x7FFFFFFF, 1, 30, 0, 0

__device__ inline u16 f2bf(float x) {
    u32 u = __builtin_bit_cast(u32, x);
    u32 r = (u + 0x7fffu + ((u >> 16) & 1u)) >> 16;   // RNE
    return (u16)r;
}
__device__ inline float bf2f(u16 h) {
    u32 u = ((u32)h) << 16;
    return __builtin_bit_cast(float, u);
}

// ---------------------------------------------------------------------------
// Pure single-bf16 MFMA GEMM (m97-style: 2 LDS tiles, 16 MFMA/chunk),
// bx-major bijective XCD swizzle, reg->LDS staging.
// C = act(A·W^T + bias). K mult of 32; lda/ldw mult 8; M mult of 128;
// W must have gridDim.y*128 rows allocated (pad rows zeroed).
// OUT: 0 -> fp32 C; 1 -> bf16 Ch only. ACT: 1 -> prelu(aptr).
// ---------------------------------------------------------------------------
template<int OUT, int ACT>
__global__ __launch_bounds__(256) void gemm_bf16(
    const u16* __restrict__ Ah, int lda,
    const u16* __restrict__ Wh, int ldw,
    float* __restrict__ C, u16* __restrict__ Ch, int ldc,
    int M, int Nd, int K,
    const float* __restrict__ bias, const float* __restrict__ aptr)
{
    __shared__ u16 At[4][1024];
    __shared__ u16 Wt[4][1024];
    const int tid  = threadIdx.x;
    const int ny  = gridDim.y;
    const int nwg = gridDim.x * ny;
    const int lin = blockIdx.y * gridDim.x + blockIdx.x;
    const int q = nwg >> 3, r8 = nwg & 7;
    const int xcd = lin & 7, off = lin >> 3;
    const int swz = (xcd < r8) ? xcd * (q + 1) + off
                               : r8 * (q + 1) + (xcd - r8) * q + off;
    const int bm   = (swz / ny) * 128;
    const int bn   = (swz % ny) * 128;
    const int wv   = tid >> 6;
    const int lane = tid & 63;
    const int wr   = (wv >> 1) * 64;
    const int wc   = (wv & 1) * 64;
    const int l15  = lane & 15;
    const int kseg = lane >> 4;

    f32x4 acc[4][4];
    #pragma unroll
    for (int i = 0; i < 4; ++i)
        #pragma unroll
        for (int j = 0; j < 4; ++j) acc[i][j] = (f32x4){0.f,0.f,0.f,0.f};

    const int srow = tid & 127;
    const bool isA = (tid < 128);
    const int gr   = isA ? (bm + srow) : (bn + srow);
    const int glim = isA ? M : 0x7FFFFFFF;        // W pad rows allocated+zeroed
    const u16* pbase = (isA ? Ah : Wh) + (size_t)gr * (isA ? lda : ldw);
    u16* dst = isA ? &At[0][0] : &Wt[0][0];

    for (int k0 = 0; k0 < K; k0 += 32) {
        __syncthreads();
        {
            const bool ok = (gr < glim);
            #pragma unroll
            for (int s = 0; s < 4; ++s) {
                bf16x8 v = {0,0,0,0,0,0,0,0};
                if (ok) v = *(const bf16x8*)(pbase + k0 + s * 8);
                *(bf16x8*)(dst + s * 1024 + srow * 8) = v;
            }
        }
        __syncthreads();
        bf16x8 a[4], b[4];
        #pragma unroll
        for (int f = 0; f < 4; ++f) {
            int ar = wr + f * 16 + l15;
            int br = wc + f * 16 + l15;
            a[f] = *(const bf16x8*)&At[kseg][ar * 8];
            b[f] = *(const bf16x8*)&Wt[kseg][br * 8];
        }
        #pragma unroll
        for (int i = 0; i < 4; ++i)
            #pragma unroll
            for (int j = 0; j < 4; ++j)
                acc[i][j] = __builtin_amdgcn_mfma_f32_16x16x32_bf16(a[i], b[j], acc[i][j], 0, 0, 0);
    }

    const float av = (ACT == 1) ? *aptr : 0.f;
    const int r4 = (lane >> 4) * 4;
    #pragma unroll
    for (int j = 0; j < 4; ++j) {
        int col = bn + wc + j * 16 + l15;
        if (col >= Nd) continue;
        float bv = bias ? bias[col] : 0.f;
        #pragma unroll
        for (int i = 0; i < 4; ++i) {
            #pragma unroll
            for (int rr = 0; rr < 4; ++rr) {
                int row = bm + wr + i * 16 + r4 + rr;
                if (row >= M) continue;
                float v = acc[i][j][rr] + bv;
                if (ACT == 1) v = (v >= 0.f) ? v : av * v;
                if (OUT == 0) {
                    C[(size_t)row * ldc + col] = v;
                } else {
                    Ch[(size_t)row * ldc + col] = f2bf(v);
                }
            }
        }
    }
}

// ---------------------------------------------------------------------------
// fp32 -> bf16 (H only; lo halves are dead since all GEMMs are single-bf16).
// 4 rows/block, 8 cols/thread.
// ---------------------------------------------------------------------------
__global__ __launch_bounds__(256) void split_rows8(
    const float* __restrict__ src, int srcld,
    int pmask, int pmul1, int pshift, int pmul2, int padd,
    u16* __restrict__ dstH, int dstld,
    int wcols, int validK, int validRows)
{
    const int r = blockIdx.y * 4 + (threadIdx.x >> 6);
    const int c = (blockIdx.x * 64 + (threadIdx.x & 63)) * 8;
    if (c >= wcols) return;
    const int sr = (r & pmask) * pmul1 + (r >> pshift) * pmul2 + padd;
    const float* s = src + (size_t)sr * srcld;
    const bool rok = (r < validRows);
    float v[8];
    if (rok && c + 8 <= validK) {
        *(float4*)&v[0] = *(const float4*)(s + c);
        *(float4*)&v[4] = *(const float4*)(s + c + 4);
    } else {
        #pragma unroll
        for (int u = 0; u < 8; ++u) v[u] = (rok && c + u < validK) ? s[c + u] : 0.f;
    }
    bf16x8 H8;
    #pragma unroll
    for (int u = 0; u < 8; ++u) H8[u] = (short)f2bf(v[u]);
    *(bf16x8*)(dstH + (size_t)r * dstld + c) = H8;
}

// biasP[n'] = b_ih[orig]+b_hh[orig], orig = (n'&3)*600+(n'>>2)
__global__ __launch_bounds__(256) void bias_perm(
    const float* __restrict__ bih, const float* __restrict__ bhh, float* __restrict__ dst)
{
    int n = blockIdx.x * 256 + threadIdx.x;
    if (n >= 4 * LHdim) return;
    int o = (n & 3) * LHdim + (n >> 2);
    dst[n] = bih[o] + bhh[o];
}

// Wr2f[l][r][c]: r<300 -> wr0[l][r][c], else wr1[l][r-300][c]
__global__ __launch_bounds__(256) void wr_cat(
    const float* __restrict__ wr0, const float* __restrict__ wr1, float* __restrict__ dst)
{
    int c = blockIdx.x * 256 + threadIdx.x;
    if (c >= HDdim) return;
    int lr = blockIdx.y;
    int l = lr / (2 * HDdim), r = lr % (2 * HDdim);
    const float* src = (r < HDdim)
        ? wr0 + ((size_t)l * HDdim + r) * HDdim
        : wr1 + ((size_t)l * HDdim + (r - HDdim)) * HDdim;
    dst[(size_t)lr * HDdim + c] = src[c];
}

__global__ __launch_bounds__(256) void zero_range(float* __restrict__ p, int n)
{
    int i = blockIdx.x * 256 + threadIdx.x;
    if (i < n) p[i] = 0.f;
}

// ---------------------------------------------------------------------------
__global__ __launch_bounds__(256) void norm_kernel(const float* __restrict__ f, float* __restrict__ invn)
{
    int row  = blockIdx.x * 4 + (threadIdx.x >> 6);
    int lane = threadIdx.x & 63;
    const float* fr = f + (size_t)row * Edim;
    float ss = 0.f;
    for (int t = lane; t < Edim; t += 64) { float v = fr[t]; ss = fmaf(v, v, ss); }
    #pragma unroll
    for (int o = 32; o > 0; o >>= 1) ss += __shfl_down(ss, o);
    if (lane == 0) invn[row] = 1.f / (sqrtf(ss) + 1e-8f);
}

__global__ __launch_bounds__(256) void simadj_kernel(
    const float* __restrict__ f, const float* __restrict__ invn,
    const float* __restrict__ entro, const float* __restrict__ alphap,
    const float* __restrict__ thrp, uint8_t* __restrict__ adj)
{
    int b = blockIdx.x;
    __shared__ float S[16][100];
    int tid = threadIdx.x;
    int i0 = (tid >> 4) * 6, j0 = (tid & 15) * 6;
    float acc[6][6];
    #pragma unroll
    for (int i = 0; i < 6; ++i)
        #pragma unroll
        for (int j = 0; j < 6; ++j) acc[i][j] = 0.f;
    const float* fb = f + (size_t)b * Ndim * Edim;

    for (int k0 = 0; k0 < Edim; k0 += 16) {
        __syncthreads();
        #pragma unroll
        for (int r = 0; r < 6; ++r) {
            int n = (tid >> 4) + r * 16;
            S[tid & 15][n] = fb[(size_t)n * Edim + k0 + (tid & 15)];
        }
        __syncthreads();
        #pragma unroll
        for (int kk = 0; kk < 16; ++kk) {
            float a[6], bb[6];
            #pragma unroll
            for (int u = 0; u < 6; ++u) a[u] = S[kk][i0 + u];
            #pragma unroll
            for (int u = 0; u < 6; ++u) bb[u] = S[kk][j0 + u];
            #pragma unroll
            for (int i = 0; i < 6; ++i)
                #pragma unroll
                for (int j = 0; j < 6; ++j)
                    acc[i][j] = fmaf(a[i], bb[j], acc[i][j]);
        }
    }

    float alpha = *alphap, thr = *thrp;
    float onem = 1.f - alpha;
    #pragma unroll
    for (int i = 0; i < 6; ++i) {
        int ii = i0 + i;
        float inv_i = invn[b * Ndim + ii];
        #pragma unroll
        for (int j = 0; j < 6; ++j) {
            int jj = j0 + j;
            float simv = acc[i][j] * inv_i * invn[b * Ndim + jj];
            float comb = alpha * entro[b * Ndim + jj] + onem * simv;
            adj[((size_t)b * Ndim + ii) * Ndim + jj] = (comb > thr) ? 1 : 0;
        }
    }
}

// k[r] = H[r,:300] . wk   (q cancels in the adjacency softmax; not computed)
__global__ __launch_bounds__(256) void k_kernel(
    const float* __restrict__ Hsrc, const float* __restrict__ wk,
    float* __restrict__ k)
{
    int row  = blockIdx.x * 4 + (threadIdx.x >> 6);
    int lane = threadIdx.x & 63;
    const float* h = Hsrc + (size_t)row * GDdim;
    float sk = 0.f;
    for (int t = lane; t < HDdim; t += 64) sk = fmaf(h[t], wk[t], sk);
    #pragma unroll
    for (int o = 32; o > 0; o >>= 1) sk += __shfl_down(sk, o);
    if (lane == 0) k[row] = sk;
}

// ---------------------------------------------------------------------------
// Fused GAT attention for one batch b (q, gat_b cancel in softmax).
// bf16 LDS for P and V tiles (77 KB total -> 2 blocks/CU, was 147 KB @ 1).
// V combined: cols 0..299 = V0, 300..599 = V1, row stride 600 (n-major rows).
// ---------------------------------------------------------------------------
__global__ __launch_bounds__(256) void gat_fused(
    const float* __restrict__ kbuf, const uint8_t* __restrict__ adj,
    const int* __restrict__ smask,
    const float* __restrict__ V,
    float* __restrict__ Mout)
{
    __shared__ u16 P0[96][100];
    __shared__ u16 P1[96][100];
    __shared__ u16 Vs0[96][96];
    __shared__ u16 Vs1[96][96];
    __shared__ float ek[96];
    __shared__ float rden[96];
    __shared__ float red[256];
    const int b = blockIdx.x;
    const int tid = threadIdx.x;

    float kj = (tid < Ndim) ? kbuf[tid * Bdim + b] : -1e30f;
    red[tid] = kj;
    __syncthreads();
    #pragma unroll
    for (int s = 128; s > 0; s >>= 1) {
        if (tid < s) red[tid] = fmaxf(red[tid], red[tid + s]);
        __syncthreads();
    }
    float kmax = red[0];
    if (tid < Ndim) ek[tid] = expf(kj - kmax);
    __syncthreads();
    if (tid < Ndim) {
        const uint8_t* ar = adj + ((size_t)b * Ndim + tid) * Ndim;
        float s = 0.f;
        for (int j = 0; j < Ndim; ++j) if (ar[j]) s += ek[j];
        rden[tid] = 1.f / s;   // diagonal always allowed -> s > 0
    }
    __syncthreads();
    for (int idx = tid; idx < Ndim * Ndim; idx += 256) {
        int i = idx / Ndim, j = idx - i * Ndim;
        float a = adj[((size_t)b * Ndim + i) * Ndim + j] ? ek[j] * rden[i] : 0.f;
        int s = smask[((size_t)b * Ndim + i) * Ndim + j];
        P0[i][j] = s ? f2bf(a) : (u16)0;
        P1[i][j] = s ? (u16)0 : f2bf(a);
    }
    __syncthreads();

    const int ti = tid >> 4, td = tid & 15;
    const int i0 = ti * 6, dbase = td * 6;
    for (int p = 0; p < 4; ++p) {
        const int d0 = p * 96;
        const int dw = (p == 3) ? (HDdim - 288) : 96;
        for (int idx = tid; idx < 96 * 24; idx += 256) {
            int j = idx / 24, q4 = (idx - j * 24) * 4;
            if (q4 < dw) {
                size_t g = ((size_t)(j * Bdim + b)) * (2 * HDdim) + d0 + q4;
                float4 a = *(const float4*)(V + g);
                float4 c = *(const float4*)(V + g + HDdim);
                u16x4 ua = { f2bf(a.x), f2bf(a.y), f2bf(a.z), f2bf(a.w) };
                u16x4 uc = { f2bf(c.x), f2bf(c.y), f2bf(c.z), f2bf(c.w) };
                *(u16x4*)&Vs0[j][q4] = ua;
                *(u16x4*)&Vs1[j][q4] = uc;
            }
        }
        __syncthreads();
        float acc[6][6];
        #pragma unroll
        for (int ii = 0; ii < 6; ++ii)
            #pragma unroll
            for (int dd = 0; dd < 6; ++dd) acc[ii][dd] = 0.f;
        for (int j = 0; j < Ndim; j += 2) {
            // P: pair (j, j+1) packed in one u32; lo=j, hi=j+1
            float paj[6], pajn[6], pbj[6], pbjn[6];
            #pragma unroll
            for (int ii = 0; ii < 6; ++ii) {
                u32 w0 = *(const u32*)&P0[i0 + ii][j];
                u32 w1 = *(const u32*)&P1[i0 + ii][j];
                paj[ii]  = __builtin_bit_cast(float, w0 << 16);
                pajn[ii] = __builtin_bit_cast(float, w0 & 0xffff0000u);
                pbj[ii]  = __builtin_bit_cast(float, w1 << 16);
                pbjn[ii] = __builtin_bit_cast(float, w1 & 0xffff0000u);
            }
            // V rows j and j+1: 3 u32 each (d pairs)
            float v0a[6], v0b[6], v1a[6], v1b[6];
            #pragma unroll
            for (int dd = 0; dd < 3; ++dd) {
                u32 wa = *(const u32*)&Vs0[j][dbase + 2 * dd];
                u32 wb = *(const u32*)&Vs0[j + 1][dbase + 2 * dd];
                u32 wc2 = *(const u32*)&Vs1[j][dbase + 2 * dd];
                u32 wd = *(const u32*)&Vs1[j + 1][dbase + 2 * dd];
                v0a[2*dd]   = __builtin_bit_cast(float, wa << 16);
                v0a[2*dd+1] = __builtin_bit_cast(float, wa & 0xffff0000u);
                v0b[2*dd]   = __builtin_bit_cast(float, wb << 16);
                v0b[2*dd+1] = __builtin_bit_cast(float, wb & 0xffff0000u);
                v1a[2*dd]   = __builtin_bit_cast(float, wc2 << 16);
                v1a[2*dd+1] = __builtin_bit_cast(float, wc2 & 0xffff0000u);
                v1b[2*dd]   = __builtin_bit_cast(float, wd << 16);
                v1b[2*dd+1] = __builtin_bit_cast(float, wd & 0xffff0000u);
            }
            #pragma unroll
            for (int ii = 0; ii < 6; ++ii)
                #pragma unroll
                for (int dd = 0; dd < 6; ++dd) {
                    acc[ii][dd] += paj[ii]  * v0a[dd] + pbj[ii]  * v1a[dd]
                                 + pajn[ii] * v0b[dd] + pbjn[ii] * v1b[dd];
                }
        }
        __syncthreads();
        #pragma unroll
        for (int ii = 0; ii < 6; ++ii) {
            #pragma unroll
            for (int dd = 0; dd < 6; ++dd) {
                int d = dbase + dd;
                if (d < dw)
                    Mout[((size_t)((i0 + ii) * Bdim + b)) * GDdim + d0 + d] = acc[ii][dd];
            }
        }
    }
}

// ---------------------------------------------------------------------------
// Per-step LSTM, SINGLE-bf16 h and W (round 21 verified). Round-13 schedule:
// double-buffered LDS, one barrier per k-chunk; T14 prefetch; Hlstm-slice
// ping-pong. 2 MFMA/chunk. Tile 32b x 64g, grid (8,38).
// ---------------------------------------------------------------------------
__global__ __launch_bounds__(256) void lstm_bf16(
    const u16* __restrict__ hH,
    const float* __restrict__ cin,
    const u16* __restrict__ WH,                  // (2432 x 608), pads zero
    const float* __restrict__ zt,
    u16* __restrict__ hHo,
    float* __restrict__ cout)
{
    __shared__ u16 As[2][4][256];
    __shared__ u16 Ws[2][4][512];
    __shared__ __align__(16) float gates[32][68];
    const int tid = threadIdx.x;
    const int bm = blockIdx.x * 32;
    const int bn = blockIdx.y * 64;
    const int wv = tid >> 6;
    const int lane = tid & 63;
    const int l15 = lane & 15;
    const int kseg = lane >> 4;
    const float4 fz = make_float4(0.f, 0.f, 0.f, 0.f);

    // --- T14: issue cell-phase loads NOW; consumed after the k-loop ---
    const int prow0 = tid >> 4,        pui0 = tid & 15;
    const int prow1 = (tid + 256) >> 4, pui1 = tid & 15;     // cell1 = tid+256
    const int pn0 = bn + pui0 * 4,  pn1 = bn + pui1 * 4;
    const int pu0 = pn0 >> 2,       pu1 = pn1 >> 2;
    const bool ok0 = (pu0 < LHdim), ok1 = (pu1 < LHdim);
    const int bb0 = bm + prow0,     bb1 = bm + prow1;
    float4 z0 = ok0 ? *(const float4*)(zt + (size_t)bb0 * (4 * LHdim) + pn0) : fz;
    float4 z1 = ok1 ? *(const float4*)(zt + (size_t)bb1 * (4 * LHdim) + pn1) : fz;
    float ci0 = ok0 ? cin[bb0 * LHdim + pu0] : 0.f;
    float ci1 = ok1 ? cin[bb1 * LHdim + pu1] : 0.f;

    // A staging: threads 0..127, one bf16x8 each (wave-uniform split)
    const int av = tid & 127;
    const int arow = av >> 2, akc = av & 3;
    const u16* asrc = hH + (size_t)(bm + arow) * 608 + akc * 8;
    const int aoff = akc * 256 + arow * 8;
    const bool doA = (tid < 128);
    // W staging: all 256 threads, one bf16x8 each
    const int wrow = tid >> 2, wkc = tid & 3;
    const u16* wsrc = WH + (size_t)(bn + wrow) * 608 + wkc * 8;
    const int woff2 = wrow * 8;

    f32x4 acc[2];
    acc[0] = (f32x4){0.f,0.f,0.f,0.f};
    acc[1] = (f32x4){0.f,0.f,0.f,0.f};

    // preload chunk 0 (upper threads load duplicate A addrs; store is guarded)
    bf16x8 ra = *(const bf16x8*)(asrc);
    bf16x8 rw = *(const bf16x8*)(wsrc);

    #pragma unroll
    for (int kc = 0; kc < 19; ++kc) {
        const int buf = kc & 1;
        if (doA) *(bf16x8*)(&As[buf][0][0] + aoff) = ra;
        *(bf16x8*)(&Ws[buf][wkc][woff2]) = rw;
        if (kc + 1 < 19) {                      // prefetch next chunk
            ra = *(const bf16x8*)(asrc + (kc + 1) * 32);
            rw = *(const bf16x8*)(wsrc + (kc + 1) * 32);
        }
        __syncthreads();                        // single barrier per chunk
        bf16x8 a0, a1, b;
        a0 = *(const bf16x8*)&As[buf][kseg][(l15) * 8];
        a1 = *(const bf16x8*)&As[buf][kseg][(16 + l15) * 8];
        b  = *(const bf16x8*)&Ws[buf][kseg][(wv * 16 + l15) * 8];
        acc[0] = __builtin_amdgcn_mfma_f32_16x16x32_bf16(a0, b, acc[0], 0, 0, 0);
        acc[1] = __builtin_amdgcn_mfma_f32_16x16x32_bf16(a1, b, acc[1], 0, 0, 0);
    }

    const int r4 = (lane >> 4) * 4;
    __syncthreads();
    #pragma unroll
    for (int i = 0; i < 2; ++i)
        #pragma unroll
        for (int rr = 0; rr < 4; ++rr)
            gates[i * 16 + r4 + rr][wv * 16 + l15] = acc[i][rr];
    __syncthreads();

    // fused cell: 2 cells per thread, using prefetched z/c
    if (ok0) {
        float4 g = *(const float4*)&gates[prow0][pui0 * 4];
        float gi = g.x + z0.x;
        float gf = g.y + z0.y;
        float gg = g.z + z0.z;
        float go = g.w + z0.w;
        float si = 1.f / (1.f + expf(-gi));
        float sf = 1.f / (1.f + expf(-gf));
        float so = 1.f / (1.f + expf(-go));
        float cn = sf * ci0 + si * tanhf(gg);
        float hn = so * tanhf(cn);
        cout[bb0 * LHdim + pu0] = cn;
        hHo[(size_t)bb0 * 608 + pu0] = f2bf(hn);
    }
    if (ok1) {
        float4 g = *(const float4*)&gates[prow1][pui1 * 4];
        float gi = g.x + z1.x;
        float gf = g.y + z1.y;
        float gg = g.z + z1.z;
        float go = g.w + z1.w;
        float si = 1.f / (1.f + expf(-gi));
        float sf = 1.f / (1.f + expf(-gf));
        float so = 1.f / (1.f + expf(-go));
        float cn = sf * ci1 + si * tanhf(gg);
        float hn = so * tanhf(cn);
        cout[bb1 * LHdim + pu1] = cn;
        hHo[(size_t)bb1 * 608 + pu1] = f2bf(hn);
    }
}

__global__ __launch_bounds__(256) void out_kernel(
    const float* __restrict__ x, int ldx, const float* __restrict__ ow,
    const float* __restrict__ ob, float* __restrict__ out)
{
    int r    = blockIdx.x * 4 + (threadIdx.x >> 6);
    int lane = threadIdx.x & 63;
    const float* xr = x + (size_t)r * ldx;
    float acc[NCdim];
    #pragma unroll
    for (int n = 0; n < NCdim; ++n) acc[n] = 0.f;
    for (int t = lane; t < HDdim; t += 64) {
        float xv = xr[t];
        #pragma unroll
        for (int n = 0; n < NCdim; ++n) acc[n] = fmaf(xv, ow[n * HDdim + t], acc[n]);
    }
    #pragma unroll
    for (int o = 32; o > 0; o >>= 1)
        #pragma unroll
        for (int n = 0; n < NCdim; ++n) acc[n] += __shfl_down(acc[n], o);
    if (lane == 0) {
        int b = r & 255, nn = r >> 8;
        #pragma unroll
        for (int n = 0; n < NCdim; ++n) out[((size_t)b * Ndim + nn) * NCdim + n] = acc[n] + ob[n];
    }
}

// ---------------------------------------------------------------------------
extern "C" void kernel_launch(void* const* d_in, const int* in_sizes, int n_in,
                              void* d_out, int out_size, void* d_ws, size_t ws_size,
                              hipStream_t stream)
{
    const float*  features  = (const float*)d_in[0];
    const int*    s_mask    = (const int*)  d_in[1];
    const float*  entro     = (const float*)d_in[2];
    const float*  alpha     = (const float*)d_in[3];
    const float*  threshold = (const float*)d_in[4];
    const float*  fc1_w     = (const float*)d_in[5];
    const float*  fc1_b     = (const float*)d_in[6];
    const float*  gat_w     = (const float*)d_in[7];
    const float*  gat_b     = (const float*)d_in[8];
    const float*  wr0       = (const float*)d_in[9];
    const float*  wr1       = (const float*)d_in[10];
    const float*  enhance_w = (const float*)d_in[11];
    const float*  enhance_b = (const float*)d_in[12];
    const float*  prelu_a   = (const float*)d_in[13];
    const float*  lstm_w_ih = (const float*)d_in[14];
    const float*  lstm_w_hh = (const float*)d_in[15];
    const float*  lstm_b_ih = (const float*)d_in[16];
    const float*  lstm_b_hh = (const float*)d_in[17];
    const float*  mlp_w0    = (const float*)d_in[18];
    const float*  mlp_b0    = (const float*)d_in[19];
    const float*  mlp_a0    = (const float*)d_in[20];
    const float*  mlp_w1    = (const float*)d_in[21];
    const float*  mlp_b1    = (const float*)d_in[22];
    const float*  mlp_a1    = (const float*)d_in[23];
    const float*  out_w     = (const float*)d_in[24];
    const float*  out_b     = (const float*)d_in[25];
    float* out = (float*)d_out;
    char* ws = (char*)d_ws;
    (void)gat_b;

    // ---- fixed workspace layout (bytes, 256-aligned; offsets unchanged) ----
    uint8_t* adj   = (uint8_t*)(ws + 0);               //  2,359,296
    float*   invn  = (float*)(ws + 2359296);
    float*   kbuf  = (float*)(ws + 2555904);
    float*   biasP = (float*)(ws + 2654208);
    float*   c0    = (float*)(ws + 2663936);           //    614,400
    float*   c1    = (float*)(ws + 3278336);
    u16*     WhhPH = (u16*)(ws + 5137920);             //  2,957,312 (2432 x 608)
    u16*     WihPH = (u16*)(ws + 11052544);            //  9,494,528 (2432 x 1952)
    u16*     EwH   = (u16*)(ws + 30041600);            //  2,097,152 (1024 x 1024)
    u16*     Fc1H  = (u16*)(ws + 34235904);            //    786,432 (384 x 1024)
    float*   Wr2f  = (float*)(ws + 35808768);          //  1,440,256 (2 x 600 x 300)
    u16*     Wr2H  = (u16*)(ws + 37249024);            //    819,200 (2 x 640 x 320)
    u16*     Wm0H  = (u16*)(ws + 38887424);            //    524,288 (384 x 608)
    u16*     Wm1H  = (u16*)(ws + 39936000);            //    262,144 (384 x 320)
    u16*     FfH   = (u16*)(ws + 40460288);            // 50,331,648 (ROWS x 1024)
    float*   Hcat  = (float*)(ws + 141123584);         // 88,473,600 (ROWS,900) n-major
    u16*     HsH   = (u16*)(ws + 229597184);           // 15,728,640 (ROWS x 320)
    // V (GAT, fp32 ROWSx600) aliases Hlstm (97 slices x 256 x 608 bf16 H-only)
    float*   V      = (float*)(ws + 261054464);        // 58,982,400
    u16*     HlstmH = (u16*)(ws + 261054464);          // 30,195,712 (97 slices)
    // MLP scratch aliases Hcat (dead after last Hcat split)
    u16*     x1H   = (u16*)Hcat;                       // 15,728,640 (ROWS x 320)
    float*   x2    = (float*)(ws + 141123584 + 31457280);   // 29,884,416 (ROWS x 304)

    // ---- tier selection for chunked seq/zin region ----
    const size_t fixedNeed = 321445888ull;
    const size_t perT = 4456448ull;                    // zin(2,457,600)+seq region
    int T;
    if      (ws_size >= fixedNeed + 96ull * perT) T = 96;
    else if (ws_size >= fixedNeed + 48ull * perT) T = 48;
    else if (ws_size >= fixedNeed + 32ull * perT) T = 32;
    else if (ws_size >= fixedNeed + 16ull * perT) T = 16;
    else if (ws_size >= fixedNeed +  8ull * perT) T = 8;
    else return;                                       // visible failure, no OOB
    char* cr = ws + fixedNeed;
    float* zin  = (float*)cr;                                // (Mc,2400)
    u16*   seqH = (u16*)(cr + (size_t)T * 2457600);          // (Mc,1952)

    // 1) norms + adjacency
    norm_kernel<<<ROWS / 4, 256, 0, stream>>>(features, invn);
    simadj_kernel<<<Bdim, 256, 0, stream>>>(features, invn, entro, alpha, threshold, adj);

    // 2) weight/activation conversions (bf16 H only — lo halves dead)
    split_rows8<<<dim3(2, ROWS / 4), 256, 0, stream>>>(            // features n-major full
        features, Edim, 255, Ndim, 8, 1, 0, FfH, Edim, Edim, Edim, ROWS);
    split_rows8<<<dim3(2, 96), 256, 0, stream>>>(                  // fc1_w (384x1024)
        fc1_w, Edim, IDP, Fc1H, Edim, Edim, Edim, HDdim);
    split_rows8<<<dim3(2, 256), 256, 0, stream>>>(                 // enhance_w
        enhance_w, Edim, IDP, EwH, Edim, Edim, Edim, Edim);
    split_rows8<<<dim3(4, 608), 256, 0, stream>>>(                 // Wih gate-interleaved
        lstm_w_ih, Edim + GDdim, 3, LHdim, 2, 1, 0, WihPH, 1952, 1952, 1924, 2400);
    split_rows8<<<dim3(2, 608), 256, 0, stream>>>(                 // Whh gate-interleaved
        lstm_w_hh, LHdim, 3, LHdim, 2, 1, 0, WhhPH, 608, 608, LHdim, 2400);
    split_rows8<<<dim3(2, 96), 256, 0, stream>>>(                  // mlp_w0 (384x608)
        mlp_w0, LHdim, IDP, Wm0H, 608, 608, LHdim, HDdim);
    split_rows8<<<dim3(1, 96), 256, 0, stream>>>(                  // mlp_w1 (384x320)
        mlp_w1, HDdim, IDP, Wm1H, 320, 320, HDdim, HDdim);
    wr_cat<<<dim3(2, 2 * Ldim * HDdim), 256, 0, stream>>>(wr0, wr1, Wr2f);
    for (int l = 0; l < Ldim; ++l)
        split_rows8<<<dim3(1, 160), 256, 0, stream>>>(             // Wr2 (640x320 per layer)
            Wr2f + (size_t)l * 2 * HDdim * HDdim, HDdim, IDP,
            Wr2H + (size_t)l * 640 * 320, 320, 320, HDdim, 2 * HDdim);
    bias_perm<<<10, 256, 0, stream>>>(lstm_b_ih, lstm_b_hh, biasP);
    zero_range<<<1200, 256, 0, stream>>>(c0, 307200);              // c0, c1

    // 3) H0 = prelu(features @ fc1_w^T + fc1_b) -> Hcat[:, 0:300] (bf16 MFMA)
    gemm_bf16<0,1><<<dim3(ROWS/128, 3), 256, 0, stream>>>(
        FfH, Edim, Fc1H, Edim,
        Hcat, nullptr, GDdim, ROWS, HDdim, Edim, fc1_b, prelu_a);

    // 4) GAT layers (bf16 MFMA V projection, fused softmax+aggregation)
    for (int l = 0; l < Ldim; ++l) {
        const float* Hsrc = Hcat + l * HDdim;
        k_kernel<<<ROWS / 4, 256, 0, stream>>>(Hsrc, gat_w + l * 2 * HDdim + HDdim, kbuf);
        split_rows8<<<dim3(1, ROWS / 4), 256, 0, stream>>>(        // Hsrc -> bf16 (K=320)
            Hsrc, GDdim, IDP, HsH, 320, 320, HDdim, ROWS);
        gemm_bf16<0,0><<<dim3(ROWS/128, 5), 256, 0, stream>>>(
            HsH, 320, Wr2H + (size_t)l * 640 * 320, 320,
            V, nullptr, 2 * HDdim, ROWS, 2 * HDdim, 320, nullptr, nullptr);
        gat_fused<<<Bdim, 256, 0, stream>>>(
            kbuf, adj, s_mask, V, Hcat + (l + 1) * HDdim);
    }

    // 5) zero Hlstm H region (pads + slice 0 = h_0; aliased V until now)
    zero_range<<<29489, 256, 0, stream>>>((float*)HlstmH, 7548928);

    // 6) chunked: enhance (bf16) -> Hcat split -> zin (bf16) -> LSTM (bf16)
    int cur = 0;
    float* cb_[2] = {c0, c1};
    for (int t0 = 0; t0 < Ndim; t0 += T) {
        int Mc = T * Bdim;
        gemm_bf16<1,1><<<dim3(Mc/128, 8), 256, 0, stream>>>(       // bf16 enhance -> seqH
            FfH + (size_t)t0 * Bdim * Edim, Edim, EwH, Edim,
            nullptr, seqH, 1952, Mc, Edim, Edim, enhance_b, prelu_a);
        split_rows8<<<dim3(2, Mc / 4), 256, 0, stream>>>(
            Hcat, GDdim, 0x7FFFFFFF, 1, 30, 0, t0 * Bdim,
            seqH + 1024, 1952, 928, GDdim, Mc);
        gemm_bf16<0,0><<<dim3(Mc/128, 19), 256, 0, stream>>>(      // bf16 zin
            seqH, 1952, WihPH, 1952,
            zin, nullptr, 4 * LHdim, Mc, 4 * LHdim, 1952, biasP, nullptr);
        for (int tl = 0; tl < T; ++tl) {
            const int g = t0 + tl;                    // global step, 0-based
            lstm_bf16<<<dim3(8, 38), 256, 0, stream>>>(
                HlstmH + (size_t)g * HSLICE, cb_[cur], WhhPH,
                zin + (size_t)tl * Bdim * 4 * LHdim,
                HlstmH + (size_t)(g + 1) * HSLICE, cb_[cur ^ 1]);
            cur ^= 1;
        }
    }

    // 7) MLP head (bf16 MFMA, A = Hlstm slices 1..96) + output
    zero_range<<<15360, 256, 0, stream>>>((float*)x1H, 3932160);   // x1H pads must be 0
    gemm_bf16<1,1><<<dim3(ROWS/128, 3), 256, 0, stream>>>(
        HlstmH + HSLICE, 608, Wm0H, 608,
        nullptr, x1H, 320, ROWS, HDdim, 608, mlp_b0, mlp_a0);
    gemm_bf16<0,1><<<dim3(ROWS/128, 3), 256, 0, stream>>>(
        x1H, 320, Wm1H, 320,
        x2, nullptr, 304, ROWS, HDdim, 320, mlp_b1, mlp_a1);
    out_kernel<<<ROWS / 4, 256, 0, stream>>>(x2, 304, out_w, out_b, out);
}

// Round 23
// 2627.629 us; speedup vs baseline: 1.7649x; 1.0474x over previous
//
#include <hip/hip_runtime.h>
#include <cstdint>
#include <cstddef>

#define Bdim 256
#define Ndim 96
#define Edim 1024
#define HDdim 300
#define Ldim 2
#define LHdim 600
#define NCdim 7
#define GDdim 900              // HD*(L+1)
#define ROWS (Bdim*Ndim)       // 24576
#define HSLICE 155648          // 256*608 elements per Hlstm time-slice

typedef unsigned short u16;
typedef unsigned int   u32;
typedef float f32x4 __attribute__((ext_vector_type(4)));
typedef short bf16x8 __attribute__((ext_vector_type(8)));
typedef unsigned short u16x4 __attribute__((ext_vector_type(4)));

// Identity row-perm constants
#define IDP 0x7FFFFFFF, 1, 30, 0, 0

__device__ inline u16 f2bf(float x) {
    u32 u = __builtin_bit_cast(u32, x);
    u32 r = (u + 0x7fffu + ((u >> 16) & 1u)) >> 16;   // RNE
    return (u16)r;
}
__device__ inline float bf2f(u16 h) {
    u32 u = ((u32)h) << 16;
    return __builtin_bit_cast(float, u);
}

// ---------------------------------------------------------------------------
// Pure single-bf16 MFMA GEMM (m97-style: 2 LDS tiles, 16 MFMA/chunk),
// bx-major bijective XCD swizzle, reg->LDS staging.
// C = act(A·W^T + bias). K mult of 32; lda/ldw mult 8; M mult of 128;
// W must have gridDim.y*128 rows allocated (pad rows zeroed).
// OUT: 0 -> fp32 C; 1 -> bf16 Ch only. ACT: 1 -> prelu(aptr).
// ---------------------------------------------------------------------------
template<int OUT, int ACT>
__global__ __launch_bounds__(256) void gemm_bf16(
    const u16* __restrict__ Ah, int lda,
    const u16* __restrict__ Wh, int ldw,
    float* __restrict__ C, u16* __restrict__ Ch, int ldc,
    int M, int Nd, int K,
    const float* __restrict__ bias, const float* __restrict__ aptr)
{
    __shared__ u16 At[4][1024];
    __shared__ u16 Wt[4][1024];
    const int tid  = threadIdx.x;
    const int ny  = gridDim.y;
    const int nwg = gridDim.x * ny;
    const int lin = blockIdx.y * gridDim.x + blockIdx.x;
    const int q = nwg >> 3, r8 = nwg & 7;
    const int xcd = lin & 7, off = lin >> 3;
    const int swz = (xcd < r8) ? xcd * (q + 1) + off
                               : r8 * (q + 1) + (xcd - r8) * q + off;
    const int bm   = (swz / ny) * 128;
    const int bn   = (swz % ny) * 128;
    const int wv   = tid >> 6;
    const int lane = tid & 63;
    const int wr   = (wv >> 1) * 64;
    const int wc   = (wv & 1) * 64;
    const int l15  = lane & 15;
    const int kseg = lane >> 4;

    f32x4 acc[4][4];
    #pragma unroll
    for (int i = 0; i < 4; ++i)
        #pragma unroll
        for (int j = 0; j < 4; ++j) acc[i][j] = (f32x4){0.f,0.f,0.f,0.f};

    const int srow = tid & 127;
    const bool isA = (tid < 128);
    const int gr   = isA ? (bm + srow) : (bn + srow);
    const int glim = isA ? M : 0x7FFFFFFF;        // W pad rows allocated+zeroed
    const u16* pbase = (isA ? Ah : Wh) + (size_t)gr * (isA ? lda : ldw);
    u16* dst = isA ? &At[0][0] : &Wt[0][0];

    for (int k0 = 0; k0 < K; k0 += 32) {
        __syncthreads();
        {
            const bool ok = (gr < glim);
            #pragma unroll
            for (int s = 0; s < 4; ++s) {
                bf16x8 v = {0,0,0,0,0,0,0,0};
                if (ok) v = *(const bf16x8*)(pbase + k0 + s * 8);
                *(bf16x8*)(dst + s * 1024 + srow * 8) = v;
            }
        }
        __syncthreads();
        bf16x8 a[4], b[4];
        #pragma unroll
        for (int f = 0; f < 4; ++f) {
            int ar = wr + f * 16 + l15;
            int br = wc + f * 16 + l15;
            a[f] = *(const bf16x8*)&At[kseg][ar * 8];
            b[f] = *(const bf16x8*)&Wt[kseg][br * 8];
        }
        #pragma unroll
        for (int i = 0; i < 4; ++i)
            #pragma unroll
            for (int j = 0; j < 4; ++j)
                acc[i][j] = __builtin_amdgcn_mfma_f32_16x16x32_bf16(a[i], b[j], acc[i][j], 0, 0, 0);
    }

    const float av = (ACT == 1) ? *aptr : 0.f;
    const int r4 = (lane >> 4) * 4;
    #pragma unroll
    for (int j = 0; j < 4; ++j) {
        int col = bn + wc + j * 16 + l15;
        if (col >= Nd) continue;
        float bv = bias ? bias[col] : 0.f;
        #pragma unroll
        for (int i = 0; i < 4; ++i) {
            #pragma unroll
            for (int rr = 0; rr < 4; ++rr) {
                int row = bm + wr + i * 16 + r4 + rr;
                if (row >= M) continue;
                float v = acc[i][j][rr] + bv;
                if (ACT == 1) v = (v >= 0.f) ? v : av * v;
                if (OUT == 0) {
                    C[(size_t)row * ldc + col] = v;
                } else {
                    Ch[(size_t)row * ldc + col] = f2bf(v);
                }
            }
        }
    }
}

// ---------------------------------------------------------------------------
// fp32 -> bf16 (H only). 4 rows/block, 8 cols/thread.
// ---------------------------------------------------------------------------
__global__ __launch_bounds__(256) void split_rows8(
    const float* __restrict__ src, int srcld,
    int pmask, int pmul1, int pshift, int pmul2, int padd,
    u16* __restrict__ dstH, int dstld,
    int wcols, int validK, int validRows)
{
    const int r = blockIdx.y * 4 + (threadIdx.x >> 6);
    const int c = (blockIdx.x * 64 + (threadIdx.x & 63)) * 8;
    if (c >= wcols) return;
    const int sr = (r & pmask) * pmul1 + (r >> pshift) * pmul2 + padd;
    const float* s = src + (size_t)sr * srcld;
    const bool rok = (r < validRows);
    float v[8];
    if (rok && c + 8 <= validK) {
        *(float4*)&v[0] = *(const float4*)(s + c);
        *(float4*)&v[4] = *(const float4*)(s + c + 4);
    } else {
        #pragma unroll
        for (int u = 0; u < 8; ++u) v[u] = (rok && c + u < validK) ? s[c + u] : 0.f;
    }
    bf16x8 H8;
    #pragma unroll
    for (int u = 0; u < 8; ++u) H8[u] = (short)f2bf(v[u]);
    *(bf16x8*)(dstH + (size_t)r * dstld + c) = H8;
}

// biasP[n'] = b_ih[orig]+b_hh[orig], orig = (n'&3)*600+(n'>>2)
__global__ __launch_bounds__(256) void bias_perm(
    const float* __restrict__ bih, const float* __restrict__ bhh, float* __restrict__ dst)
{
    int n = blockIdx.x * 256 + threadIdx.x;
    if (n >= 4 * LHdim) return;
    int o = (n & 3) * LHdim + (n >> 2);
    dst[n] = bih[o] + bhh[o];
}

// Wr2f[l][r][c]: r<300 -> wr0[l][r][c], else wr1[l][r-300][c]
__global__ __launch_bounds__(256) void wr_cat(
    const float* __restrict__ wr0, const float* __restrict__ wr1, float* __restrict__ dst)
{
    int c = blockIdx.x * 256 + threadIdx.x;
    if (c >= HDdim) return;
    int lr = blockIdx.y;
    int l = lr / (2 * HDdim), r = lr % (2 * HDdim);
    const float* src = (r < HDdim)
        ? wr0 + ((size_t)l * HDdim + r) * HDdim
        : wr1 + ((size_t)l * HDdim + (r - HDdim)) * HDdim;
    dst[(size_t)lr * HDdim + c] = src[c];
}

__global__ __launch_bounds__(256) void zero_range(float* __restrict__ p, int n)
{
    int i = blockIdx.x * 256 + threadIdx.x;
    if (i < n) p[i] = 0.f;
}

// ---------------------------------------------------------------------------
__global__ __launch_bounds__(256) void norm_kernel(const float* __restrict__ f, float* __restrict__ invn)
{
    int row  = blockIdx.x * 4 + (threadIdx.x >> 6);
    int lane = threadIdx.x & 63;
    const float* fr = f + (size_t)row * Edim;
    float ss = 0.f;
    for (int t = lane; t < Edim; t += 64) { float v = fr[t]; ss = fmaf(v, v, ss); }
    #pragma unroll
    for (int o = 32; o > 0; o >>= 1) ss += __shfl_down(ss, o);
    if (lane == 0) invn[row] = 1.f / (sqrtf(ss) + 1e-8f);
}

__global__ __launch_bounds__(256) void simadj_kernel(
    const float* __restrict__ f, const float* __restrict__ invn,
    const float* __restrict__ entro, const float* __restrict__ alphap,
    const float* __restrict__ thrp, uint8_t* __restrict__ adj)
{
    int b = blockIdx.x;
    __shared__ float S[16][100];
    int tid = threadIdx.x;
    int i0 = (tid >> 4) * 6, j0 = (tid & 15) * 6;
    float acc[6][6];
    #pragma unroll
    for (int i = 0; i < 6; ++i)
        #pragma unroll
        for (int j = 0; j < 6; ++j) acc[i][j] = 0.f;
    const float* fb = f + (size_t)b * Ndim * Edim;

    for (int k0 = 0; k0 < Edim; k0 += 16) {
        __syncthreads();
        #pragma unroll
        for (int r = 0; r < 6; ++r) {
            int n = (tid >> 4) + r * 16;
            S[tid & 15][n] = fb[(size_t)n * Edim + k0 + (tid & 15)];
        }
        __syncthreads();
        #pragma unroll
        for (int kk = 0; kk < 16; ++kk) {
            float a[6], bb[6];
            #pragma unroll
            for (int u = 0; u < 6; ++u) a[u] = S[kk][i0 + u];
            #pragma unroll
            for (int u = 0; u < 6; ++u) bb[u] = S[kk][j0 + u];
            #pragma unroll
            for (int i = 0; i < 6; ++i)
                #pragma unroll
                for (int j = 0; j < 6; ++j)
                    acc[i][j] = fmaf(a[i], bb[j], acc[i][j]);
        }
    }

    float alpha = *alphap, thr = *thrp;
    float onem = 1.f - alpha;
    #pragma unroll
    for (int i = 0; i < 6; ++i) {
        int ii = i0 + i;
        float inv_i = invn[b * Ndim + ii];
        #pragma unroll
        for (int j = 0; j < 6; ++j) {
            int jj = j0 + j;
            float simv = acc[i][j] * inv_i * invn[b * Ndim + jj];
            float comb = alpha * entro[b * Ndim + jj] + onem * simv;
            adj[((size_t)b * Ndim + ii) * Ndim + jj] = (comb > thr) ? 1 : 0;
        }
    }
}

// k[r] = H[r,:300] . wk   (q cancels in the adjacency softmax; not computed)
__global__ __launch_bounds__(256) void k_kernel(
    const float* __restrict__ Hsrc, const float* __restrict__ wk,
    float* __restrict__ k)
{
    int row  = blockIdx.x * 4 + (threadIdx.x >> 6);
    int lane = threadIdx.x & 63;
    const float* h = Hsrc + (size_t)row * GDdim;
    float sk = 0.f;
    for (int t = lane; t < HDdim; t += 64) sk = fmaf(h[t], wk[t], sk);
    #pragma unroll
    for (int o = 32; o > 0; o >>= 1) sk += __shfl_down(sk, o);
    if (lane == 0) k[row] = sk;
}

// ---------------------------------------------------------------------------
// Fused GAT attention (q, gat_b cancel in softmax). bf16 LDS (77 KB).
// grid (B, 2): block half handles d-passes {2*half, 2*half+1} -> 512 blocks,
// 2 blocks/CU co-resident (round-22 fix: grid was the occupancy limiter).
// V combined: cols 0..299 = V0, 300..599 = V1, row stride 600 (n-major rows).
// ---------------------------------------------------------------------------
__global__ __launch_bounds__(256) void gat_fused(
    const float* __restrict__ kbuf, const uint8_t* __restrict__ adj,
    const int* __restrict__ smask,
    const float* __restrict__ V,
    float* __restrict__ Mout)
{
    __shared__ u16 P0[96][100];
    __shared__ u16 P1[96][100];
    __shared__ u16 Vs0[96][96];
    __shared__ u16 Vs1[96][96];
    __shared__ float ek[96];
    __shared__ float rden[96];
    __shared__ float red[256];
    const int b = blockIdx.x;
    const int half = blockIdx.y;
    const int tid = threadIdx.x;

    float kj = (tid < Ndim) ? kbuf[tid * Bdim + b] : -1e30f;
    red[tid] = kj;
    __syncthreads();
    #pragma unroll
    for (int s = 128; s > 0; s >>= 1) {
        if (tid < s) red[tid] = fmaxf(red[tid], red[tid + s]);
        __syncthreads();
    }
    float kmax = red[0];
    if (tid < Ndim) ek[tid] = expf(kj - kmax);
    __syncthreads();
    if (tid < Ndim) {
        const uint8_t* ar = adj + ((size_t)b * Ndim + tid) * Ndim;
        float s = 0.f;
        for (int j = 0; j < Ndim; ++j) if (ar[j]) s += ek[j];
        rden[tid] = 1.f / s;   // diagonal always allowed -> s > 0
    }
    __syncthreads();
    for (int idx = tid; idx < Ndim * Ndim; idx += 256) {
        int i = idx / Ndim, j = idx - i * Ndim;
        float a = adj[((size_t)b * Ndim + i) * Ndim + j] ? ek[j] * rden[i] : 0.f;
        int s = smask[((size_t)b * Ndim + i) * Ndim + j];
        P0[i][j] = s ? f2bf(a) : (u16)0;
        P1[i][j] = s ? (u16)0 : f2bf(a);
    }
    __syncthreads();

    const int ti = tid >> 4, td = tid & 15;
    const int i0 = ti * 6, dbase = td * 6;
    for (int p = 2 * half; p < 2 * half + 2; ++p) {
        const int d0 = p * 96;
        const int dw = (p == 3) ? (HDdim - 288) : 96;
        for (int idx = tid; idx < 96 * 24; idx += 256) {
            int j = idx / 24, q4 = (idx - j * 24) * 4;
            if (q4 < dw) {
                size_t g = ((size_t)(j * Bdim + b)) * (2 * HDdim) + d0 + q4;
                float4 a = *(const float4*)(V + g);
                float4 c = *(const float4*)(V + g + HDdim);
                u16x4 ua = { f2bf(a.x), f2bf(a.y), f2bf(a.z), f2bf(a.w) };
                u16x4 uc = { f2bf(c.x), f2bf(c.y), f2bf(c.z), f2bf(c.w) };
                *(u16x4*)&Vs0[j][q4] = ua;
                *(u16x4*)&Vs1[j][q4] = uc;
            }
        }
        __syncthreads();
        float acc[6][6];
        #pragma unroll
        for (int ii = 0; ii < 6; ++ii)
            #pragma unroll
            for (int dd = 0; dd < 6; ++dd) acc[ii][dd] = 0.f;
        for (int j = 0; j < Ndim; j += 2) {
            float paj[6], pajn[6], pbj[6], pbjn[6];
            #pragma unroll
            for (int ii = 0; ii < 6; ++ii) {
                u32 w0 = *(const u32*)&P0[i0 + ii][j];
                u32 w1 = *(const u32*)&P1[i0 + ii][j];
                paj[ii]  = __builtin_bit_cast(float, w0 << 16);
                pajn[ii] = __builtin_bit_cast(float, w0 & 0xffff0000u);
                pbj[ii]  = __builtin_bit_cast(float, w1 << 16);
                pbjn[ii] = __builtin_bit_cast(float, w1 & 0xffff0000u);
            }
            float v0a[6], v0b[6], v1a[6], v1b[6];
            #pragma unroll
            for (int dd = 0; dd < 3; ++dd) {
                u32 wa = *(const u32*)&Vs0[j][dbase + 2 * dd];
                u32 wb = *(const u32*)&Vs0[j + 1][dbase + 2 * dd];
                u32 wc2 = *(const u32*)&Vs1[j][dbase + 2 * dd];
                u32 wd = *(const u32*)&Vs1[j + 1][dbase + 2 * dd];
                v0a[2*dd]   = __builtin_bit_cast(float, wa << 16);
                v0a[2*dd+1] = __builtin_bit_cast(float, wa & 0xffff0000u);
                v0b[2*dd]   = __builtin_bit_cast(float, wb << 16);
                v0b[2*dd+1] = __builtin_bit_cast(float, wb & 0xffff0000u);
                v1a[2*dd]   = __builtin_bit_cast(float, wc2 << 16);
                v1a[2*dd+1] = __builtin_bit_cast(float, wc2 & 0xffff0000u);
                v1b[2*dd]   = __builtin_bit_cast(float, wd << 16);
                v1b[2*dd+1] = __builtin_bit_cast(float, wd & 0xffff0000u);
            }
            #pragma unroll
            for (int ii = 0; ii < 6; ++ii)
                #pragma unroll
                for (int dd = 0; dd < 6; ++dd) {
                    acc[ii][dd] += paj[ii]  * v0a[dd] + pbj[ii]  * v1a[dd]
                                 + pajn[ii] * v0b[dd] + pbjn[ii] * v1b[dd];
                }
        }
        __syncthreads();
        #pragma unroll
        for (int ii = 0; ii < 6; ++ii) {
            #pragma unroll
            for (int dd = 0; dd < 6; ++dd) {
                int d = dbase + dd;
                if (d < dw)
                    Mout[((size_t)((i0 + ii) * Bdim + b)) * GDdim + d0 + d] = acc[ii][dd];
            }
        }
    }
}

// ---------------------------------------------------------------------------
// Per-step LSTM, SINGLE-bf16 h and W (round 21 verified). Round-13 schedule:
// double-buffered LDS, one barrier per k-chunk; T14 prefetch; Hlstm-slice
// ping-pong. 2 MFMA/chunk. Tile 32b x 64g, grid (8,38).
// ---------------------------------------------------------------------------
__global__ __launch_bounds__(256) void lstm_bf16(
    const u16* __restrict__ hH,
    const float* __restrict__ cin,
    const u16* __restrict__ WH,                  // (2432 x 608), pads zero
    const float* __restrict__ zt,
    u16* __restrict__ hHo,
    float* __restrict__ cout)
{
    __shared__ u16 As[2][4][256];
    __shared__ u16 Ws[2][4][512];
    __shared__ __align__(16) float gates[32][68];
    const int tid = threadIdx.x;
    const int bm = blockIdx.x * 32;
    const int bn = blockIdx.y * 64;
    const int wv = tid >> 6;
    const int lane = tid & 63;
    const int l15 = lane & 15;
    const int kseg = lane >> 4;
    const float4 fz = make_float4(0.f, 0.f, 0.f, 0.f);

    // --- T14: issue cell-phase loads NOW; consumed after the k-loop ---
    const int prow0 = tid >> 4,        pui0 = tid & 15;
    const int prow1 = (tid + 256) >> 4, pui1 = tid & 15;     // cell1 = tid+256
    const int pn0 = bn + pui0 * 4,  pn1 = bn + pui1 * 4;
    const int pu0 = pn0 >> 2,       pu1 = pn1 >> 2;
    const bool ok0 = (pu0 < LHdim), ok1 = (pu1 < LHdim);
    const int bb0 = bm + prow0,     bb1 = bm + prow1;
    float4 z0 = ok0 ? *(const float4*)(zt + (size_t)bb0 * (4 * LHdim) + pn0) : fz;
    float4 z1 = ok1 ? *(const float4*)(zt + (size_t)bb1 * (4 * LHdim) + pn1) : fz;
    float ci0 = ok0 ? cin[bb0 * LHdim + pu0] : 0.f;
    float ci1 = ok1 ? cin[bb1 * LHdim + pu1] : 0.f;

    // A staging: threads 0..127, one bf16x8 each (wave-uniform split)
    const int av = tid & 127;
    const int arow = av >> 2, akc = av & 3;
    const u16* asrc = hH + (size_t)(bm + arow) * 608 + akc * 8;
    const int aoff = akc * 256 + arow * 8;
    const bool doA = (tid < 128);
    // W staging: all 256 threads, one bf16x8 each
    const int wrow = tid >> 2, wkc = tid & 3;
    const u16* wsrc = WH + (size_t)(bn + wrow) * 608 + wkc * 8;
    const int woff2 = wrow * 8;

    f32x4 acc[2];
    acc[0] = (f32x4){0.f,0.f,0.f,0.f};
    acc[1] = (f32x4){0.f,0.f,0.f,0.f};

    // preload chunk 0 (upper threads load duplicate A addrs; store is guarded)
    bf16x8 ra = *(const bf16x8*)(asrc);
    bf16x8 rw = *(const bf16x8*)(wsrc);

    #pragma unroll
    for (int kc = 0; kc < 19; ++kc) {
        const int buf = kc & 1;
        if (doA) *(bf16x8*)(&As[buf][0][0] + aoff) = ra;
        *(bf16x8*)(&Ws[buf][wkc][woff2]) = rw;
        if (kc + 1 < 19) {                      // prefetch next chunk
            ra = *(const bf16x8*)(asrc + (kc + 1) * 32);
            rw = *(const bf16x8*)(wsrc + (kc + 1) * 32);
        }
        __syncthreads();                        // single barrier per chunk
        bf16x8 a0, a1, b;
        a0 = *(const bf16x8*)&As[buf][kseg][(l15) * 8];
        a1 = *(const bf16x8*)&As[buf][kseg][(16 + l15) * 8];
        b  = *(const bf16x8*)&Ws[buf][kseg][(wv * 16 + l15) * 8];
        acc[0] = __builtin_amdgcn_mfma_f32_16x16x32_bf16(a0, b, acc[0], 0, 0, 0);
        acc[1] = __builtin_amdgcn_mfma_f32_16x16x32_bf16(a1, b, acc[1], 0, 0, 0);
    }

    const int r4 = (lane >> 4) * 4;
    __syncthreads();
    #pragma unroll
    for (int i = 0; i < 2; ++i)
        #pragma unroll
        for (int rr = 0; rr < 4; ++rr)
            gates[i * 16 + r4 + rr][wv * 16 + l15] = acc[i][rr];
    __syncthreads();

    // fused cell: 2 cells per thread, using prefetched z/c
    if (ok0) {
        float4 g = *(const float4*)&gates[prow0][pui0 * 4];
        float gi = g.x + z0.x;
        float gf = g.y + z0.y;
        float gg = g.z + z0.z;
        float go = g.w + z0.w;
        float si = 1.f / (1.f + expf(-gi));
        float sf = 1.f / (1.f + expf(-gf));
        float so = 1.f / (1.f + expf(-go));
        float cn = sf * ci0 + si * tanhf(gg);
        float hn = so * tanhf(cn);
        cout[bb0 * LHdim + pu0] = cn;
        hHo[(size_t)bb0 * 608 + pu0] = f2bf(hn);
    }
    if (ok1) {
        float4 g = *(const float4*)&gates[prow1][pui1 * 4];
        float gi = g.x + z1.x;
        float gf = g.y + z1.y;
        float gg = g.z + z1.z;
        float go = g.w + z1.w;
        float si = 1.f / (1.f + expf(-gi));
        float sf = 1.f / (1.f + expf(-gf));
        float so = 1.f / (1.f + expf(-go));
        float cn = sf * ci1 + si * tanhf(gg);
        float hn = so * tanhf(cn);
        cout[bb1 * LHdim + pu1] = cn;
        hHo[(size_t)bb1 * 608 + pu1] = f2bf(hn);
    }
}

__global__ __launch_bounds__(256) void out_kernel(
    const float* __restrict__ x, int ldx, const float* __restrict__ ow,
    const float* __restrict__ ob, float* __restrict__ out)
{
    int r    = blockIdx.x * 4 + (threadIdx.x >> 6);
    int lane = threadIdx.x & 63;
    const float* xr = x + (size_t)r * ldx;
    float acc[NCdim];
    #pragma unroll
    for (int n = 0; n < NCdim; ++n) acc[n] = 0.f;
    for (int t = lane; t < HDdim; t += 64) {
        float xv = xr[t];
        #pragma unroll
        for (int n = 0; n < NCdim; ++n) acc[n] = fmaf(xv, ow[n * HDdim + t], acc[n]);
    }
    #pragma unroll
    for (int o = 32; o > 0; o >>= 1)
        #pragma unroll
        for (int n = 0; n < NCdim; ++n) acc[n] += __shfl_down(acc[n], o);
    if (lane == 0) {
        int b = r & 255, nn = r >> 8;
        #pragma unroll
        for (int n = 0; n < NCdim; ++n) out[((size_t)b * Ndim + nn) * NCdim + n] = acc[n] + ob[n];
    }
}

// ---------------------------------------------------------------------------
extern "C" void kernel_launch(void* const* d_in, const int* in_sizes, int n_in,
                              void* d_out, int out_size, void* d_ws, size_t ws_size,
                              hipStream_t stream)
{
    const float*  features  = (const float*)d_in[0];
    const int*    s_mask    = (const int*)  d_in[1];
    const float*  entro     = (const float*)d_in[2];
    const float*  alpha     = (const float*)d_in[3];
    const float*  threshold = (const float*)d_in[4];
    const float*  fc1_w     = (const float*)d_in[5];
    const float*  fc1_b     = (const float*)d_in[6];
    const float*  gat_w     = (const float*)d_in[7];
    const float*  gat_b     = (const float*)d_in[8];
    const float*  wr0       = (const float*)d_in[9];
    const float*  wr1       = (const float*)d_in[10];
    const float*  enhance_w = (const float*)d_in[11];
    const float*  enhance_b = (const float*)d_in[12];
    const float*  prelu_a   = (const float*)d_in[13];
    const float*  lstm_w_ih = (const float*)d_in[14];
    const float*  lstm_w_hh = (const float*)d_in[15];
    const float*  lstm_b_ih = (const float*)d_in[16];
    const float*  lstm_b_hh = (const float*)d_in[17];
    const float*  mlp_w0    = (const float*)d_in[18];
    const float*  mlp_b0    = (const float*)d_in[19];
    const float*  mlp_a0    = (const float*)d_in[20];
    const float*  mlp_w1    = (const float*)d_in[21];
    const float*  mlp_b1    = (const float*)d_in[22];
    const float*  mlp_a1    = (const float*)d_in[23];
    const float*  out_w     = (const float*)d_in[24];
    const float*  out_b     = (const float*)d_in[25];
    float* out = (float*)d_out;
    char* ws = (char*)d_ws;
    (void)gat_b;

    // ---- compacted workspace layout (bytes, 256-aligned) ----
    uint8_t* adj   = (uint8_t*)(ws + 0);               //  2,359,296
    float*   invn  = (float*)(ws + 2359296);           //     98,304
    float*   kbuf  = (float*)(ws + 2457600);           //     98,304
    float*   biasP = (float*)(ws + 2555904);           //      9,728
    float*   c0    = (float*)(ws + 2566144);           //    614,400
    float*   c1    = (float*)(ws + 3180544);           //    614,400
    u16*     WhhPH = (u16*)(ws + 3794944);             //  2,957,312 (2432 x 608)
    u16*     WihPH = (u16*)(ws + 6752256);             //  9,494,528 (2432 x 1952)
    u16*     EwH   = (u16*)(ws + 16246784);            //  2,097,152 (1024 x 1024)
    u16*     Fc1H  = (u16*)(ws + 18343936);            //    786,432 (384 x 1024)
    float*   Wr2f  = (float*)(ws + 19130368);          //  1,440,000 (2 x 600 x 300)
    u16*     Wr2H  = (u16*)(ws + 20570368);            //    819,200 (2 x 640 x 320)
    u16*     Wm0H  = (u16*)(ws + 21389568);            //    466,944 (384 x 608)
    u16*     Wm1H  = (u16*)(ws + 21856512);            //    245,760 (384 x 320)
    u16*     FfH   = (u16*)(ws + 22102272);            // 50,331,648 (ROWS x 1024)
    float*   Hcat  = (float*)(ws + 72433920);          // 88,473,600 (ROWS,900) n-major
    u16*     HsH   = (u16*)(ws + 160907520);           // 15,728,640 (ROWS x 320)
    // V (GAT, fp32 ROWSx600) aliases Hlstm (97 slices x 256 x 608 bf16 H-only)
    float*   V      = (float*)(ws + 176636160);        // 58,982,400
    u16*     HlstmH = (u16*)(ws + 176636160);          // 30,195,712 (97 slices)
    // MLP scratch aliases Hcat (dead after last Hcat split)
    u16*     x1H   = (u16*)Hcat;                       // 15,728,640 (ROWS x 320)
    float*   x2    = (float*)(ws + 72433920 + 31457280);    // 29,884,416 (ROWS x 304)

    // ---- tier selection for chunked seq/zin region ----
    const size_t fixedNeed = 235618560ull;
    const size_t perT = 3457024ull;                    // zin(2,457,600)+seqH(999,424)
    int T;
    if      (ws_size >= fixedNeed + 96ull * perT) T = 96;
    else if (ws_size >= fixedNeed + 48ull * perT) T = 48;
    else if (ws_size >= fixedNeed + 32ull * perT) T = 32;
    else if (ws_size >= fixedNeed + 16ull * perT) T = 16;
    else if (ws_size >= fixedNeed +  8ull * perT) T = 8;
    else return;                                       // visible failure, no OOB
    char* cr = ws + fixedNeed;
    float* zin  = (float*)cr;                                // (Mc,2400)
    u16*   seqH = (u16*)(cr + (size_t)T * 2457600);          // (Mc,1952)

    // 1) norms + adjacency
    norm_kernel<<<ROWS / 4, 256, 0, stream>>>(features, invn);
    simadj_kernel<<<Bdim, 256, 0, stream>>>(features, invn, entro, alpha, threshold, adj);

    // 2) weight/activation conversions (bf16 H only)
    split_rows8<<<dim3(2, ROWS / 4), 256, 0, stream>>>(            // features n-major full
        features, Edim, 255, Ndim, 8, 1, 0, FfH, Edim, Edim, Edim, ROWS);
    split_rows8<<<dim3(2, 96), 256, 0, stream>>>(                  // fc1_w (384x1024)
        fc1_w, Edim, IDP, Fc1H, Edim, Edim, Edim, HDdim);
    split_rows8<<<dim3(2, 256), 256, 0, stream>>>(                 // enhance_w
        enhance_w, Edim, IDP, EwH, Edim, Edim, Edim, Edim);
    split_rows8<<<dim3(4, 608), 256, 0, stream>>>(                 // Wih gate-interleaved
        lstm_w_ih, Edim + GDdim, 3, LHdim, 2, 1, 0, WihPH, 1952, 1952, 1924, 2400);
    split_rows8<<<dim3(2, 608), 256, 0, stream>>>(                 // Whh gate-interleaved
        lstm_w_hh, LHdim, 3, LHdim, 2, 1, 0, WhhPH, 608, 608, LHdim, 2400);
    split_rows8<<<dim3(2, 96), 256, 0, stream>>>(                  // mlp_w0 (384x608)
        mlp_w0, LHdim, IDP, Wm0H, 608, 608, LHdim, HDdim);
    split_rows8<<<dim3(1, 96), 256, 0, stream>>>(                  // mlp_w1 (384x320)
        mlp_w1, HDdim, IDP, Wm1H, 320, 320, HDdim, HDdim);
    wr_cat<<<dim3(2, 2 * Ldim * HDdim), 256, 0, stream>>>(wr0, wr1, Wr2f);
    for (int l = 0; l < Ldim; ++l)
        split_rows8<<<dim3(1, 160), 256, 0, stream>>>(             // Wr2 (640x320 per layer)
            Wr2f + (size_t)l * 2 * HDdim * HDdim, HDdim, IDP,
            Wr2H + (size_t)l * 640 * 320, 320, 320, HDdim, 2 * HDdim);
    bias_perm<<<10, 256, 0, stream>>>(lstm_b_ih, lstm_b_hh, biasP);
    zero_range<<<1200, 256, 0, stream>>>(c0, 307200);              // c0, c1

    // 3) H0 = prelu(features @ fc1_w^T + fc1_b) -> Hcat[:, 0:300] (bf16 MFMA)
    gemm_bf16<0,1><<<dim3(ROWS/128, 3), 256, 0, stream>>>(
        FfH, Edim, Fc1H, Edim,
        Hcat, nullptr, GDdim, ROWS, HDdim, Edim, fc1_b, prelu_a);

    // 4) GAT layers (bf16 MFMA V projection, fused softmax+aggregation)
    for (int l = 0; l < Ldim; ++l) {
        const float* Hsrc = Hcat + l * HDdim;
        k_kernel<<<ROWS / 4, 256, 0, stream>>>(Hsrc, gat_w + l * 2 * HDdim + HDdim, kbuf);
        split_rows8<<<dim3(1, ROWS / 4), 256, 0, stream>>>(        // Hsrc -> bf16 (K=320)
            Hsrc, GDdim, IDP, HsH, 320, 320, HDdim, ROWS);
        gemm_bf16<0,0><<<dim3(ROWS/128, 5), 256, 0, stream>>>(
            HsH, 320, Wr2H + (size_t)l * 640 * 320, 320,
            V, nullptr, 2 * HDdim, ROWS, 2 * HDdim, 320, nullptr, nullptr);
        gat_fused<<<dim3(Bdim, 2), 256, 0, stream>>>(
            kbuf, adj, s_mask, V, Hcat + (l + 1) * HDdim);
    }

    // 5) zero Hlstm H region (pads + slice 0 = h_0; aliased V until now)
    zero_range<<<29489, 256, 0, stream>>>((float*)HlstmH, 7548928);

    // 6) chunked: enhance (bf16) -> Hcat split -> zin (bf16) -> LSTM (bf16)
    int cur = 0;
    float* cb_[2] = {c0, c1};
    for (int t0 = 0; t0 < Ndim; t0 += T) {
        int Mc = T * Bdim;
        gemm_bf16<1,1><<<dim3(Mc/128, 8), 256, 0, stream>>>(       // bf16 enhance -> seqH
            FfH + (size_t)t0 * Bdim * Edim, Edim, EwH, Edim,
            nullptr, seqH, 1952, Mc, Edim, Edim, enhance_b, prelu_a);
        split_rows8<<<dim3(2, Mc / 4), 256, 0, stream>>>(
            Hcat, GDdim, 0x7FFFFFFF, 1, 30, 0, t0 * Bdim,
            seqH + 1024, 1952, 928, GDdim, Mc);
        gemm_bf16<0,0><<<dim3(Mc/128, 19), 256, 0, stream>>>(      // bf16 zin
            seqH, 1952, WihPH, 1952,
            zin, nullptr, 4 * LHdim, Mc, 4 * LHdim, 1952, biasP, nullptr);
        for (int tl = 0; tl < T; ++tl) {
            const int g = t0 + tl;                    // global step, 0-based
            lstm_bf16<<<dim3(8, 38), 256, 0, stream>>>(
                HlstmH + (size_t)g * HSLICE, cb_[cur], WhhPH,
                zin + (size_t)tl * Bdim * 4 * LHdim,
                HlstmH + (size_t)(g + 1) * HSLICE, cb_[cur ^ 1]);
            cur ^= 1;
        }
    }

    // 7) MLP head (bf16 MFMA, A = Hlstm slices 1..96) + output
    zero_range<<<15360, 256, 0, stream>>>((float*)x1H, 3932160);   // x1H pads must be 0
    gemm_bf16<1,1><<<dim3(ROWS/128, 3), 256, 0, stream>>>(
        HlstmH + HSLICE, 608, Wm0H, 608,
        nullptr, x1H, 320, ROWS, HDdim, 608, mlp_b0, mlp_a0);
    gemm_bf16<0,1><<<dim3(ROWS/128, 3), 256, 0, stream>>>(
        x1H, 320, Wm1H, 320,
        x2, nullptr, 304, ROWS, HDdim, 320, mlp_b1, mlp_a1);
    out_kernel<<<ROWS / 4, 256, 0, stream>>>(x2, 304, out_w, out_b, out);
}

// Round 24
// 2436.812 us; speedup vs baseline: 1.9031x; 1.0783x over previous
//
#include <hip/hip_runtime.h>
#include <cstdint>
#include <cstddef>

#define Bdim 256
#define Ndim 96
#define Edim 1024
#define HDdim 300
#define Ldim 2
#define LHdim 600
#define NCdim 7
#define GDdim 900              // HD*(L+1)
#define ROWS (Bdim*Ndim)       // 24576
#define HSLICE 155648          // 256*608 elements per Hlstm time-slice

typedef unsigned short u16;
typedef unsigned int   u32;
typedef float f32x4 __attribute__((ext_vector_type(4)));
typedef short bf16x8 __attribute__((ext_vector_type(8)));
typedef unsigned short u16x4 __attribute__((ext_vector_type(4)));

// Identity row-perm constants
#define IDP 0x7FFFFFFF, 1, 30, 0, 0

__device__ inline u16 f2bf(float x) {
    u32 u = __builtin_bit_cast(u32, x);
    u32 r = (u + 0x7fffu + ((u >> 16) & 1u)) >> 16;   // RNE
    return (u16)r;
}
__device__ inline float bf2f(u16 h) {
    u32 u = ((u32)h) << 16;
    return __builtin_bit_cast(float, u);
}

// ---------------------------------------------------------------------------
// Pure single-bf16 MFMA GEMM. Round-24: round-13 LSTM schedule applied —
// double-buffered LDS (2x16 KB), reg prefetch of next k-chunk, ONE barrier
// per chunk (was 2 + loads on the critical path -> latency-bound at 230 TF).
// Staging guard removed: every call site has M mult 128, W pad rows
// allocated+zeroed, K pad cols zeroed.
// C = act(A·W^T + bias). K mult of 32; lda/ldw mult 8.
// OUT: 0 -> fp32 C; 1 -> bf16 Ch only. ACT: 1 -> prelu(aptr).
// ---------------------------------------------------------------------------
template<int OUT, int ACT>
__global__ __launch_bounds__(256) void gemm_bf16(
    const u16* __restrict__ Ah, int lda,
    const u16* __restrict__ Wh, int ldw,
    float* __restrict__ C, u16* __restrict__ Ch, int ldc,
    int M, int Nd, int K,
    const float* __restrict__ bias, const float* __restrict__ aptr)
{
    __shared__ u16 At[2][4][1024];
    __shared__ u16 Wt[2][4][1024];
    const int tid  = threadIdx.x;
    const int ny  = gridDim.y;
    const int nwg = gridDim.x * ny;
    const int lin = blockIdx.y * gridDim.x + blockIdx.x;
    const int q = nwg >> 3, r8 = nwg & 7;
    const int xcd = lin & 7, off = lin >> 3;
    const int swz = (xcd < r8) ? xcd * (q + 1) + off
                               : r8 * (q + 1) + (xcd - r8) * q + off;
    const int bm   = (swz / ny) * 128;
    const int bn   = (swz % ny) * 128;
    const int wv   = tid >> 6;
    const int lane = tid & 63;
    const int wr   = (wv >> 1) * 64;
    const int wc   = (wv & 1) * 64;
    const int l15  = lane & 15;
    const int kseg = lane >> 4;

    f32x4 acc[4][4];
    #pragma unroll
    for (int i = 0; i < 4; ++i)
        #pragma unroll
        for (int j = 0; j < 4; ++j) acc[i][j] = (f32x4){0.f,0.f,0.f,0.f};

    const int srow = tid & 127;
    const bool isA = (tid < 128);
    const int gr   = isA ? (bm + srow) : (bn + srow);
    const u16* pbase = (isA ? Ah : Wh) + (size_t)gr * (isA ? lda : ldw);
    u16* dst = isA ? &At[0][0][0] : &Wt[0][0][0];
    const int soff = srow * 8;

    // preload chunk 0
    bf16x8 rv[4];
    #pragma unroll
    for (int s = 0; s < 4; ++s) rv[s] = *(const bf16x8*)(pbase + s * 8);

    const int nk = K >> 5;
    for (int kc = 0; kc < nk; ++kc) {
        const int bufo = (kc & 1) << 12;              // buffer stride 4096 u16
        #pragma unroll
        for (int s = 0; s < 4; ++s)
            *(bf16x8*)(dst + bufo + s * 1024 + soff) = rv[s];
        if (kc + 1 < nk) {                            // prefetch next chunk
            const u16* p = pbase + (kc + 1) * 32;
            #pragma unroll
            for (int s = 0; s < 4; ++s) rv[s] = *(const bf16x8*)(p + s * 8);
        }
        __syncthreads();                              // single barrier per chunk
        const u16* Ab = &At[0][0][0] + bufo + kseg * 1024;
        const u16* Wb = &Wt[0][0][0] + bufo + kseg * 1024;
        bf16x8 a[4], b[4];
        #pragma unroll
        for (int f = 0; f < 4; ++f) {
            a[f] = *(const bf16x8*)(Ab + (wr + f * 16 + l15) * 8);
            b[f] = *(const bf16x8*)(Wb + (wc + f * 16 + l15) * 8);
        }
        #pragma unroll
        for (int i = 0; i < 4; ++i)
            #pragma unroll
            for (int j = 0; j < 4; ++j)
                acc[i][j] = __builtin_amdgcn_mfma_f32_16x16x32_bf16(a[i], b[j], acc[i][j], 0, 0, 0);
    }

    const float av = (ACT == 1) ? *aptr : 0.f;
    const int r4 = (lane >> 4) * 4;
    #pragma unroll
    for (int j = 0; j < 4; ++j) {
        int col = bn + wc + j * 16 + l15;
        if (col >= Nd) continue;
        float bv = bias ? bias[col] : 0.f;
        #pragma unroll
        for (int i = 0; i < 4; ++i) {
            #pragma unroll
            for (int rr = 0; rr < 4; ++rr) {
                int row = bm + wr + i * 16 + r4 + rr;
                if (row >= M) continue;
                float v = acc[i][j][rr] + bv;
                if (ACT == 1) v = (v >= 0.f) ? v : av * v;
                if (OUT == 0) {
                    C[(size_t)row * ldc + col] = v;
                } else {
                    Ch[(size_t)row * ldc + col] = f2bf(v);
                }
            }
        }
    }
}

// ---------------------------------------------------------------------------
// fp32 -> bf16 (H only). 4 rows/block, 8 cols/thread.
// ---------------------------------------------------------------------------
__global__ __launch_bounds__(256) void split_rows8(
    const float* __restrict__ src, int srcld,
    int pmask, int pmul1, int pshift, int pmul2, int padd,
    u16* __restrict__ dstH, int dstld,
    int wcols, int validK, int validRows)
{
    const int r = blockIdx.y * 4 + (threadIdx.x >> 6);
    const int c = (blockIdx.x * 64 + (threadIdx.x & 63)) * 8;
    if (c >= wcols) return;
    const int sr = (r & pmask) * pmul1 + (r >> pshift) * pmul2 + padd;
    const float* s = src + (size_t)sr * srcld;
    const bool rok = (r < validRows);
    float v[8];
    if (rok && c + 8 <= validK) {
        *(float4*)&v[0] = *(const float4*)(s + c);
        *(float4*)&v[4] = *(const float4*)(s + c + 4);
    } else {
        #pragma unroll
        for (int u = 0; u < 8; ++u) v[u] = (rok && c + u < validK) ? s[c + u] : 0.f;
    }
    bf16x8 H8;
    #pragma unroll
    for (int u = 0; u < 8; ++u) H8[u] = (short)f2bf(v[u]);
    *(bf16x8*)(dstH + (size_t)r * dstld + c) = H8;
}

// biasP[n'] = b_ih[orig]+b_hh[orig], orig = (n'&3)*600+(n'>>2)
__global__ __launch_bounds__(256) void bias_perm(
    const float* __restrict__ bih, const float* __restrict__ bhh, float* __restrict__ dst)
{
    int n = blockIdx.x * 256 + threadIdx.x;
    if (n >= 4 * LHdim) return;
    int o = (n & 3) * LHdim + (n >> 2);
    dst[n] = bih[o] + bhh[o];
}

// Wr2f[l][r][c]: r<300 -> wr0[l][r][c], else wr1[l][r-300][c]
__global__ __launch_bounds__(256) void wr_cat(
    const float* __restrict__ wr0, const float* __restrict__ wr1, float* __restrict__ dst)
{
    int c = blockIdx.x * 256 + threadIdx.x;
    if (c >= HDdim) return;
    int lr = blockIdx.y;
    int l = lr / (2 * HDdim), r = lr % (2 * HDdim);
    const float* src = (r < HDdim)
        ? wr0 + ((size_t)l * HDdim + r) * HDdim
        : wr1 + ((size_t)l * HDdim + (r - HDdim)) * HDdim;
    dst[(size_t)lr * HDdim + c] = src[c];
}

__global__ __launch_bounds__(256) void zero_range(float* __restrict__ p, int n)
{
    int i = blockIdx.x * 256 + threadIdx.x;
    if (i < n) p[i] = 0.f;
}

// ---------------------------------------------------------------------------
__global__ __launch_bounds__(256) void norm_kernel(const float* __restrict__ f, float* __restrict__ invn)
{
    int row  = blockIdx.x * 4 + (threadIdx.x >> 6);
    int lane = threadIdx.x & 63;
    const float* fr = f + (size_t)row * Edim;
    float ss = 0.f;
    for (int t = lane; t < Edim; t += 64) { float v = fr[t]; ss = fmaf(v, v, ss); }
    #pragma unroll
    for (int o = 32; o > 0; o >>= 1) ss += __shfl_down(ss, o);
    if (lane == 0) invn[row] = 1.f / (sqrtf(ss) + 1e-8f);
}

__global__ __launch_bounds__(256) void simadj_kernel(
    const float* __restrict__ f, const float* __restrict__ invn,
    const float* __restrict__ entro, const float* __restrict__ alphap,
    const float* __restrict__ thrp, uint8_t* __restrict__ adj)
{
    int b = blockIdx.x;
    __shared__ float S[16][100];
    int tid = threadIdx.x;
    int i0 = (tid >> 4) * 6, j0 = (tid & 15) * 6;
    float acc[6][6];
    #pragma unroll
    for (int i = 0; i < 6; ++i)
        #pragma unroll
        for (int j = 0; j < 6; ++j) acc[i][j] = 0.f;
    const float* fb = f + (size_t)b * Ndim * Edim;

    for (int k0 = 0; k0 < Edim; k0 += 16) {
        __syncthreads();
        #pragma unroll
        for (int r = 0; r < 6; ++r) {
            int n = (tid >> 4) + r * 16;
            S[tid & 15][n] = fb[(size_t)n * Edim + k0 + (tid & 15)];
        }
        __syncthreads();
        #pragma unroll
        for (int kk = 0; kk < 16; ++kk) {
            float a[6], bb[6];
            #pragma unroll
            for (int u = 0; u < 6; ++u) a[u] = S[kk][i0 + u];
            #pragma unroll
            for (int u = 0; u < 6; ++u) bb[u] = S[kk][j0 + u];
            #pragma unroll
            for (int i = 0; i < 6; ++i)
                #pragma unroll
                for (int j = 0; j < 6; ++j)
                    acc[i][j] = fmaf(a[i], bb[j], acc[i][j]);
        }
    }

    float alpha = *alphap, thr = *thrp;
    float onem = 1.f - alpha;
    #pragma unroll
    for (int i = 0; i < 6; ++i) {
        int ii = i0 + i;
        float inv_i = invn[b * Ndim + ii];
        #pragma unroll
        for (int j = 0; j < 6; ++j) {
            int jj = j0 + j;
            float simv = acc[i][j] * inv_i * invn[b * Ndim + jj];
            float comb = alpha * entro[b * Ndim + jj] + onem * simv;
            adj[((size_t)b * Ndim + ii) * Ndim + jj] = (comb > thr) ? 1 : 0;
        }
    }
}

// k[r] = H[r,:300] . wk   (q cancels in the adjacency softmax; not computed)
__global__ __launch_bounds__(256) void k_kernel(
    const float* __restrict__ Hsrc, const float* __restrict__ wk,
    float* __restrict__ k)
{
    int row  = blockIdx.x * 4 + (threadIdx.x >> 6);
    int lane = threadIdx.x & 63;
    const float* h = Hsrc + (size_t)row * GDdim;
    float sk = 0.f;
    for (int t = lane; t < HDdim; t += 64) sk = fmaf(h[t], wk[t], sk);
    #pragma unroll
    for (int o = 32; o > 0; o >>= 1) sk += __shfl_down(sk, o);
    if (lane == 0) k[row] = sk;
}

// ---------------------------------------------------------------------------
// Fused GAT attention (q, gat_b cancel in softmax). bf16 LDS (77 KB).
// grid (B, 2): block half handles d-passes {2*half, 2*half+1} -> 512 blocks,
// 2 blocks/CU co-resident (round-22 fix: grid was the occupancy limiter).
// V combined: cols 0..299 = V0, 300..599 = V1, row stride 600 (n-major rows).
// ---------------------------------------------------------------------------
__global__ __launch_bounds__(256) void gat_fused(
    const float* __restrict__ kbuf, const uint8_t* __restrict__ adj,
    const int* __restrict__ smask,
    const float* __restrict__ V,
    float* __restrict__ Mout)
{
    __shared__ u16 P0[96][100];
    __shared__ u16 P1[96][100];
    __shared__ u16 Vs0[96][96];
    __shared__ u16 Vs1[96][96];
    __shared__ float ek[96];
    __shared__ float rden[96];
    __shared__ float red[256];
    const int b = blockIdx.x;
    const int half = blockIdx.y;
    const int tid = threadIdx.x;

    float kj = (tid < Ndim) ? kbuf[tid * Bdim + b] : -1e30f;
    red[tid] = kj;
    __syncthreads();
    #pragma unroll
    for (int s = 128; s > 0; s >>= 1) {
        if (tid < s) red[tid] = fmaxf(red[tid], red[tid + s]);
        __syncthreads();
    }
    float kmax = red[0];
    if (tid < Ndim) ek[tid] = expf(kj - kmax);
    __syncthreads();
    if (tid < Ndim) {
        const uint8_t* ar = adj + ((size_t)b * Ndim + tid) * Ndim;
        float s = 0.f;
        for (int j = 0; j < Ndim; ++j) if (ar[j]) s += ek[j];
        rden[tid] = 1.f / s;   // diagonal always allowed -> s > 0
    }
    __syncthreads();
    for (int idx = tid; idx < Ndim * Ndim; idx += 256) {
        int i = idx / Ndim, j = idx - i * Ndim;
        float a = adj[((size_t)b * Ndim + i) * Ndim + j] ? ek[j] * rden[i] : 0.f;
        int s = smask[((size_t)b * Ndim + i) * Ndim + j];
        P0[i][j] = s ? f2bf(a) : (u16)0;
        P1[i][j] = s ? (u16)0 : f2bf(a);
    }
    __syncthreads();

    const int ti = tid >> 4, td = tid & 15;
    const int i0 = ti * 6, dbase = td * 6;
    for (int p = 2 * half; p < 2 * half + 2; ++p) {
        const int d0 = p * 96;
        const int dw = (p == 3) ? (HDdim - 288) : 96;
        for (int idx = tid; idx < 96 * 24; idx += 256) {
            int j = idx / 24, q4 = (idx - j * 24) * 4;
            if (q4 < dw) {
                size_t g = ((size_t)(j * Bdim + b)) * (2 * HDdim) + d0 + q4;
                float4 a = *(const float4*)(V + g);
                float4 c = *(const float4*)(V + g + HDdim);
                u16x4 ua = { f2bf(a.x), f2bf(a.y), f2bf(a.z), f2bf(a.w) };
                u16x4 uc = { f2bf(c.x), f2bf(c.y), f2bf(c.z), f2bf(c.w) };
                *(u16x4*)&Vs0[j][q4] = ua;
                *(u16x4*)&Vs1[j][q4] = uc;
            }
        }
        __syncthreads();
        float acc[6][6];
        #pragma unroll
        for (int ii = 0; ii < 6; ++ii)
            #pragma unroll
            for (int dd = 0; dd < 6; ++dd) acc[ii][dd] = 0.f;
        for (int j = 0; j < Ndim; j += 2) {
            float paj[6], pajn[6], pbj[6], pbjn[6];
            #pragma unroll
            for (int ii = 0; ii < 6; ++ii) {
                u32 w0 = *(const u32*)&P0[i0 + ii][j];
                u32 w1 = *(const u32*)&P1[i0 + ii][j];
                paj[ii]  = __builtin_bit_cast(float, w0 << 16);
                pajn[ii] = __builtin_bit_cast(float, w0 & 0xffff0000u);
                pbj[ii]  = __builtin_bit_cast(float, w1 << 16);
                pbjn[ii] = __builtin_bit_cast(float, w1 & 0xffff0000u);
            }
            float v0a[6], v0b[6], v1a[6], v1b[6];
            #pragma unroll
            for (int dd = 0; dd < 3; ++dd) {
                u32 wa = *(const u32*)&Vs0[j][dbase + 2 * dd];
                u32 wb = *(const u32*)&Vs0[j + 1][dbase + 2 * dd];
                u32 wc2 = *(const u32*)&Vs1[j][dbase + 2 * dd];
                u32 wd = *(const u32*)&Vs1[j + 1][dbase + 2 * dd];
                v0a[2*dd]   = __builtin_bit_cast(float, wa << 16);
                v0a[2*dd+1] = __builtin_bit_cast(float, wa & 0xffff0000u);
                v0b[2*dd]   = __builtin_bit_cast(float, wb << 16);
                v0b[2*dd+1] = __builtin_bit_cast(float, wb & 0xffff0000u);
                v1a[2*dd]   = __builtin_bit_cast(float, wc2 << 16);
                v1a[2*dd+1] = __builtin_bit_cast(float, wc2 & 0xffff0000u);
                v1b[2*dd]   = __builtin_bit_cast(float, wd << 16);
                v1b[2*dd+1] = __builtin_bit_cast(float, wd & 0xffff0000u);
            }
            #pragma unroll
            for (int ii = 0; ii < 6; ++ii)
                #pragma unroll
                for (int dd = 0; dd < 6; ++dd) {
                    acc[ii][dd] += paj[ii]  * v0a[dd] + pbj[ii]  * v1a[dd]
                                 + pajn[ii] * v0b[dd] + pbjn[ii] * v1b[dd];
                }
        }
        __syncthreads();
        #pragma unroll
        for (int ii = 0; ii < 6; ++ii) {
            #pragma unroll
            for (int dd = 0; dd < 6; ++dd) {
                int d = dbase + dd;
                if (d < dw)
                    Mout[((size_t)((i0 + ii) * Bdim + b)) * GDdim + d0 + d] = acc[ii][dd];
            }
        }
    }
}

// ---------------------------------------------------------------------------
// Per-step LSTM, SINGLE-bf16 h and W (round 21 verified). Round-13 schedule:
// double-buffered LDS, one barrier per k-chunk; T14 prefetch; Hlstm-slice
// ping-pong. 2 MFMA/chunk. Tile 32b x 64g, grid (8,38).
// ---------------------------------------------------------------------------
__global__ __launch_bounds__(256) void lstm_bf16(
    const u16* __restrict__ hH,
    const float* __restrict__ cin,
    const u16* __restrict__ WH,                  // (2432 x 608), pads zero
    const float* __restrict__ zt,
    u16* __restrict__ hHo,
    float* __restrict__ cout)
{
    __shared__ u16 As[2][4][256];
    __shared__ u16 Ws[2][4][512];
    __shared__ __align__(16) float gates[32][68];
    const int tid = threadIdx.x;
    const int bm = blockIdx.x * 32;
    const int bn = blockIdx.y * 64;
    const int wv = tid >> 6;
    const int lane = tid & 63;
    const int l15 = lane & 15;
    const int kseg = lane >> 4;
    const float4 fz = make_float4(0.f, 0.f, 0.f, 0.f);

    // --- T14: issue cell-phase loads NOW; consumed after the k-loop ---
    const int prow0 = tid >> 4,        pui0 = tid & 15;
    const int prow1 = (tid + 256) >> 4, pui1 = tid & 15;     // cell1 = tid+256
    const int pn0 = bn + pui0 * 4,  pn1 = bn + pui1 * 4;
    const int pu0 = pn0 >> 2,       pu1 = pn1 >> 2;
    const bool ok0 = (pu0 < LHdim), ok1 = (pu1 < LHdim);
    const int bb0 = bm + prow0,     bb1 = bm + prow1;
    float4 z0 = ok0 ? *(const float4*)(zt + (size_t)bb0 * (4 * LHdim) + pn0) : fz;
    float4 z1 = ok1 ? *(const float4*)(zt + (size_t)bb1 * (4 * LHdim) + pn1) : fz;
    float ci0 = ok0 ? cin[bb0 * LHdim + pu0] : 0.f;
    float ci1 = ok1 ? cin[bb1 * LHdim + pu1] : 0.f;

    // A staging: threads 0..127, one bf16x8 each (wave-uniform split)
    const int av = tid & 127;
    const int arow = av >> 2, akc = av & 3;
    const u16* asrc = hH + (size_t)(bm + arow) * 608 + akc * 8;
    const int aoff = akc * 256 + arow * 8;
    const bool doA = (tid < 128);
    // W staging: all 256 threads, one bf16x8 each
    const int wrow = tid >> 2, wkc = tid & 3;
    const u16* wsrc = WH + (size_t)(bn + wrow) * 608 + wkc * 8;
    const int woff2 = wrow * 8;

    f32x4 acc[2];
    acc[0] = (f32x4){0.f,0.f,0.f,0.f};
    acc[1] = (f32x4){0.f,0.f,0.f,0.f};

    // preload chunk 0 (upper threads load duplicate A addrs; store is guarded)
    bf16x8 ra = *(const bf16x8*)(asrc);
    bf16x8 rw = *(const bf16x8*)(wsrc);

    #pragma unroll
    for (int kc = 0; kc < 19; ++kc) {
        const int buf = kc & 1;
        if (doA) *(bf16x8*)(&As[buf][0][0] + aoff) = ra;
        *(bf16x8*)(&Ws[buf][wkc][woff2]) = rw;
        if (kc + 1 < 19) {                      // prefetch next chunk
            ra = *(const bf16x8*)(asrc + (kc + 1) * 32);
            rw = *(const bf16x8*)(wsrc + (kc + 1) * 32);
        }
        __syncthreads();                        // single barrier per chunk
        bf16x8 a0, a1, b;
        a0 = *(const bf16x8*)&As[buf][kseg][(l15) * 8];
        a1 = *(const bf16x8*)&As[buf][kseg][(16 + l15) * 8];
        b  = *(const bf16x8*)&Ws[buf][kseg][(wv * 16 + l15) * 8];
        acc[0] = __builtin_amdgcn_mfma_f32_16x16x32_bf16(a0, b, acc[0], 0, 0, 0);
        acc[1] = __builtin_amdgcn_mfma_f32_16x16x32_bf16(a1, b, acc[1], 0, 0, 0);
    }

    const int r4 = (lane >> 4) * 4;
    __syncthreads();
    #pragma unroll
    for (int i = 0; i < 2; ++i)
        #pragma unroll
        for (int rr = 0; rr < 4; ++rr)
            gates[i * 16 + r4 + rr][wv * 16 + l15] = acc[i][rr];
    __syncthreads();

    // fused cell: 2 cells per thread, using prefetched z/c
    if (ok0) {
        float4 g = *(const float4*)&gates[prow0][pui0 * 4];
        float gi = g.x + z0.x;
        float gf = g.y + z0.y;
        float gg = g.z + z0.z;
        float go = g.w + z0.w;
        float si = 1.f / (1.f + expf(-gi));
        float sf = 1.f / (1.f + expf(-gf));
        float so = 1.f / (1.f + expf(-go));
        float cn = sf * ci0 + si * tanhf(gg);
        float hn = so * tanhf(cn);
        cout[bb0 * LHdim + pu0] = cn;
        hHo[(size_t)bb0 * 608 + pu0] = f2bf(hn);
    }
    if (ok1) {
        float4 g = *(const float4*)&gates[prow1][pui1 * 4];
        float gi = g.x + z1.x;
        float gf = g.y + z1.y;
        float gg = g.z + z1.z;
        float go = g.w + z1.w;
        float si = 1.f / (1.f + expf(-gi));
        float sf = 1.f / (1.f + expf(-gf));
        float so = 1.f / (1.f + expf(-go));
        float cn = sf * ci1 + si * tanhf(gg);
        float hn = so * tanhf(cn);
        cout[bb1 * LHdim + pu1] = cn;
        hHo[(size_t)bb1 * 608 + pu1] = f2bf(hn);
    }
}

__global__ __launch_bounds__(256) void out_kernel(
    const float* __restrict__ x, int ldx, const float* __restrict__ ow,
    const float* __restrict__ ob, float* __restrict__ out)
{
    int r    = blockIdx.x * 4 + (threadIdx.x >> 6);
    int lane = threadIdx.x & 63;
    const float* xr = x + (size_t)r * ldx;
    float acc[NCdim];
    #pragma unroll
    for (int n = 0; n < NCdim; ++n) acc[n] = 0.f;
    for (int t = lane; t < HDdim; t += 64) {
        float xv = xr[t];
        #pragma unroll
        for (int n = 0; n < NCdim; ++n) acc[n] = fmaf(xv, ow[n * HDdim + t], acc[n]);
    }
    #pragma unroll
    for (int o = 32; o > 0; o >>= 1)
        #pragma unroll
        for (int n = 0; n < NCdim; ++n) acc[n] += __shfl_down(acc[n], o);
    if (lane == 0) {
        int b = r & 255, nn = r >> 8;
        #pragma unroll
        for (int n = 0; n < NCdim; ++n) out[((size_t)b * Ndim + nn) * NCdim + n] = acc[n] + ob[n];
    }
}

// ---------------------------------------------------------------------------
extern "C" void kernel_launch(void* const* d_in, const int* in_sizes, int n_in,
                              void* d_out, int out_size, void* d_ws, size_t ws_size,
                              hipStream_t stream)
{
    const float*  features  = (const float*)d_in[0];
    const int*    s_mask    = (const int*)  d_in[1];
    const float*  entro     = (const float*)d_in[2];
    const float*  alpha     = (const float*)d_in[3];
    const float*  threshold = (const float*)d_in[4];
    const float*  fc1_w     = (const float*)d_in[5];
    const float*  fc1_b     = (const float*)d_in[6];
    const float*  gat_w     = (const float*)d_in[7];
    const float*  gat_b     = (const float*)d_in[8];
    const float*  wr0       = (const float*)d_in[9];
    const float*  wr1       = (const float*)d_in[10];
    const float*  enhance_w = (const float*)d_in[11];
    const float*  enhance_b = (const float*)d_in[12];
    const float*  prelu_a   = (const float*)d_in[13];
    const float*  lstm_w_ih = (const float*)d_in[14];
    const float*  lstm_w_hh = (const float*)d_in[15];
    const float*  lstm_b_ih = (const float*)d_in[16];
    const float*  lstm_b_hh = (const float*)d_in[17];
    const float*  mlp_w0    = (const float*)d_in[18];
    const float*  mlp_b0    = (const float*)d_in[19];
    const float*  mlp_a0    = (const float*)d_in[20];
    const float*  mlp_w1    = (const float*)d_in[21];
    const float*  mlp_b1    = (const float*)d_in[22];
    const float*  mlp_a1    = (const float*)d_in[23];
    const float*  out_w     = (const float*)d_in[24];
    const float*  out_b     = (const float*)d_in[25];
    float* out = (float*)d_out;
    char* ws = (char*)d_ws;
    (void)gat_b;

    // ---- compacted workspace layout (bytes, 256-aligned) ----
    uint8_t* adj   = (uint8_t*)(ws + 0);               //  2,359,296
    float*   invn  = (float*)(ws + 2359296);           //     98,304
    float*   kbuf  = (float*)(ws + 2457600);           //     98,304
    float*   biasP = (float*)(ws + 2555904);           //      9,728
    float*   c0    = (float*)(ws + 2566144);           //    614,400
    float*   c1    = (float*)(ws + 3180544);           //    614,400
    u16*     WhhPH = (u16*)(ws + 3794944);             //  2,957,312 (2432 x 608)
    u16*     WihPH = (u16*)(ws + 6752256);             //  9,494,528 (2432 x 1952)
    u16*     EwH   = (u16*)(ws + 16246784);            //  2,097,152 (1024 x 1024)
    u16*     Fc1H  = (u16*)(ws + 18343936);            //    786,432 (384 x 1024)
    float*   Wr2f  = (float*)(ws + 19130368);          //  1,440,000 (2 x 600 x 300)
    u16*     Wr2H  = (u16*)(ws + 20570368);            //    819,200 (2 x 640 x 320)
    u16*     Wm0H  = (u16*)(ws + 21389568);            //    466,944 (384 x 608)
    u16*     Wm1H  = (u16*)(ws + 21856512);            //    245,760 (384 x 320)
    u16*     FfH   = (u16*)(ws + 22102272);            // 50,331,648 (ROWS x 1024)
    float*   Hcat  = (float*)(ws + 72433920);          // 88,473,600 (ROWS,900) n-major
    u16*     HsH   = (u16*)(ws + 160907520);           // 15,728,640 (ROWS x 320)
    // V (GAT, fp32 ROWSx600) aliases Hlstm (97 slices x 256 x 608 bf16 H-only)
    float*   V      = (float*)(ws + 176636160);        // 58,982,400
    u16*     HlstmH = (u16*)(ws + 176636160);          // 30,195,712 (97 slices)
    // MLP scratch aliases Hcat (dead after last Hcat split)
    u16*     x1H   = (u16*)Hcat;                       // 15,728,640 (ROWS x 320)
    float*   x2    = (float*)(ws + 72433920 + 31457280);    // 29,884,416 (ROWS x 304)

    // ---- tier selection for chunked seq/zin region ----
    const size_t fixedNeed = 235618560ull;
    const size_t perT = 3457024ull;                    // zin(2,457,600)+seqH(999,424)
    int T;
    if      (ws_size >= fixedNeed + 96ull * perT) T = 96;
    else if (ws_size >= fixedNeed + 48ull * perT) T = 48;
    else if (ws_size >= fixedNeed + 32ull * perT) T = 32;
    else if (ws_size >= fixedNeed + 16ull * perT) T = 16;
    else if (ws_size >= fixedNeed +  8ull * perT) T = 8;
    else return;                                       // visible failure, no OOB
    char* cr = ws + fixedNeed;
    float* zin  = (float*)cr;                                // (Mc,2400)
    u16*   seqH = (u16*)(cr + (size_t)T * 2457600);          // (Mc,1952)

    // 1) norms + adjacency
    norm_kernel<<<ROWS / 4, 256, 0, stream>>>(features, invn);
    simadj_kernel<<<Bdim, 256, 0, stream>>>(features, invn, entro, alpha, threshold, adj);

    // 2) weight/activation conversions (bf16 H only)
    split_rows8<<<dim3(2, ROWS / 4), 256, 0, stream>>>(            // features n-major full
        features, Edim, 255, Ndim, 8, 1, 0, FfH, Edim, Edim, Edim, ROWS);
    split_rows8<<<dim3(2, 96), 256, 0, stream>>>(                  // fc1_w (384x1024)
        fc1_w, Edim, IDP, Fc1H, Edim, Edim, Edim, HDdim);
    split_rows8<<<dim3(2, 256), 256, 0, stream>>>(                 // enhance_w
        enhance_w, Edim, IDP, EwH, Edim, Edim, Edim, Edim);
    split_rows8<<<dim3(4, 608), 256, 0, stream>>>(                 // Wih gate-interleaved
        lstm_w_ih, Edim + GDdim, 3, LHdim, 2, 1, 0, WihPH, 1952, 1952, 1924, 2400);
    split_rows8<<<dim3(2, 608), 256, 0, stream>>>(                 // Whh gate-interleaved
        lstm_w_hh, LHdim, 3, LHdim, 2, 1, 0, WhhPH, 608, 608, LHdim, 2400);
    split_rows8<<<dim3(2, 96), 256, 0, stream>>>(                  // mlp_w0 (384x608)
        mlp_w0, LHdim, IDP, Wm0H, 608, 608, LHdim, HDdim);
    split_rows8<<<dim3(1, 96), 256, 0, stream>>>(                  // mlp_w1 (384x320)
        mlp_w1, HDdim, IDP, Wm1H, 320, 320, HDdim, HDdim);
    wr_cat<<<dim3(2, 2 * Ldim * HDdim), 256, 0, stream>>>(wr0, wr1, Wr2f);
    for (int l = 0; l < Ldim; ++l)
        split_rows8<<<dim3(1, 160), 256, 0, stream>>>(             // Wr2 (640x320 per layer)
            Wr2f + (size_t)l * 2 * HDdim * HDdim, HDdim, IDP,
            Wr2H + (size_t)l * 640 * 320, 320, 320, HDdim, 2 * HDdim);
    bias_perm<<<10, 256, 0, stream>>>(lstm_b_ih, lstm_b_hh, biasP);
    zero_range<<<1200, 256, 0, stream>>>(c0, 307200);              // c0, c1

    // 3) H0 = prelu(features @ fc1_w^T + fc1_b) -> Hcat[:, 0:300] (bf16 MFMA)
    gemm_bf16<0,1><<<dim3(ROWS/128, 3), 256, 0, stream>>>(
        FfH, Edim, Fc1H, Edim,
        Hcat, nullptr, GDdim, ROWS, HDdim, Edim, fc1_b, prelu_a);

    // 4) GAT layers (bf16 MFMA V projection, fused softmax+aggregation)
    for (int l = 0; l < Ldim; ++l) {
        const float* Hsrc = Hcat + l * HDdim;
        k_kernel<<<ROWS / 4, 256, 0, stream>>>(Hsrc, gat_w + l * 2 * HDdim + HDdim, kbuf);
        split_rows8<<<dim3(1, ROWS / 4), 256, 0, stream>>>(        // Hsrc -> bf16 (K=320)
            Hsrc, GDdim, IDP, HsH, 320, 320, HDdim, ROWS);
        gemm_bf16<0,0><<<dim3(ROWS/128, 5), 256, 0, stream>>>(
            HsH, 320, Wr2H + (size_t)l * 640 * 320, 320,
            V, nullptr, 2 * HDdim, ROWS, 2 * HDdim, 320, nullptr, nullptr);
        gat_fused<<<dim3(Bdim, 2), 256, 0, stream>>>(
            kbuf, adj, s_mask, V, Hcat + (l + 1) * HDdim);
    }

    // 5) zero Hlstm H region (pads + slice 0 = h_0; aliased V until now)
    zero_range<<<29489, 256, 0, stream>>>((float*)HlstmH, 7548928);

    // 6) chunked: enhance (bf16) -> Hcat split -> zin (bf16) -> LSTM (bf16)
    int cur = 0;
    float* cb_[2] = {c0, c1};
    for (int t0 = 0; t0 < Ndim; t0 += T) {
        int Mc = T * Bdim;
        gemm_bf16<1,1><<<dim3(Mc/128, 8), 256, 0, stream>>>(       // bf16 enhance -> seqH
            FfH + (size_t)t0 * Bdim * Edim, Edim, EwH, Edim,
            nullptr, seqH, 1952, Mc, Edim, Edim, enhance_b, prelu_a);
        split_rows8<<<dim3(2, Mc / 4), 256, 0, stream>>>(
            Hcat, GDdim, 0x7FFFFFFF, 1, 30, 0, t0 * Bdim,
            seqH + 1024, 1952, 928, GDdim, Mc);
        gemm_bf16<0,0><<<dim3(Mc/128, 19), 256, 0, stream>>>(      // bf16 zin
            seqH, 1952, WihPH, 1952,
            zin, nullptr, 4 * LHdim, Mc, 4 * LHdim, 1952, biasP, nullptr);
        for (int tl = 0; tl < T; ++tl) {
            const int g = t0 + tl;                    // global step, 0-based
            lstm_bf16<<<dim3(8, 38), 256, 0, stream>>>(
                HlstmH + (size_t)g * HSLICE, cb_[cur], WhhPH,
                zin + (size_t)tl * Bdim * 4 * LHdim,
                HlstmH + (size_t)(g + 1) * HSLICE, cb_[cur ^ 1]);
            cur ^= 1;
        }
    }

    // 7) MLP head (bf16 MFMA, A = Hlstm slices 1..96) + output
    zero_range<<<15360, 256, 0, stream>>>((float*)x1H, 3932160);   // x1H pads must be 0
    gemm_bf16<1,1><<<dim3(ROWS/128, 3), 256, 0, stream>>>(
        HlstmH + HSLICE, 608, Wm0H, 608,
        nullptr, x1H, 320, ROWS, HDdim, 608, mlp_b0, mlp_a0);
    gemm_bf16<0,1><<<dim3(ROWS/128, 3), 256, 0, stream>>>(
        x1H, 320, Wm1H, 320,
        x2, nullptr, 304, ROWS, HDdim, 320, mlp_b1, mlp_a1);
    out_kernel<<<ROWS / 4, 256, 0, stream>>>(x2, 304, out_w, out_b, out);
}

// Round 25
// 2187.870 us; speedup vs baseline: 2.1196x; 1.1138x over previous
//
#include <hip/hip_runtime.h>
#include <cstdint>
#include <cstddef>

#define Bdim 256
#define Ndim 96
#define Edim 1024
#define HDdim 300
#define Ldim 2
#define LHdim 600
#define NCdim 7
#define GDdim 900              // HD*(L+1)
#define ROWS (Bdim*Ndim)       // 24576
#define HSLICE 155648          // 256*608 elements per Hlstm time-slice

typedef unsigned short u16;
typedef unsigned int   u32;
typedef float f32x4 __attribute__((ext_vector_type(4)));
typedef short bf16x8 __attribute__((ext_vector_type(8)));
typedef unsigned short u16x4 __attribute__((ext_vector_type(4)));

// Identity row-perm constants
#define IDP 0x7FFFFFFF, 1, 30, 0, 0

__device__ inline u16 f2bf(float x) {
    u32 u = __builtin_bit_cast(u32, x);
    u32 r = (u + 0x7fffu + ((u >> 16) & 1u)) >> 16;   // RNE
    return (u16)r;
}
__device__ inline float bf2f(u16 h) {
    u32 u = ((u32)h) << 16;
    return __builtin_bit_cast(float, u);
}

// ---------------------------------------------------------------------------
// Pure single-bf16 MFMA GEMM. Round-24 schedule: double-buffered LDS
// (2x16 KB), reg prefetch of next k-chunk, ONE barrier per chunk.
// C = act(A·W^T + bias). K mult of 32; lda/ldw mult 8; M mult of 128;
// W must have gridDim.y*128 rows allocated (pad rows zeroed).
// OUT: 0 -> fp32 C; 1 -> bf16 Ch only. ACT: 1 -> prelu(aptr).
// ---------------------------------------------------------------------------
template<int OUT, int ACT>
__global__ __launch_bounds__(256) void gemm_bf16(
    const u16* __restrict__ Ah, int lda,
    const u16* __restrict__ Wh, int ldw,
    float* __restrict__ C, u16* __restrict__ Ch, int ldc,
    int M, int Nd, int K,
    const float* __restrict__ bias, const float* __restrict__ aptr)
{
    __shared__ u16 At[2][4][1024];
    __shared__ u16 Wt[2][4][1024];
    const int tid  = threadIdx.x;
    const int ny  = gridDim.y;
    const int nwg = gridDim.x * ny;
    const int lin = blockIdx.y * gridDim.x + blockIdx.x;
    const int q = nwg >> 3, r8 = nwg & 7;
    const int xcd = lin & 7, off = lin >> 3;
    const int swz = (xcd < r8) ? xcd * (q + 1) + off
                               : r8 * (q + 1) + (xcd - r8) * q + off;
    const int bm   = (swz / ny) * 128;
    const int bn   = (swz % ny) * 128;
    const int wv   = tid >> 6;
    const int lane = tid & 63;
    const int wr   = (wv >> 1) * 64;
    const int wc   = (wv & 1) * 64;
    const int l15  = lane & 15;
    const int kseg = lane >> 4;

    f32x4 acc[4][4];
    #pragma unroll
    for (int i = 0; i < 4; ++i)
        #pragma unroll
        for (int j = 0; j < 4; ++j) acc[i][j] = (f32x4){0.f,0.f,0.f,0.f};

    const int srow = tid & 127;
    const bool isA = (tid < 128);
    const int gr   = isA ? (bm + srow) : (bn + srow);
    const u16* pbase = (isA ? Ah : Wh) + (size_t)gr * (isA ? lda : ldw);
    u16* dst = isA ? &At[0][0][0] : &Wt[0][0][0];
    const int soff = srow * 8;

    // preload chunk 0
    bf16x8 rv[4];
    #pragma unroll
    for (int s = 0; s < 4; ++s) rv[s] = *(const bf16x8*)(pbase + s * 8);

    const int nk = K >> 5;
    for (int kc = 0; kc < nk; ++kc) {
        const int bufo = (kc & 1) << 12;              // buffer stride 4096 u16
        #pragma unroll
        for (int s = 0; s < 4; ++s)
            *(bf16x8*)(dst + bufo + s * 1024 + soff) = rv[s];
        if (kc + 1 < nk) {                            // prefetch next chunk
            const u16* p = pbase + (kc + 1) * 32;
            #pragma unroll
            for (int s = 0; s < 4; ++s) rv[s] = *(const bf16x8*)(p + s * 8);
        }
        __syncthreads();                              // single barrier per chunk
        const u16* Ab = &At[0][0][0] + bufo + kseg * 1024;
        const u16* Wb = &Wt[0][0][0] + bufo + kseg * 1024;
        bf16x8 a[4], b[4];
        #pragma unroll
        for (int f = 0; f < 4; ++f) {
            a[f] = *(const bf16x8*)(Ab + (wr + f * 16 + l15) * 8);
            b[f] = *(const bf16x8*)(Wb + (wc + f * 16 + l15) * 8);
        }
        #pragma unroll
        for (int i = 0; i < 4; ++i)
            #pragma unroll
            for (int j = 0; j < 4; ++j)
                acc[i][j] = __builtin_amdgcn_mfma_f32_16x16x32_bf16(a[i], b[j], acc[i][j], 0, 0, 0);
    }

    const float av = (ACT == 1) ? *aptr : 0.f;
    const int r4 = (lane >> 4) * 4;
    #pragma unroll
    for (int j = 0; j < 4; ++j) {
        int col = bn + wc + j * 16 + l15;
        if (col >= Nd) continue;
        float bv = bias ? bias[col] : 0.f;
        #pragma unroll
        for (int i = 0; i < 4; ++i) {
            #pragma unroll
            for (int rr = 0; rr < 4; ++rr) {
                int row = bm + wr + i * 16 + r4 + rr;
                if (row >= M) continue;
                float v = acc[i][j][rr] + bv;
                if (ACT == 1) v = (v >= 0.f) ? v : av * v;
                if (OUT == 0) {
                    C[(size_t)row * ldc + col] = v;
                } else {
                    Ch[(size_t)row * ldc + col] = f2bf(v);
                }
            }
        }
    }
}

// ---------------------------------------------------------------------------
// fp32 -> bf16 (H only). 4 rows/block, 8 cols/thread.
// ---------------------------------------------------------------------------
__global__ __launch_bounds__(256) void split_rows8(
    const float* __restrict__ src, int srcld,
    int pmask, int pmul1, int pshift, int pmul2, int padd,
    u16* __restrict__ dstH, int dstld,
    int wcols, int validK, int validRows)
{
    const int r = blockIdx.y * 4 + (threadIdx.x >> 6);
    const int c = (blockIdx.x * 64 + (threadIdx.x & 63)) * 8;
    if (c >= wcols) return;
    const int sr = (r & pmask) * pmul1 + (r >> pshift) * pmul2 + padd;
    const float* s = src + (size_t)sr * srcld;
    const bool rok = (r < validRows);
    float v[8];
    if (rok && c + 8 <= validK) {
        *(float4*)&v[0] = *(const float4*)(s + c);
        *(float4*)&v[4] = *(const float4*)(s + c + 4);
    } else {
        #pragma unroll
        for (int u = 0; u < 8; ++u) v[u] = (rok && c + u < validK) ? s[c + u] : 0.f;
    }
    bf16x8 H8;
    #pragma unroll
    for (int u = 0; u < 8; ++u) H8[u] = (short)f2bf(v[u]);
    *(bf16x8*)(dstH + (size_t)r * dstld + c) = H8;
}

// biasP[n'] = b_ih[orig]+b_hh[orig], orig = (n'&3)*600+(n'>>2)
__global__ __launch_bounds__(256) void bias_perm(
    const float* __restrict__ bih, const float* __restrict__ bhh, float* __restrict__ dst)
{
    int n = blockIdx.x * 256 + threadIdx.x;
    if (n >= 4 * LHdim) return;
    int o = (n & 3) * LHdim + (n >> 2);
    dst[n] = bih[o] + bhh[o];
}

// Wr2f[l][r][c]: r<300 -> wr0[l][r][c], else wr1[l][r-300][c]
__global__ __launch_bounds__(256) void wr_cat(
    const float* __restrict__ wr0, const float* __restrict__ wr1, float* __restrict__ dst)
{
    int c = blockIdx.x * 256 + threadIdx.x;
    if (c >= HDdim) return;
    int lr = blockIdx.y;
    int l = lr / (2 * HDdim), r = lr % (2 * HDdim);
    const float* src = (r < HDdim)
        ? wr0 + ((size_t)l * HDdim + r) * HDdim
        : wr1 + ((size_t)l * HDdim + (r - HDdim)) * HDdim;
    dst[(size_t)lr * HDdim + c] = src[c];
}

__global__ __launch_bounds__(256) void zero_range(float* __restrict__ p, int n)
{
    int i = blockIdx.x * 256 + threadIdx.x;
    if (i < n) p[i] = 0.f;
}

// ---------------------------------------------------------------------------
__global__ __launch_bounds__(256) void norm_kernel(const float* __restrict__ f, float* __restrict__ invn)
{
    int row  = blockIdx.x * 4 + (threadIdx.x >> 6);
    int lane = threadIdx.x & 63;
    const float* fr = f + (size_t)row * Edim;
    float ss = 0.f;
    for (int t = lane; t < Edim; t += 64) { float v = fr[t]; ss = fmaf(v, v, ss); }
    #pragma unroll
    for (int o = 32; o > 0; o >>= 1) ss += __shfl_down(ss, o);
    if (lane == 0) invn[row] = 1.f / (sqrtf(ss) + 1e-8f);
}

__global__ __launch_bounds__(256) void simadj_kernel(
    const float* __restrict__ f, const float* __restrict__ invn,
    const float* __restrict__ entro, const float* __restrict__ alphap,
    const float* __restrict__ thrp, uint8_t* __restrict__ adj)
{
    int b = blockIdx.x;
    __shared__ float S[16][100];
    int tid = threadIdx.x;
    int i0 = (tid >> 4) * 6, j0 = (tid & 15) * 6;
    float acc[6][6];
    #pragma unroll
    for (int i = 0; i < 6; ++i)
        #pragma unroll
        for (int j = 0; j < 6; ++j) acc[i][j] = 0.f;
    const float* fb = f + (size_t)b * Ndim * Edim;

    for (int k0 = 0; k0 < Edim; k0 += 16) {
        __syncthreads();
        #pragma unroll
        for (int r = 0; r < 6; ++r) {
            int n = (tid >> 4) + r * 16;
            S[tid & 15][n] = fb[(size_t)n * Edim + k0 + (tid & 15)];
        }
        __syncthreads();
        #pragma unroll
        for (int kk = 0; kk < 16; ++kk) {
            float a[6], bb[6];
            #pragma unroll
            for (int u = 0; u < 6; ++u) a[u] = S[kk][i0 + u];
            #pragma unroll
            for (int u = 0; u < 6; ++u) bb[u] = S[kk][j0 + u];
            #pragma unroll
            for (int i = 0; i < 6; ++i)
                #pragma unroll
                for (int j = 0; j < 6; ++j)
                    acc[i][j] = fmaf(a[i], bb[j], acc[i][j]);
        }
    }

    float alpha = *alphap, thr = *thrp;
    float onem = 1.f - alpha;
    #pragma unroll
    for (int i = 0; i < 6; ++i) {
        int ii = i0 + i;
        float inv_i = invn[b * Ndim + ii];
        #pragma unroll
        for (int j = 0; j < 6; ++j) {
            int jj = j0 + j;
            float simv = acc[i][j] * inv_i * invn[b * Ndim + jj];
            float comb = alpha * entro[b * Ndim + jj] + onem * simv;
            adj[((size_t)b * Ndim + ii) * Ndim + jj] = (comb > thr) ? 1 : 0;
        }
    }
}

// k[r] = H[r,:300] . wk   (q cancels in the adjacency softmax; not computed)
__global__ __launch_bounds__(256) void k_kernel(
    const float* __restrict__ Hsrc, const float* __restrict__ wk,
    float* __restrict__ k)
{
    int row  = blockIdx.x * 4 + (threadIdx.x >> 6);
    int lane = threadIdx.x & 63;
    const float* h = Hsrc + (size_t)row * GDdim;
    float sk = 0.f;
    for (int t = lane; t < HDdim; t += 64) sk = fmaf(h[t], wk[t], sk);
    #pragma unroll
    for (int o = 32; o > 0; o >>= 1) sk += __shfl_down(sk, o);
    if (lane == 0) k[row] = sk;
}

// ---------------------------------------------------------------------------
// Fused GAT attention (q, gat_b cancel in softmax). bf16 LDS (77 KB).
// grid (B, 2): block half handles d-passes {2*half, 2*half+1}.
// V combined: cols 0..299 = V0, 300..599 = V1, row stride 600 (n-major rows).
// ---------------------------------------------------------------------------
__global__ __launch_bounds__(256) void gat_fused(
    const float* __restrict__ kbuf, const uint8_t* __restrict__ adj,
    const int* __restrict__ smask,
    const float* __restrict__ V,
    float* __restrict__ Mout)
{
    __shared__ u16 P0[96][100];
    __shared__ u16 P1[96][100];
    __shared__ u16 Vs0[96][96];
    __shared__ u16 Vs1[96][96];
    __shared__ float ek[96];
    __shared__ float rden[96];
    __shared__ float red[256];
    const int b = blockIdx.x;
    const int half = blockIdx.y;
    const int tid = threadIdx.x;

    float kj = (tid < Ndim) ? kbuf[tid * Bdim + b] : -1e30f;
    red[tid] = kj;
    __syncthreads();
    #pragma unroll
    for (int s = 128; s > 0; s >>= 1) {
        if (tid < s) red[tid] = fmaxf(red[tid], red[tid + s]);
        __syncthreads();
    }
    float kmax = red[0];
    if (tid < Ndim) ek[tid] = expf(kj - kmax);
    __syncthreads();
    if (tid < Ndim) {
        const uint8_t* ar = adj + ((size_t)b * Ndim + tid) * Ndim;
        float s = 0.f;
        for (int j = 0; j < Ndim; ++j) if (ar[j]) s += ek[j];
        rden[tid] = 1.f / s;   // diagonal always allowed -> s > 0
    }
    __syncthreads();
    for (int idx = tid; idx < Ndim * Ndim; idx += 256) {
        int i = idx / Ndim, j = idx - i * Ndim;
        float a = adj[((size_t)b * Ndim + i) * Ndim + j] ? ek[j] * rden[i] : 0.f;
        int s = smask[((size_t)b * Ndim + i) * Ndim + j];
        P0[i][j] = s ? f2bf(a) : (u16)0;
        P1[i][j] = s ? (u16)0 : f2bf(a);
    }
    __syncthreads();

    const int ti = tid >> 4, td = tid & 15;
    const int i0 = ti * 6, dbase = td * 6;
    for (int p = 2 * half; p < 2 * half + 2; ++p) {
        const int d0 = p * 96;
        const int dw = (p == 3) ? (HDdim - 288) : 96;
        for (int idx = tid; idx < 96 * 24; idx += 256) {
            int j = idx / 24, q4 = (idx - j * 24) * 4;
            if (q4 < dw) {
                size_t g = ((size_t)(j * Bdim + b)) * (2 * HDdim) + d0 + q4;
                float4 a = *(const float4*)(V + g);
                float4 c = *(const float4*)(V + g + HDdim);
                u16x4 ua = { f2bf(a.x), f2bf(a.y), f2bf(a.z), f2bf(a.w) };
                u16x4 uc = { f2bf(c.x), f2bf(c.y), f2bf(c.z), f2bf(c.w) };
                *(u16x4*)&Vs0[j][q4] = ua;
                *(u16x4*)&Vs1[j][q4] = uc;
            }
        }
        __syncthreads();
        float acc[6][6];
        #pragma unroll
        for (int ii = 0; ii < 6; ++ii)
            #pragma unroll
            for (int dd = 0; dd < 6; ++dd) acc[ii][dd] = 0.f;
        for (int j = 0; j < Ndim; j += 2) {
            float paj[6], pajn[6], pbj[6], pbjn[6];
            #pragma unroll
            for (int ii = 0; ii < 6; ++ii) {
                u32 w0 = *(const u32*)&P0[i0 + ii][j];
                u32 w1 = *(const u32*)&P1[i0 + ii][j];
                paj[ii]  = __builtin_bit_cast(float, w0 << 16);
                pajn[ii] = __builtin_bit_cast(float, w0 & 0xffff0000u);
                pbj[ii]  = __builtin_bit_cast(float, w1 << 16);
                pbjn[ii] = __builtin_bit_cast(float, w1 & 0xffff0000u);
            }
            float v0a[6], v0b[6], v1a[6], v1b[6];
            #pragma unroll
            for (int dd = 0; dd < 3; ++dd) {
                u32 wa = *(const u32*)&Vs0[j][dbase + 2 * dd];
                u32 wb = *(const u32*)&Vs0[j + 1][dbase + 2 * dd];
                u32 wc2 = *(const u32*)&Vs1[j][dbase + 2 * dd];
                u32 wd = *(const u32*)&Vs1[j + 1][dbase + 2 * dd];
                v0a[2*dd]   = __builtin_bit_cast(float, wa << 16);
                v0a[2*dd+1] = __builtin_bit_cast(float, wa & 0xffff0000u);
                v0b[2*dd]   = __builtin_bit_cast(float, wb << 16);
                v0b[2*dd+1] = __builtin_bit_cast(float, wb & 0xffff0000u);
                v1a[2*dd]   = __builtin_bit_cast(float, wc2 << 16);
                v1a[2*dd+1] = __builtin_bit_cast(float, wc2 & 0xffff0000u);
                v1b[2*dd]   = __builtin_bit_cast(float, wd << 16);
                v1b[2*dd+1] = __builtin_bit_cast(float, wd & 0xffff0000u);
            }
            #pragma unroll
            for (int ii = 0; ii < 6; ++ii)
                #pragma unroll
                for (int dd = 0; dd < 6; ++dd) {
                    acc[ii][dd] += paj[ii]  * v0a[dd] + pbj[ii]  * v1a[dd]
                                 + pajn[ii] * v0b[dd] + pbjn[ii] * v1b[dd];
                }
        }
        __syncthreads();
        #pragma unroll
        for (int ii = 0; ii < 6; ++ii) {
            #pragma unroll
            for (int dd = 0; dd < 6; ++dd) {
                int d = dbase + dd;
                if (d < dw)
                    Mout[((size_t)((i0 + ii) * Bdim + b)) * GDdim + d0 + d] = acc[ii][dd];
            }
        }
    }
}

// ---------------------------------------------------------------------------
// Per-step LSTM, round-25 rewrite: whole A (64x608) + W (64x608) staged into
// 152 KB LDS with batched loads, then a barrier-free k-loop (19 chunks of
// pure LDS reads + MFMA; each wave owns a 32x32 output tile). Kills the
// per-chunk {load-stall + barrier} serialization (was ~10.4 us/step).
// Tile 64 batch x 64 gate-cols, grid (4,38) = 152 blocks, 1 block/CU.
// Same K order / same MFMA per output as lstm_bf16 -> bitwise-identical.
// ---------------------------------------------------------------------------
__global__ __launch_bounds__(256) void lstm_fused(
    const u16* __restrict__ hH,
    const float* __restrict__ cin,
    const u16* __restrict__ WH,                  // (2432 x 608), pads zero
    const float* __restrict__ zt,
    u16* __restrict__ hHo,
    float* __restrict__ cout)
{
    __shared__ u16 AW[2][38912];                 // [0]=A, [1]=W; 155,648 B
    const int tid = threadIdx.x;
    const int bm = blockIdx.x * 64;
    const int bn = blockIdx.y * 64;
    const int wv = tid >> 6;
    const int lane = tid & 63;
    const int l15 = lane & 15;
    const int kseg = lane >> 4;
    const int wr2 = (wv >> 1) * 32;
    const int wc2 = (wv & 1) * 32;

    // T14: cell-phase loads issued now; consumed after the k-loop. 4 cells/t.
    float4 z[4]; float ci[4]; bool ok[4]; int bb[4], pu[4];
    #pragma unroll
    for (int k = 0; k < 4; ++k) {
        int c4 = k * 256 + tid;
        int row = c4 >> 4, u = c4 & 15;
        bb[k] = bm + row;
        pu[k] = (bn >> 2) + u;
        ok[k] = (pu[k] < LHdim);
        z[k] = ok[k] ? *(const float4*)(zt + (size_t)bb[k] * (4 * LHdim) + bn + u * 4)
                     : make_float4(0.f, 0.f, 0.f, 0.f);
        ci[k] = ok[k] ? cin[bb[k] * LHdim + pu[k]] : 0.f;
    }

    // Stage ALL of A and W into LDS; batches of 4 chunks keep 8 loads in
    // flight per thread (amortizes L2 latency ~5x vs chunk-at-a-time).
    const int srow = tid >> 2, sks = tid & 3;
    const u16* ag = hH + (size_t)(bm + srow) * 608 + sks * 8;
    const u16* wg = WH + (size_t)(bn + srow) * 608 + sks * 8;
    u16* al = &AW[0][(sks * 64 + srow) * 8];
    u16* wl = &AW[1][(sks * 64 + srow) * 8];
    #pragma unroll
    for (int cb = 0; cb < 20; cb += 4) {
        bf16x8 ra[4], rw[4];
        #pragma unroll
        for (int c = 0; c < 4; ++c)
            if (cb + c < 19) {
                ra[c] = *(const bf16x8*)(ag + (cb + c) * 32);
                rw[c] = *(const bf16x8*)(wg + (cb + c) * 32);
            }
        #pragma unroll
        for (int c = 0; c < 4; ++c)
            if (cb + c < 19) {
                *(bf16x8*)(al + (cb + c) * 2048) = ra[c];
                *(bf16x8*)(wl + (cb + c) * 2048) = rw[c];
            }
    }
    __syncthreads();

    // Barrier-free k-loop: 19 chunks, 4 MFMA each, acc 32x32 per wave.
    f32x4 acc[2][2];
    acc[0][0] = acc[0][1] = acc[1][0] = acc[1][1] = (f32x4){0.f,0.f,0.f,0.f};
    const u16* Ab = &AW[0][kseg * 512];
    const u16* Wb = &AW[1][kseg * 512];
    #pragma unroll
    for (int c = 0; c < 19; ++c) {
        bf16x8 a0 = *(const bf16x8*)(Ab + c * 2048 + (wr2 + l15) * 8);
        bf16x8 a1 = *(const bf16x8*)(Ab + c * 2048 + (wr2 + 16 + l15) * 8);
        bf16x8 b0 = *(const bf16x8*)(Wb + c * 2048 + (wc2 + l15) * 8);
        bf16x8 b1 = *(const bf16x8*)(Wb + c * 2048 + (wc2 + 16 + l15) * 8);
        acc[0][0] = __builtin_amdgcn_mfma_f32_16x16x32_bf16(a0, b0, acc[0][0], 0, 0, 0);
        acc[0][1] = __builtin_amdgcn_mfma_f32_16x16x32_bf16(a0, b1, acc[0][1], 0, 0, 0);
        acc[1][0] = __builtin_amdgcn_mfma_f32_16x16x32_bf16(a1, b0, acc[1][0], 0, 0, 0);
        acc[1][1] = __builtin_amdgcn_mfma_f32_16x16x32_bf16(a1, b1, acc[1][1], 0, 0, 0);
    }

    // gates via LDS (alias the dead A region: 64x68 f32 = 17.4 KB < 77.8 KB)
    __syncthreads();
    float* gates = (float*)&AW[0][0];
    const int r4 = (lane >> 4) * 4;
    #pragma unroll
    for (int i = 0; i < 2; ++i)
        #pragma unroll
        for (int j = 0; j < 2; ++j)
            #pragma unroll
            for (int rr = 0; rr < 4; ++rr)
                gates[(wr2 + i * 16 + r4 + rr) * 68 + wc2 + j * 16 + l15] = acc[i][j][rr];
    __syncthreads();

    // fused cell: 4 cells per thread, using prefetched z/c
    #pragma unroll
    for (int k = 0; k < 4; ++k) {
        if (!ok[k]) continue;
        int c4 = k * 256 + tid;
        int row = c4 >> 4, u = c4 & 15;
        float4 g = *(const float4*)&gates[row * 68 + u * 4];
        float gi = g.x + z[k].x;
        float gf = g.y + z[k].y;
        float gg = g.z + z[k].z;
        float go = g.w + z[k].w;
        float si = 1.f / (1.f + expf(-gi));
        float sf = 1.f / (1.f + expf(-gf));
        float so = 1.f / (1.f + expf(-go));
        float cn = sf * ci[k] + si * tanhf(gg);
        float hn = so * tanhf(cn);
        cout[bb[k] * LHdim + pu[k]] = cn;
        hHo[(size_t)bb[k] * 608 + pu[k]] = f2bf(hn);
    }
}

__global__ __launch_bounds__(256) void out_kernel(
    const float* __restrict__ x, int ldx, const float* __restrict__ ow,
    const float* __restrict__ ob, float* __restrict__ out)
{
    int r    = blockIdx.x * 4 + (threadIdx.x >> 6);
    int lane = threadIdx.x & 63;
    const float* xr = x + (size_t)r * ldx;
    float acc[NCdim];
    #pragma unroll
    for (int n = 0; n < NCdim; ++n) acc[n] = 0.f;
    for (int t = lane; t < HDdim; t += 64) {
        float xv = xr[t];
        #pragma unroll
        for (int n = 0; n < NCdim; ++n) acc[n] = fmaf(xv, ow[n * HDdim + t], acc[n]);
    }
    #pragma unroll
    for (int o = 32; o > 0; o >>= 1)
        #pragma unroll
        for (int n = 0; n < NCdim; ++n) acc[n] += __shfl_down(acc[n], o);
    if (lane == 0) {
        int b = r & 255, nn = r >> 8;
        #pragma unroll
        for (int n = 0; n < NCdim; ++n) out[((size_t)b * Ndim + nn) * NCdim + n] = acc[n] + ob[n];
    }
}

// ---------------------------------------------------------------------------
extern "C" void kernel_launch(void* const* d_in, const int* in_sizes, int n_in,
                              void* d_out, int out_size, void* d_ws, size_t ws_size,
                              hipStream_t stream)
{
    const float*  features  = (const float*)d_in[0];
    const int*    s_mask    = (const int*)  d_in[1];
    const float*  entro     = (const float*)d_in[2];
    const float*  alpha     = (const float*)d_in[3];
    const float*  threshold = (const float*)d_in[4];
    const float*  fc1_w     = (const float*)d_in[5];
    const float*  fc1_b     = (const float*)d_in[6];
    const float*  gat_w     = (const float*)d_in[7];
    const float*  gat_b     = (const float*)d_in[8];
    const float*  wr0       = (const float*)d_in[9];
    const float*  wr1       = (const float*)d_in[10];
    const float*  enhance_w = (const float*)d_in[11];
    const float*  enhance_b = (const float*)d_in[12];
    const float*  prelu_a   = (const float*)d_in[13];
    const float*  lstm_w_ih = (const float*)d_in[14];
    const float*  lstm_w_hh = (const float*)d_in[15];
    const float*  lstm_b_ih = (const float*)d_in[16];
    const float*  lstm_b_hh = (const float*)d_in[17];
    const float*  mlp_w0    = (const float*)d_in[18];
    const float*  mlp_b0    = (const float*)d_in[19];
    const float*  mlp_a0    = (const float*)d_in[20];
    const float*  mlp_w1    = (const float*)d_in[21];
    const float*  mlp_b1    = (const float*)d_in[22];
    const float*  mlp_a1    = (const float*)d_in[23];
    const float*  out_w     = (const float*)d_in[24];
    const float*  out_b     = (const float*)d_in[25];
    float* out = (float*)d_out;
    char* ws = (char*)d_ws;
    (void)gat_b;

    // ---- compacted workspace layout (bytes, 256-aligned) ----
    uint8_t* adj   = (uint8_t*)(ws + 0);               //  2,359,296
    float*   invn  = (float*)(ws + 2359296);           //     98,304
    float*   kbuf  = (float*)(ws + 2457600);           //     98,304
    float*   biasP = (float*)(ws + 2555904);           //      9,728
    float*   c0    = (float*)(ws + 2566144);           //    614,400
    float*   c1    = (float*)(ws + 3180544);           //    614,400
    u16*     WhhPH = (u16*)(ws + 3794944);             //  2,957,312 (2432 x 608)
    u16*     WihPH = (u16*)(ws + 6752256);             //  9,494,528 (2432 x 1952)
    u16*     EwH   = (u16*)(ws + 16246784);            //  2,097,152 (1024 x 1024)
    u16*     Fc1H  = (u16*)(ws + 18343936);            //    786,432 (384 x 1024)
    float*   Wr2f  = (float*)(ws + 19130368);          //  1,440,000 (2 x 600 x 300)
    u16*     Wr2H  = (u16*)(ws + 20570368);            //    819,200 (2 x 640 x 320)
    u16*     Wm0H  = (u16*)(ws + 21389568);            //    466,944 (384 x 608)
    u16*     Wm1H  = (u16*)(ws + 21856512);            //    245,760 (384 x 320)
    u16*     FfH   = (u16*)(ws + 22102272);            // 50,331,648 (ROWS x 1024)
    float*   Hcat  = (float*)(ws + 72433920);          // 88,473,600 (ROWS,900) n-major
    u16*     HsH   = (u16*)(ws + 160907520);           // 15,728,640 (ROWS x 320)
    // V (GAT, fp32 ROWSx600) aliases Hlstm (97 slices x 256 x 608 bf16 H-only)
    float*   V      = (float*)(ws + 176636160);        // 58,982,400
    u16*     HlstmH = (u16*)(ws + 176636160);          // 30,195,712 (97 slices)
    // MLP scratch aliases Hcat (dead after last Hcat split)
    u16*     x1H   = (u16*)Hcat;                       // 15,728,640 (ROWS x 320)
    float*   x2    = (float*)(ws + 72433920 + 31457280);    // 29,884,416 (ROWS x 304)

    // ---- tier selection for chunked seq/zin region ----
    const size_t fixedNeed = 235618560ull;
    const size_t perT = 3457024ull;                    // zin(2,457,600)+seqH(999,424)
    int T;
    if      (ws_size >= fixedNeed + 96ull * perT) T = 96;
    else if (ws_size >= fixedNeed + 48ull * perT) T = 48;
    else if (ws_size >= fixedNeed + 32ull * perT) T = 32;
    else if (ws_size >= fixedNeed + 16ull * perT) T = 16;
    else if (ws_size >= fixedNeed +  8ull * perT) T = 8;
    else return;                                       // visible failure, no OOB
    char* cr = ws + fixedNeed;
    float* zin  = (float*)cr;                                // (Mc,2400)
    u16*   seqH = (u16*)(cr + (size_t)T * 2457600);          // (Mc,1952)

    // 1) norms + adjacency
    norm_kernel<<<ROWS / 4, 256, 0, stream>>>(features, invn);
    simadj_kernel<<<Bdim, 256, 0, stream>>>(features, invn, entro, alpha, threshold, adj);

    // 2) weight/activation conversions (bf16 H only)
    split_rows8<<<dim3(2, ROWS / 4), 256, 0, stream>>>(            // features n-major full
        features, Edim, 255, Ndim, 8, 1, 0, FfH, Edim, Edim, Edim, ROWS);
    split_rows8<<<dim3(2, 96), 256, 0, stream>>>(                  // fc1_w (384x1024)
        fc1_w, Edim, IDP, Fc1H, Edim, Edim, Edim, HDdim);
    split_rows8<<<dim3(2, 256), 256, 0, stream>>>(                 // enhance_w
        enhance_w, Edim, IDP, EwH, Edim, Edim, Edim, Edim);
    split_rows8<<<dim3(4, 608), 256, 0, stream>>>(                 // Wih gate-interleaved
        lstm_w_ih, Edim + GDdim, 3, LHdim, 2, 1, 0, WihPH, 1952, 1952, 1924, 2400);
    split_rows8<<<dim3(2, 608), 256, 0, stream>>>(                 // Whh gate-interleaved
        lstm_w_hh, LHdim, 3, LHdim, 2, 1, 0, WhhPH, 608, 608, LHdim, 2400);
    split_rows8<<<dim3(2, 96), 256, 0, stream>>>(                  // mlp_w0 (384x608)
        mlp_w0, LHdim, IDP, Wm0H, 608, 608, LHdim, HDdim);
    split_rows8<<<dim3(1, 96), 256, 0, stream>>>(                  // mlp_w1 (384x320)
        mlp_w1, HDdim, IDP, Wm1H, 320, 320, HDdim, HDdim);
    wr_cat<<<dim3(2, 2 * Ldim * HDdim), 256, 0, stream>>>(wr0, wr1, Wr2f);
    for (int l = 0; l < Ldim; ++l)
        split_rows8<<<dim3(1, 160), 256, 0, stream>>>(             // Wr2 (640x320 per layer)
            Wr2f + (size_t)l * 2 * HDdim * HDdim, HDdim, IDP,
            Wr2H + (size_t)l * 640 * 320, 320, 320, HDdim, 2 * HDdim);
    bias_perm<<<10, 256, 0, stream>>>(lstm_b_ih, lstm_b_hh, biasP);
    zero_range<<<1200, 256, 0, stream>>>(c0, 307200);              // c0, c1

    // 3) H0 = prelu(features @ fc1_w^T + fc1_b) -> Hcat[:, 0:300] (bf16 MFMA)
    gemm_bf16<0,1><<<dim3(ROWS/128, 3), 256, 0, stream>>>(
        FfH, Edim, Fc1H, Edim,
        Hcat, nullptr, GDdim, ROWS, HDdim, Edim, fc1_b, prelu_a);

    // 4) GAT layers (bf16 MFMA V projection, fused softmax+aggregation)
    for (int l = 0; l < Ldim; ++l) {
        const float* Hsrc = Hcat + l * HDdim;
        k_kernel<<<ROWS / 4, 256, 0, stream>>>(Hsrc, gat_w + l * 2 * HDdim + HDdim, kbuf);
        split_rows8<<<dim3(1, ROWS / 4), 256, 0, stream>>>(        // Hsrc -> bf16 (K=320)
            Hsrc, GDdim, IDP, HsH, 320, 320, HDdim, ROWS);
        gemm_bf16<0,0><<<dim3(ROWS/128, 5), 256, 0, stream>>>(
            HsH, 320, Wr2H + (size_t)l * 640 * 320, 320,
            V, nullptr, 2 * HDdim, ROWS, 2 * HDdim, 320, nullptr, nullptr);
        gat_fused<<<dim3(Bdim, 2), 256, 0, stream>>>(
            kbuf, adj, s_mask, V, Hcat + (l + 1) * HDdim);
    }

    // 5) zero Hlstm H region (pads + slice 0 = h_0; aliased V until now)
    zero_range<<<29489, 256, 0, stream>>>((float*)HlstmH, 7548928);

    // 6) chunked: enhance (bf16) -> Hcat split -> zin (bf16) -> LSTM (fused)
    int cur = 0;
    float* cb_[2] = {c0, c1};
    for (int t0 = 0; t0 < Ndim; t0 += T) {
        int Mc = T * Bdim;
        gemm_bf16<1,1><<<dim3(Mc/128, 8), 256, 0, stream>>>(       // bf16 enhance -> seqH
            FfH + (size_t)t0 * Bdim * Edim, Edim, EwH, Edim,
            nullptr, seqH, 1952, Mc, Edim, Edim, enhance_b, prelu_a);
        split_rows8<<<dim3(2, Mc / 4), 256, 0, stream>>>(
            Hcat, GDdim, 0x7FFFFFFF, 1, 30, 0, t0 * Bdim,
            seqH + 1024, 1952, 928, GDdim, Mc);
        gemm_bf16<0,0><<<dim3(Mc/128, 19), 256, 0, stream>>>(      // bf16 zin
            seqH, 1952, WihPH, 1952,
            zin, nullptr, 4 * LHdim, Mc, 4 * LHdim, 1952, biasP, nullptr);
        for (int tl = 0; tl < T; ++tl) {
            const int g = t0 + tl;                    // global step, 0-based
            lstm_fused<<<dim3(4, 38), 256, 0, stream>>>(
                HlstmH + (size_t)g * HSLICE, cb_[cur], WhhPH,
                zin + (size_t)tl * Bdim * 4 * LHdim,
                HlstmH + (size_t)(g + 1) * HSLICE, cb_[cur ^ 1]);
            cur ^= 1;
        }
    }

    // 7) MLP head (bf16 MFMA, A = Hlstm slices 1..96) + output
    zero_range<<<15360, 256, 0, stream>>>((float*)x1H, 3932160);   // x1H pads must be 0
    gemm_bf16<1,1><<<dim3(ROWS/128, 3), 256, 0, stream>>>(
        HlstmH + HSLICE, 608, Wm0H, 608,
        nullptr, x1H, 320, ROWS, HDdim, 608, mlp_b0, mlp_a0);
    gemm_bf16<0,1><<<dim3(ROWS/128, 3), 256, 0, stream>>>(
        x1H, 320, Wm1H, 320,
        x2, nullptr, 304, ROWS, HDdim, 320, mlp_b1, mlp_a1);
    out_kernel<<<ROWS / 4, 256, 0, stream>>>(x2, 304, out_w, out_b, out);
}